// Round 1
// baseline (919.326 us; speedup 1.0000x reference)
//
#include <hip/hip_runtime.h>
#include <math.h>

#define NI   50000
#define Tt   1000
#define KP   50176              // 50000 padded: 32 chunks x 1568 (=49*32)
#define MW   1568               // mask words per row (KP/32)
#define NPAD 50048              // 391*128 n-pad for dec gemm

typedef __bf16 bf16x8 __attribute__((ext_vector_type(8)));
typedef float  f32x4  __attribute__((ext_vector_type(4)));

__device__ __forceinline__ unsigned short f2bf(float f) {
  unsigned u = __float_as_uint(f);
  u += 0x7FFFu + ((u >> 16) & 1u);   // RNE
  return (unsigned short)(u >> 16);
}
__device__ __forceinline__ float bf2f(unsigned short u) {
  return __uint_as_float(((unsigned)u) << 16);
}
__device__ __forceinline__ unsigned pack2(float a, float b) {
  return (unsigned)f2bf(a) | ((unsigned)f2bf(b) << 16);
}
__device__ __forceinline__ f32x4 mfma16(const unsigned short* a, const unsigned short* b, f32x4 c) {
  typedef unsigned short u16x8 __attribute__((ext_vector_type(8)));
  u16x8 av = *(const u16x8*)a;
  u16x8 bv = *(const u16x8*)b;
  return __builtin_amdgcn_mfma_f32_16x16x32_bf16(
      __builtin_bit_cast(bf16x8, av), __builtin_bit_cast(bf16x8, bv), c, 0, 0, 0);
}
__device__ __forceinline__ float gelu_f(float x) {
  return 0.5f * x * (1.f + erff(x * 0.70710678118654752f));
}

#define GLD16(gsrc, ldst) __builtin_amdgcn_global_load_lds( \
    (const __attribute__((address_space(1))) unsigned int*)(const void*)(gsrc), \
    (__attribute__((address_space(3))) unsigned int*)(void*)(ldst), 16, 0, 0)

// ---------------------------------------------------------------------------
// bm_expand: x0 f32 -> xmask bits + x0b bf16 {0,1}; one barrier per block
// grid (25, 1024): y = row, x = 2048-elem chunk
// ---------------------------------------------------------------------------
__global__ __launch_bounds__(256) void bm_expand(
    const float* __restrict__ x0, unsigned int* __restrict__ xmask,
    unsigned short* __restrict__ x0b)
{
  __shared__ unsigned int nib[256];
  int r = blockIdx.y, tid = threadIdx.x;
  int c0 = blockIdx.x * 2048;
  int k = c0 + tid * 8;
  const float* row = x0 + (size_t)r * NI;
  float4 a = make_float4(0.f, 0.f, 0.f, 0.f), b = a;
  if (k + 8 <= NI) {                   // NI % 8 == 0
    a = *(const float4*)(row + k);
    b = *(const float4*)(row + k + 4);
  }
  uint4 o;
  o.x = (a.x != 0.f ? 0x3F80u : 0u) | (a.y != 0.f ? 0x3F800000u : 0u);
  o.y = (a.z != 0.f ? 0x3F80u : 0u) | (a.w != 0.f ? 0x3F800000u : 0u);
  o.z = (b.x != 0.f ? 0x3F80u : 0u) | (b.y != 0.f ? 0x3F800000u : 0u);
  o.w = (b.z != 0.f ? 0x3F80u : 0u) | (b.w != 0.f ? 0x3F800000u : 0u);
  if (k < KP) *(uint4*)(x0b + (size_t)r * KP + k) = o;
  unsigned bits8 =
      (a.x != 0.f ? 1u : 0u)  | (a.y != 0.f ? 2u : 0u)  |
      (a.z != 0.f ? 4u : 0u)  | (a.w != 0.f ? 8u : 0u)  |
      (b.x != 0.f ? 16u : 0u) | (b.y != 0.f ? 32u : 0u) |
      (b.z != 0.f ? 64u : 0u) | (b.w != 0.f ? 128u : 0u);
  nib[tid] = bits8;
  __syncthreads();
  if (tid < 64) {
    unsigned wv = nib[tid * 4] | (nib[tid * 4 + 1] << 8) |
                  (nib[tid * 4 + 2] << 16) | (nib[tid * 4 + 3] << 24);
    int widx = (c0 >> 5) + tid;
    if (widx < MW) xmask[(size_t)r * MW + widx] = wv;
  }
}

// enc_w1 (512 x 50000 f32) -> bf16 (512 x KP), k-pad zeroed
__global__ __launch_bounds__(256) void cvt_w1(const float* __restrict__ src,
                                              unsigned short* __restrict__ dst) {
  int c = blockIdx.x * 2048 + threadIdx.x * 8;
  if (c >= KP) return;
  int r = blockIdx.y;
  const float* s = src + (size_t)r * NI;
  uint4 o;
  if (c + 8 <= NI) {
    float4 a = *(const float4*)(s + c), b = *(const float4*)(s + c + 4);
    o.x = pack2(a.x, a.y); o.y = pack2(a.z, a.w);
    o.z = pack2(b.x, b.y); o.w = pack2(b.z, b.w);
  } else {
    float v[8];
#pragma unroll
    for (int i = 0; i < 8; ++i) v[i] = (c + i < NI) ? s[c + i] : 0.f;
    o.x = pack2(v[0], v[1]); o.y = pack2(v[2], v[3]);
    o.z = pack2(v[4], v[5]); o.w = pack2(v[6], v[7]);
  }
  *(uint4*)(dst + (size_t)r * KP + c) = o;
}

// dec_w2 (50000 x 512 f32) -> bf16 straight cvt
__global__ __launch_bounds__(256) void cvt_w2n(const float* __restrict__ src,
                                               unsigned short* __restrict__ dst) {
  size_t idx = ((size_t)blockIdx.x * 256 + threadIdx.x) * 8;   // 12500 blocks exact
  float4 a = *(const float4*)(src + idx), b = *(const float4*)(src + idx + 4);
  uint4 o;
  o.x = pack2(a.x, a.y); o.y = pack2(a.z, a.w);
  o.z = pack2(b.x, b.y); o.w = pack2(b.z, b.w);
  *(uint4*)(dst + idx) = o;
}

// batch-convert 7 small weights f32->bf16
__global__ __launch_bounds__(256) void cvt_many(
    const float* s0, const float* s1, const float* s2, const float* s3,
    const float* s4, const float* s5, const float* s6,
    unsigned short* d0, unsigned short* d1, unsigned short* d2, unsigned short* d3,
    unsigned short* d4, unsigned short* d5, unsigned short* d6)
{
  const float* srcs[7] = {s0, s1, s2, s3, s4, s5, s6};
  unsigned short* dsts[7] = {d0, d1, d2, d3, d4, d5, d6};
  const int ns[7] = {131072, 65536, 65536, 65536, 131072, 131072, 131072};
  int j = blockIdx.y;
  int i = (blockIdx.x * 256 + threadIdx.x) * 8;
  if (i >= ns[j]) return;
  float4 a = *(const float4*)(srcs[j] + i), b = *(const float4*)(srcs[j] + i + 4);
  uint4 o;
  o.x = pack2(a.x, a.y); o.y = pack2(a.z, a.w);
  o.z = pack2(b.x, b.y); o.w = pack2(b.z, b.w);
  *(uint4*)(dsts[j] + i) = o;
}

// compose fused weights (kv-path and seq1-selfattn), bf16 outputs
__global__ __launch_bounds__(256) void compose_k(
    const float* __restrict__ ca_wqkv, const float* __restrict__ ca_bqkv,
    const float* __restrict__ ip_w, const float* __restrict__ ip_b,
    const float* __restrict__ sa_wqkv, const float* __restrict__ sa_bqkv,
    const float* __restrict__ sa_wo, const float* __restrict__ sa_bo,
    unsigned short* __restrict__ Wkv, float* __restrict__ bkv,
    unsigned short* __restrict__ Wsa, float* __restrict__ bsa)
{
  int b = blockIdx.x, k = threadIdx.x;
  if (b < 512) {
    const float* wrow = ca_wqkv + (size_t)(256 + b) * 256;
    float s = 0.f;
    for (int c = 0; c < 256; ++c) s += wrow[c] * ip_w[c * 256 + k];
    Wkv[b * 256 + k] = f2bf(s);
    if (k == 0) {
      float sb = 0.f;
      for (int c = 0; c < 256; ++c) sb += wrow[c] * ip_b[c];
      bkv[b] = sb + ca_bqkv[256 + b];
    }
  } else {
    int i = b - 512;
    const float* worow = sa_wo + (size_t)i * 256;
    float s = 0.f;
    for (int c = 0; c < 256; ++c) s += worow[c] * sa_wqkv[(512 + c) * 256 + k];
    Wsa[i * 256 + k] = f2bf(s);
    if (k == 0) {
      float sb = 0.f;
      for (int c = 0; c < 256; ++c) sb += worow[c] * sa_bqkv[512 + c];
      bsa[i] = sb + sa_bo[i];
    }
  }
}

// ---------------------------------------------------------------------------
// gemm128<T>: 128x128 tile, pure GLD16 staging (m97 structure)
// T0: C bf16 = acc + bias (grid (mx,ny))
// T1: dec recon loss, linear grid 3136, XCD-swizzled, n-groups of 8 m-blocks
// T2: enc split-K 32 -> per-split partial buffer, linear grid 1024, swizzled;
//     slices 0-15 in Cv, 16-31 in loss (2nd partial bank)
// ---------------------------------------------------------------------------
template<int T>
__global__ __launch_bounds__(256) void gemm128(
    const unsigned short* __restrict__ A, int lda,
    const unsigned short* __restrict__ Bw, int ldb,
    const float* __restrict__ bias, void* __restrict__ Cv, int ldc, int K,
    const unsigned int* __restrict__ xmask, float* __restrict__ loss, int Nvalid)
{
  __shared__ __align__(16) unsigned short As[128 * 32];
  __shared__ __align__(16) unsigned short Bs[128 * 32];
  __shared__ unsigned int msk[128][4];
  __shared__ float red[4];
  const int tid = threadIdx.x;
  int m0, n0, kb = 0, kc = 0, iters;
  if (T == 2) {
    // 1024 blocks: g = n + 4*kc (128 groups); same-g => same XCD (id%8 const)
    int id = blockIdx.x;
    int g = (id & 7) + 8 * (id >> 6);
    m0 = ((id >> 3) & 7) * 128;
    n0 = (g & 3) * 128;
    kc = g >> 2;                       // 32 k-splits
    kb = kc * 1568;
    iters = 49;
  } else if (T == 1) {
    // 3136 blocks: group = n-tile (391 used); 8 m-blocks per group on one XCD
    int id = blockIdx.x;
    int n = (id & 7) + 8 * (id >> 6);
    if (n >= 391) return;
    m0 = ((id >> 3) & 7) * 128;
    n0 = n * 128;
    iters = 16;
  } else {
    m0 = blockIdx.x * 128; n0 = blockIdx.y * 128;
    iters = K >> 5;
  }
  const int w = tid >> 6, l = tid & 63;
  const int wm = (w >> 1) * 64, wn = (w & 1) * 64;
  const int fr = l & 15, fo = (l >> 4) * 8;
  const int s0 = tid, s1 = tid + 256;
  f32x4 acc[4][4] = {};
  for (int it = 0; it < iters; ++it) {
    int k0 = kb + it * 32;
    __syncthreads();
    GLD16(A  + (size_t)(m0 + (s0 >> 2)) * lda + k0 + (s0 & 3) * 8, &As[s0 * 8]);
    GLD16(A  + (size_t)(m0 + (s1 >> 2)) * lda + k0 + (s1 & 3) * 8, &As[s1 * 8]);
    GLD16(Bw + (size_t)(n0 + (s0 >> 2)) * ldb + k0 + (s0 & 3) * 8, &Bs[s0 * 8]);
    GLD16(Bw + (size_t)(n0 + (s1 >> 2)) * ldb + k0 + (s1 & 3) * 8, &Bs[s1 * 8]);
    __syncthreads();
    const unsigned short *ap[4], *bp[4];
#pragma unroll
    for (int i = 0; i < 4; ++i) {
      ap[i] = &As[(wm + 16 * i + fr) * 32 + fo];
      bp[i] = &Bs[(wn + 16 * i + fr) * 32 + fo];
    }
#pragma unroll
    for (int i = 0; i < 4; ++i)
#pragma unroll
      for (int j = 0; j < 4; ++j)
        acc[i][j] = mfma16(ap[i], bp[j], acc[i][j]);
  }
  const int cr = (l >> 4) * 4, cc = l & 15;
  if (T == 0) {
    unsigned short* Cb = (unsigned short*)Cv;
#pragma unroll
    for (int j = 0; j < 4; ++j) {
      int n = n0 + wn + 16 * j + cc;
      float bv = bias[n];
#pragma unroll
      for (int i = 0; i < 4; ++i)
#pragma unroll
        for (int r = 0; r < 4; ++r) {
          int m = m0 + wm + 16 * i + cr + r;
          Cb[(size_t)m * ldc + n] = f2bf(acc[i][j][r] + bv);
        }
    }
  } else if (T == 2) {
    // slices 0-15 in bank0 (Cv), 16-31 in bank1 (loss param)
    float* Cp = ((kc < 16) ? (float*)Cv : loss) + (size_t)(kc & 15) * 524288;
#pragma unroll
    for (int i = 0; i < 4; ++i)
#pragma unroll
      for (int j = 0; j < 4; ++j) {
        int n = n0 + wn + 16 * j + cc;
#pragma unroll
        for (int r = 0; r < 4; ++r) {
          int m = m0 + wm + 16 * i + cr + r;
          Cp[(size_t)m * 512 + n] = acc[i][j][r];
        }
      }
  } else {
    // stage this block's mask tile: 128 rows x 4 words
    {
      int row = tid >> 1, p = tid & 1;
      *(uint2*)&msk[row][p * 2] =
          *(const uint2*)(xmask + (size_t)(m0 + row) * MW + (n0 >> 5) + p * 2);
    }
    __syncthreads();
    float ts = 0.f;
#pragma unroll
    for (int j = 0; j < 4; ++j) {
      int nl = wn + 16 * j + cc;
      int n = n0 + nl;
      if (n < Nvalid) {
        float bv = bias[n];
#pragma unroll
        for (int i = 0; i < 4; ++i)
#pragma unroll
          for (int r = 0; r < 4; ++r) {
            int ml = wm + 16 * i + cr + r;
            float lg = acc[i][j][r] + bv;
            float sp = fmaxf(lg, 0.f) + __logf(1.f + __expf(-fabsf(lg)));
            unsigned word = msk[ml][nl >> 5];
            ts += sp - (((word >> (nl & 31)) & 1u) ? lg : 0.f);
          }
      }
    }
    for (int off = 32; off > 0; off >>= 1) ts += __shfl_xor(ts, off);
    if (l == 0) red[w] = ts;
    __syncthreads();
    if (tid == 0) atomicAdd(loss, red[0] + red[1] + red[2] + red[3]);
  }
}

// ---------------------------------------------------------------------------
// gemm64<EPI>: 64x64 tile GLD16 bf16 GEMM for the mid-chain
// EPI 0: f32 = acc+bias       1: bf16         2: gelu->bf16
//     3: z0 triple-write (z0f, z0b, ztb)      4: +te -> bf16 (qp)
//     5: ff2: +h2b residual, (v - z0f)^2 -> atomic loss
// ---------------------------------------------------------------------------
template<int EPI>
__global__ __launch_bounds__(256) void gemm64(
    const unsigned short* __restrict__ A, int lda,
    const unsigned short* __restrict__ Bw, int ldb,
    const float* __restrict__ bias, void* __restrict__ Cv, int ldc, int K,
    const void* __restrict__ R0, const void* __restrict__ R1, const void* __restrict__ R2,
    void* __restrict__ W0, void* __restrict__ W1, float* __restrict__ loss)
{
  __shared__ __align__(16) unsigned short As[64 * 32];
  __shared__ __align__(16) unsigned short Bs[64 * 32];
  __shared__ float red[4];
  const int tid = threadIdx.x;
  const int m0 = blockIdx.x * 64, n0 = blockIdx.y * 64;
  const int w = tid >> 6, l = tid & 63;
  const int wm = (w >> 1) * 32, wn = (w & 1) * 32;
  const int fr = l & 15, fo = (l >> 4) * 8;
  const int srow = tid >> 2, scol = (tid & 3) * 8;
  f32x4 acc[2][2] = {};
  for (int k0 = 0; k0 < K; k0 += 32) {
    __syncthreads();
    GLD16(A  + (size_t)(m0 + srow) * lda + k0 + scol, &As[tid * 8]);
    GLD16(Bw + (size_t)(n0 + srow) * ldb + k0 + scol, &Bs[tid * 8]);
    __syncthreads();
    const unsigned short* ap0 = &As[(wm +      fr) * 32 + fo];
    const unsigned short* ap1 = &As[(wm + 16 + fr) * 32 + fo];
    const unsigned short* bp0 = &Bs[(wn +      fr) * 32 + fo];
    const unsigned short* bp1 = &Bs[(wn + 16 + fr) * 32 + fo];
    acc[0][0] = mfma16(ap0, bp0, acc[0][0]);
    acc[0][1] = mfma16(ap0, bp1, acc[0][1]);
    acc[1][0] = mfma16(ap1, bp0, acc[1][0]);
    acc[1][1] = mfma16(ap1, bp1, acc[1][1]);
  }
  const int cr = (l >> 4) * 4, cc = l & 15;
  float ts = 0.f;
#pragma unroll
  for (int i = 0; i < 2; ++i)
#pragma unroll
    for (int j = 0; j < 2; ++j) {
      int n = n0 + wn + 16 * j + cc;
      float bv = bias[n];
#pragma unroll
      for (int r = 0; r < 4; ++r) {
        int m = m0 + wm + 16 * i + cr + r;
        float v = acc[i][j][r] + bv;
        size_t idx = (size_t)m * ldc + n;
        if (EPI == 0) ((float*)Cv)[idx] = v;
        if (EPI == 1) ((unsigned short*)Cv)[idx] = f2bf(v);
        if (EPI == 2) ((unsigned short*)Cv)[idx] = f2bf(gelu_f(v));
        if (EPI == 3) {
          ((float*)Cv)[idx] = v;
          ((unsigned short*)W0)[idx] = f2bf(v);
          float zt = ((const float*)R1)[m] * v +
                     ((const float*)R2)[m] * ((const float*)R0)[idx];
          ((unsigned short*)W1)[idx] = f2bf(zt);
        }
        if (EPI == 4) {
          v += ((const float*)R0)[idx];
          ((unsigned short*)Cv)[idx] = f2bf(v);
        }
        if (EPI == 5) {
          v += bf2f(((const unsigned short*)R0)[idx]);
          float d = v - ((const float*)R1)[idx];
          ts += d * d;
        }
      }
    }
  if (EPI == 5) {
    for (int off = 32; off > 0; off >>= 1) ts += __shfl_xor(ts, off);
    if (l == 0) red[w] = ts;
    __syncthreads();
    if (tid == 0) atomicAdd(loss, red[0] + red[1] + red[2] + red[3]);
  }
}

// H1b = gelu(sum_k P0[k]+P1[k] + enc_b1) -> bf16, 1024x512; 32-slice reduce
__global__ __launch_bounds__(256) void h1_epi(const float* __restrict__ P0,
                                              const float* __restrict__ P1,
                                              const float* __restrict__ b,
                                              unsigned short* __restrict__ H) {
  int i = blockIdx.x * 256 + threadIdx.x;
  float s = b[i & 511];
#pragma unroll
  for (int k = 0; k < 16; ++k) s += P0[(size_t)k * 524288 + i];
#pragma unroll
  for (int k = 0; k < 16; ++k) s += P1[(size_t)k * 524288 + i];
  H[i] = f2bf(gelu_f(s));
}

// te row + per-row schedule scalars
__global__ __launch_bounds__(256) void prep_te(
    const int* __restrict__ t,
    const float* __restrict__ te_w1, const float* __restrict__ te_b1,
    const float* __restrict__ te_w2, const float* __restrict__ te_b2,
    float* __restrict__ te, float* __restrict__ sab, float* __restrict__ s1ab)
{
  __shared__ float sj[32];
  int b = blockIdx.x, d = threadIdx.x;
  int ti = t[b];
  float tn = (float)ti / (float)Tt;
  if (d < 32) {
    float a = tn * te_w1[d] + te_b1[d];
    sj[d] = a / (1.f + __expf(-a));
  }
  if (d == 0) {
    double tt = (double)(ti + 1) / (double)Tt;
    double c  = cos((tt + 0.008) / 1.008 * M_PI * 0.5);
    double c0 = cos((0.008) / 1.008 * M_PI * 0.5);
    double ab = (c * c) / (c0 * c0);
    sab[b]  = (float)sqrt(ab);
    s1ab[b] = (float)sqrt(1.0 - ab);
  }
  __syncthreads();
  float accv = te_b2[d];
#pragma unroll
  for (int j = 0; j < 32; ++j) accv += sj[j] * te_w2[d * 32 + j];
  te[(size_t)b * 256 + d] = accv;
}

// gather neighbors -> bf16
__global__ __launch_bounds__(256) void gather_nb(
    const int* __restrict__ uid, const int* __restrict__ nidx,
    const float* __restrict__ emb, unsigned short* __restrict__ nb)
{
  int b = blockIdx.x, j = blockIdx.y, d = threadIdx.x;
  int idx = nidx[uid[b] * 20 + j];
  nb[((size_t)b * 20 + j) * 256 + d] = f2bf(emb[(size_t)idx * 256 + d]);
}

// cross-attention core: 20 keys, one wave per (b, head); kvh bf16
__global__ __launch_bounds__(256) void attn_k(
    const float* __restrict__ qh, const unsigned short* __restrict__ kvh,
    unsigned short* __restrict__ o)
{
  int b = blockIdx.x, tid = threadIdx.x;
  int h = tid >> 6, d = tid & 63;
  float qv = qh[(size_t)b * 256 + h * 64 + d];
  const unsigned short* kbase = kvh + (size_t)b * 20 * 512 + h * 64 + d;
  const unsigned short* vbase = kbase + 256;
  float s[20];
#pragma unroll
  for (int k = 0; k < 20; ++k) {
    float p = qv * bf2f(kbase[k * 512]);
    for (int off = 32; off > 0; off >>= 1) p += __shfl_xor(p, off);
    s[k] = p * 0.125f;
  }
  float mx = s[0];
#pragma unroll
  for (int k = 1; k < 20; ++k) mx = fmaxf(mx, s[k]);
  float sum = 0.f;
#pragma unroll
  for (int k = 0; k < 20; ++k) { s[k] = __expf(s[k] - mx); sum += s[k]; }
  float inv = 1.f / sum;
  float ov = 0.f;
#pragma unroll
  for (int k = 0; k < 20; ++k) ov += s[k] * bf2f(vbase[k * 512]);
  o[(size_t)b * 256 + h * 64 + d] = f2bf(ov * inv);
}

// LayerNorm(X + Y), bf16 in/out
__global__ __launch_bounds__(256) void ln_k(
    const unsigned short* __restrict__ X, const unsigned short* __restrict__ Y,
    const float* __restrict__ g, const float* __restrict__ bb,
    unsigned short* __restrict__ out)
{
  __shared__ float rs[4], rs2[4];
  int b = blockIdx.x, d = threadIdx.x;
  size_t i = (size_t)b * 256 + d;
  float v = bf2f(X[i]) + bf2f(Y[i]);
  float s = v, s2 = v * v;
  for (int off = 32; off > 0; off >>= 1) { s += __shfl_xor(s, off); s2 += __shfl_xor(s2, off); }
  int w = d >> 6, l = d & 63;
  if (l == 0) { rs[w] = s; rs2[w] = s2; }
  __syncthreads();
  s  = rs[0] + rs[1] + rs[2] + rs[3];
  s2 = rs2[0] + rs2[1] + rs2[2] + rs2[3];
  float mean = s * (1.f / 256.f);
  float var  = s2 * (1.f / 256.f) - mean * mean;
  out[i] = f2bf((v - mean) * rsqrtf(var + 1e-5f) * g[d] + bb[d]);
}

__global__ void final_k(const float* __restrict__ scal, float* __restrict__ out) {
  out[0] = scal[0] * (1.f / (1024.f * 256.f)) + 0.1f * scal[1] * (1.f / (1024.f * 50000.f));
}

// ---------------------------------------------------------------------------
extern "C" void kernel_launch(void* const* d_in, const int* in_sizes, int n_in,
                              void* d_out, int out_size, void* d_ws, size_t ws_size,
                              hipStream_t stream) {
  const float* x0      = (const float*)d_in[0];
  const int*   uid     = (const int*)  d_in[1];
  const int*   t       = (const int*)  d_in[2];
  const float* noise   = (const float*)d_in[3];
  const int*   nidx    = (const int*)  d_in[4];
  const float* item_emb= (const float*)d_in[5];
  const float* enc_w1  = (const float*)d_in[6];
  const float* enc_b1  = (const float*)d_in[7];
  const float* enc_w2  = (const float*)d_in[8];
  const float* enc_b2  = (const float*)d_in[9];
  const float* dec_w1  = (const float*)d_in[10];
  const float* dec_b1  = (const float*)d_in[11];
  const float* dec_w2  = (const float*)d_in[12];
  const float* dec_b2  = (const float*)d_in[13];
  const float* up_w    = (const float*)d_in[14];
  const float* up_b    = (const float*)d_in[15];
  const float* ip_w    = (const float*)d_in[16];
  const float* ip_b    = (const float*)d_in[17];
  const float* te_w1   = (const float*)d_in[18];
  const float* te_b1   = (const float*)d_in[19];
  const float* te_w2   = (const float*)d_in[20];
  const float* te_b2   = (const float*)d_in[21];
  const float* ca_wqkv = (const float*)d_in[22];
  const float* ca_bqkv = (const float*)d_in[23];
  const float* ca_wo   = (const float*)d_in[24];
  const float* ca_bo   = (const float*)d_in[25];
  const float* sa_wqkv = (const float*)d_in[26];
  const float* sa_bqkv = (const float*)d_in[27];
  const float* sa_wo   = (const float*)d_in[28];
  const float* sa_bo   = (const float*)d_in[29];
  const float* n1_g    = (const float*)d_in[30];
  const float* n1_b    = (const float*)d_in[31];
  const float* n2_g    = (const float*)d_in[32];
  const float* n2_b    = (const float*)d_in[33];
  const float* ff_w1   = (const float*)d_in[34];
  const float* ff_b1   = (const float*)d_in[35];
  const float* ff_w2   = (const float*)d_in[36];
  const float* ff_b2   = (const float*)d_in[37];
  (void)in_sizes; (void)n_in; (void)out_size; (void)ws_size;

  float* ws   = (float*)d_ws;
  float* scal = ws;                    // 4 (diff, recon)
  float* sab  = ws + 4;                // 1024
  float* s1ab = sab + 1024;
  float* te   = s1ab + 1024;           // 1024*256
  float* qhf  = te + 262144;           // 1024*256
  float* z0f  = qhf + 262144;          // 1024*256
  float* bkv  = z0f + 262144;          // 512
  float* bsa  = bkv + 512;             // 256
  unsigned int* xmask = (unsigned int*)(bsa + 256);           // 1024*MW
  // P-pool bank0: slices 0-15 (16 x 1024x512 f32 = 33,554,432 B) aliases
  // exactly [nbb | kvhb | f1b | Gb] (same byte size) — written post-h1_epi
  unsigned short* sh  = (unsigned short*)(xmask + 1024 * MW);
  float*          OUTp = (float*)sh;                          // 8,388,608 f32
  unsigned short* nbb  = sh;                                  // 20480*256
  unsigned short* kvhb = nbb + 5242880;                       // 20480*512
  unsigned short* f1b  = kvhb + 10485760;                     // 1024*512
  unsigned short* Gb   = f1b + 524288;                        // 1024*512
  unsigned short* x0b  = Gb + 524288;                         // 1024*KP (aliased w2n)
  unsigned short* w2n  = x0b;                                 // NPAD*512 <= x0b size
  unsigned short* w1b  = x0b + (size_t)1024 * KP;             // 512*KP
  unsigned short* H1b  = w1b + (size_t)512 * KP;              // 1024*512
  unsigned short* z0b  = H1b + 524288;
  unsigned short* ztb  = z0b + 262144;
  unsigned short* qpb  = ztb + 262144;
  unsigned short* ob   = qpb + 262144;
  unsigned short* cab  = ob  + 262144;
  unsigned short* hb   = cab + 262144;
  unsigned short* saob = hb  + 262144;
  unsigned short* h2b  = saob+ 262144;
  unsigned short* enc_w2b = h2b + 262144;                     // 131072
  unsigned short* up_wb   = enc_w2b + 131072;
  unsigned short* ca_wqb  = up_wb + 65536;
  unsigned short* ca_wob  = ca_wqb + 65536;
  unsigned short* ff_w1b  = ca_wob + 65536;
  unsigned short* ff_w2b  = ff_w1b + 131072;
  unsigned short* dec_w1b = ff_w2b + 131072;
  unsigned short* Wkv     = dec_w1b + 131072;
  unsigned short* Wsab    = Wkv + 131072;
  // P-pool bank1: slices 16-31, fresh tail region (33,554,432 B)
  float*          OUTp2   = (float*)(Wsab + 131072);          // 8,388,608 f32

  hipMemsetAsync(scal, 0, 4 * sizeof(float), stream);

  // independent prep
  prep_te<<<1024, 256, 0, stream>>>(t, te_w1, te_b1, te_w2, te_b2, te, sab, s1ab);
  bm_expand<<<dim3(25, 1024), 256, 0, stream>>>(x0, xmask, x0b);
  cvt_w1<<<dim3(25, 512), 256, 0, stream>>>(enc_w1, w1b);
  cvt_many<<<dim3(64, 7), 256, 0, stream>>>(enc_w2, up_w, ca_wqkv, ca_wo, ff_w1, ff_w2, dec_w1,
                                            enc_w2b, up_wb, ca_wqb, ca_wob, ff_w1b, ff_w2b, dec_w1b);
  compose_k<<<768, 256, 0, stream>>>(ca_wqkv, ca_bqkv, ip_w, ip_b,
                                     sa_wqkv, sa_bqkv, sa_wo, sa_bo,
                                     Wkv, bkv, Wsab, bsa);

  // encoder big GEMM: split-K 32 -> private partial slices (no atomics),
  // 1024 blocks = 4 blocks/CU, XCD-swizzled; bank1 passed via loss param
  gemm128<2><<<1024, 256, 0, stream>>>(
      x0b, KP, w1b, KP, nullptr, OUTp, 512, 1568, nullptr, OUTp2, 0);
  h1_epi<<<2048, 256, 0, stream>>>(OUTp, OUTp2, enc_b1, H1b);  // OUTp dead after

  // reuse x0b region for dec_w2 bf16 (x0b dead after enc GEMM)
  cvt_w2n<<<12500, 256, 0, stream>>>(dec_w2, w2n);

  // kv path (P-pool bank0 live again: OUTp dead)
  gather_nb<<<dim3(1024, 20), 256, 0, stream>>>(uid, nidx, item_emb, nbb);
  gemm128<0><<<dim3(160, 4), 256, 0, stream>>>(
      nbb, 256, Wkv, 256, bkv, kvhb, 512, 256, nullptr, nullptr, 0);

  // z0 GEMM + fused z_t
  gemm64<3><<<dim3(16, 4), 256, 0, stream>>>(
      H1b, 512, enc_w2b, 512, enc_b2, z0f, 256, 512, noise, sab, s1ab, z0b, ztb, nullptr);

  // q path
  gemm64<4><<<dim3(16, 4), 256, 0, stream>>>(
      ztb, 256, up_wb, 256, up_b, qpb, 256, 256, te, nullptr, nullptr, nullptr, nullptr, nullptr);
  gemm64<0><<<dim3(16, 4), 256, 0, stream>>>(
      qpb, 256, ca_wqb, 256, ca_bqkv, qhf, 256, 256,
      nullptr, nullptr, nullptr, nullptr, nullptr, nullptr);

  // attention + out-proj + LN1
  attn_k<<<1024, 256, 0, stream>>>(qhf, kvhb, ob);
  gemm64<1><<<dim3(16, 4), 256, 0, stream>>>(
      ob, 256, ca_wob, 256, ca_bo, cab, 256, 256,
      nullptr, nullptr, nullptr, nullptr, nullptr, nullptr);
  ln_k<<<1024, 256, 0, stream>>>(qpb, cab, n1_g, n1_b, hb);

  // self-attn (seq=1, composed) + LN2
  gemm64<1><<<dim3(16, 4), 256, 0, stream>>>(
      hb, 256, Wsab, 256, bsa, saob, 256, 256,
      nullptr, nullptr, nullptr, nullptr, nullptr, nullptr);
  ln_k<<<1024, 256, 0, stream>>>(hb, saob, n2_g, n2_b, h2b);

  // FF with fused residual + diffusion loss
  gemm64<2><<<dim3(16, 8), 256, 0, stream>>>(
      h2b, 256, ff_w1b, 256, ff_b1, f1b, 512, 256,
      nullptr, nullptr, nullptr, nullptr, nullptr, nullptr);
  gemm64<5><<<dim3(16, 4), 256, 0, stream>>>(
      f1b, 512, ff_w2b, 512, ff_b2, nullptr, 256, 512,
      h2b, z0f, nullptr, nullptr, nullptr, &scal[0]);

  // decoder: G = gelu(z0@dec_w1^T+b) bf16, then big GEMM + fused recon loss
  gemm64<2><<<dim3(16, 8), 256, 0, stream>>>(
      z0b, 256, dec_w1b, 256, dec_b1, Gb, 512, 256,
      nullptr, nullptr, nullptr, nullptr, nullptr, nullptr);
  gemm128<1><<<3136, 256, 0, stream>>>(
      Gb, 512, w2n, 512, dec_b2, nullptr, 0, 512, xmask, &scal[1], NI);

  final_k<<<1, 1, 0, stream>>>(scal, (float*)d_out);
}

// Round 2
// 910.987 us; speedup vs baseline: 1.0092x; 1.0092x over previous
//
#include <hip/hip_runtime.h>
#include <math.h>

#define NI   50000
#define Tt   1000
#define KP   50176              // 50000 padded: 32 chunks x 1568 (=49*32)
#define MW   1568               // mask words per row (KP/32)
#define NPAD 50048              // 391*128 n-pad for dec gemm

typedef __bf16 bf16x8 __attribute__((ext_vector_type(8)));
typedef float  f32x4  __attribute__((ext_vector_type(4)));

__device__ __forceinline__ unsigned short f2bf(float f) {
  unsigned u = __float_as_uint(f);
  u += 0x7FFFu + ((u >> 16) & 1u);   // RNE
  return (unsigned short)(u >> 16);
}
__device__ __forceinline__ float bf2f(unsigned short u) {
  return __uint_as_float(((unsigned)u) << 16);
}
__device__ __forceinline__ unsigned pack2(float a, float b) {
  return (unsigned)f2bf(a) | ((unsigned)f2bf(b) << 16);
}
__device__ __forceinline__ f32x4 mfma16(const unsigned short* a, const unsigned short* b, f32x4 c) {
  typedef unsigned short u16x8 __attribute__((ext_vector_type(8)));
  u16x8 av = *(const u16x8*)a;
  u16x8 bv = *(const u16x8*)b;
  return __builtin_amdgcn_mfma_f32_16x16x32_bf16(
      __builtin_bit_cast(bf16x8, av), __builtin_bit_cast(bf16x8, bv), c, 0, 0, 0);
}
__device__ __forceinline__ float gelu_f(float x) {
  return 0.5f * x * (1.f + erff(x * 0.70710678118654752f));
}

#define GLD16(gsrc, ldst) __builtin_amdgcn_global_load_lds( \
    (const __attribute__((address_space(1))) unsigned int*)(const void*)(gsrc), \
    (__attribute__((address_space(3))) unsigned int*)(void*)(ldst), 16, 0, 0)

// counted-vmcnt pipeline fences (T3/T4: loads stay in flight across barriers)
#define PIPE_FENCE() __builtin_amdgcn_sched_barrier(0)
#define RAW_BAR()    __builtin_amdgcn_s_barrier()

// ---------------------------------------------------------------------------
// bm_expand: x0 f32 -> xmask bits + x0b bf16 {0,1}; one barrier per block
// grid (25, 1024): y = row, x = 2048-elem chunk
// ---------------------------------------------------------------------------
__global__ __launch_bounds__(256) void bm_expand(
    const float* __restrict__ x0, unsigned int* __restrict__ xmask,
    unsigned short* __restrict__ x0b)
{
  __shared__ unsigned int nib[256];
  int r = blockIdx.y, tid = threadIdx.x;
  int c0 = blockIdx.x * 2048;
  int k = c0 + tid * 8;
  const float* row = x0 + (size_t)r * NI;
  float4 a = make_float4(0.f, 0.f, 0.f, 0.f), b = a;
  if (k + 8 <= NI) {                   // NI % 8 == 0
    a = *(const float4*)(row + k);
    b = *(const float4*)(row + k + 4);
  }
  uint4 o;
  o.x = (a.x != 0.f ? 0x3F80u : 0u) | (a.y != 0.f ? 0x3F800000u : 0u);
  o.y = (a.z != 0.f ? 0x3F80u : 0u) | (a.w != 0.f ? 0x3F800000u : 0u);
  o.z = (b.x != 0.f ? 0x3F80u : 0u) | (b.y != 0.f ? 0x3F800000u : 0u);
  o.w = (b.z != 0.f ? 0x3F80u : 0u) | (b.w != 0.f ? 0x3F800000u : 0u);
  if (k < KP) *(uint4*)(x0b + (size_t)r * KP + k) = o;
  unsigned bits8 =
      (a.x != 0.f ? 1u : 0u)  | (a.y != 0.f ? 2u : 0u)  |
      (a.z != 0.f ? 4u : 0u)  | (a.w != 0.f ? 8u : 0u)  |
      (b.x != 0.f ? 16u : 0u) | (b.y != 0.f ? 32u : 0u) |
      (b.z != 0.f ? 64u : 0u) | (b.w != 0.f ? 128u : 0u);
  nib[tid] = bits8;
  __syncthreads();
  if (tid < 64) {
    unsigned wv = nib[tid * 4] | (nib[tid * 4 + 1] << 8) |
                  (nib[tid * 4 + 2] << 16) | (nib[tid * 4 + 3] << 24);
    int widx = (c0 >> 5) + tid;
    if (widx < MW) xmask[(size_t)r * MW + widx] = wv;
  }
}

// enc_w1 (512 x 50000 f32) -> bf16 (512 x KP), k-pad zeroed
__global__ __launch_bounds__(256) void cvt_w1(const float* __restrict__ src,
                                              unsigned short* __restrict__ dst) {
  int c = blockIdx.x * 2048 + threadIdx.x * 8;
  if (c >= KP) return;
  int r = blockIdx.y;
  const float* s = src + (size_t)r * NI;
  uint4 o;
  if (c + 8 <= NI) {
    float4 a = *(const float4*)(s + c), b = *(const float4*)(s + c + 4);
    o.x = pack2(a.x, a.y); o.y = pack2(a.z, a.w);
    o.z = pack2(b.x, b.y); o.w = pack2(b.z, b.w);
  } else {
    float v[8];
#pragma unroll
    for (int i = 0; i < 8; ++i) v[i] = (c + i < NI) ? s[c + i] : 0.f;
    o.x = pack2(v[0], v[1]); o.y = pack2(v[2], v[3]);
    o.z = pack2(v[4], v[5]); o.w = pack2(v[6], v[7]);
  }
  *(uint4*)(dst + (size_t)r * KP + c) = o;
}

// dec_w2 (50000 x 512 f32) -> bf16 straight cvt
__global__ __launch_bounds__(256) void cvt_w2n(const float* __restrict__ src,
                                               unsigned short* __restrict__ dst) {
  size_t idx = ((size_t)blockIdx.x * 256 + threadIdx.x) * 8;   // 12500 blocks exact
  float4 a = *(const float4*)(src + idx), b = *(const float4*)(src + idx + 4);
  uint4 o;
  o.x = pack2(a.x, a.y); o.y = pack2(a.z, a.w);
  o.z = pack2(b.x, b.y); o.w = pack2(b.z, b.w);
  *(uint4*)(dst + idx) = o;
}

// batch-convert 7 small weights f32->bf16
__global__ __launch_bounds__(256) void cvt_many(
    const float* s0, const float* s1, const float* s2, const float* s3,
    const float* s4, const float* s5, const float* s6,
    unsigned short* d0, unsigned short* d1, unsigned short* d2, unsigned short* d3,
    unsigned short* d4, unsigned short* d5, unsigned short* d6)
{
  const float* srcs[7] = {s0, s1, s2, s3, s4, s5, s6};
  unsigned short* dsts[7] = {d0, d1, d2, d3, d4, d5, d6};
  const int ns[7] = {131072, 65536, 65536, 65536, 131072, 131072, 131072};
  int j = blockIdx.y;
  int i = (blockIdx.x * 256 + threadIdx.x) * 8;
  if (i >= ns[j]) return;
  float4 a = *(const float4*)(srcs[j] + i), b = *(const float4*)(srcs[j] + i + 4);
  uint4 o;
  o.x = pack2(a.x, a.y); o.y = pack2(a.z, a.w);
  o.z = pack2(b.x, b.y); o.w = pack2(b.z, b.w);
  *(uint4*)(dsts[j] + i) = o;
}

// compose fused weights (kv-path and seq1-selfattn), bf16 outputs
__global__ __launch_bounds__(256) void compose_k(
    const float* __restrict__ ca_wqkv, const float* __restrict__ ca_bqkv,
    const float* __restrict__ ip_w, const float* __restrict__ ip_b,
    const float* __restrict__ sa_wqkv, const float* __restrict__ sa_bqkv,
    const float* __restrict__ sa_wo, const float* __restrict__ sa_bo,
    unsigned short* __restrict__ Wkv, float* __restrict__ bkv,
    unsigned short* __restrict__ Wsa, float* __restrict__ bsa)
{
  int b = blockIdx.x, k = threadIdx.x;
  if (b < 512) {
    const float* wrow = ca_wqkv + (size_t)(256 + b) * 256;
    float s = 0.f;
    for (int c = 0; c < 256; ++c) s += wrow[c] * ip_w[c * 256 + k];
    Wkv[b * 256 + k] = f2bf(s);
    if (k == 0) {
      float sb = 0.f;
      for (int c = 0; c < 256; ++c) sb += wrow[c] * ip_b[c];
      bkv[b] = sb + ca_bqkv[256 + b];
    }
  } else {
    int i = b - 512;
    const float* worow = sa_wo + (size_t)i * 256;
    float s = 0.f;
    for (int c = 0; c < 256; ++c) s += worow[c] * sa_wqkv[(512 + c) * 256 + k];
    Wsa[i * 256 + k] = f2bf(s);
    if (k == 0) {
      float sb = 0.f;
      for (int c = 0; c < 256; ++c) sb += worow[c] * sa_bqkv[512 + c];
      bsa[i] = sb + sa_bo[i];
    }
  }
}

// ---------------------------------------------------------------------------
// gemm128<T>: 128x128 tile, GLD16 staging, double-buffered counted-vmcnt
// pipeline (T3/T4: next tile's loads stay in flight across barriers).
// T0: C bf16 = acc + bias (grid (mx,ny))
// T1: dec recon loss, linear grid 3136, XCD-swizzled, n-groups of 8 m-blocks
// T2: enc split-K 32 -> per-split partial buffer, linear grid 1024, swizzled;
//     slices 0-15 in Cv, 16-31 in loss (2nd partial bank)
// ---------------------------------------------------------------------------
template<int T>
__global__ __launch_bounds__(256) void gemm128(
    const unsigned short* __restrict__ A, int lda,
    const unsigned short* __restrict__ Bw, int ldb,
    const float* __restrict__ bias, void* __restrict__ Cv, int ldc, int K,
    const unsigned int* __restrict__ xmask, float* __restrict__ loss, int Nvalid)
{
  __shared__ __align__(16) unsigned short As[2][128 * 32];
  __shared__ __align__(16) unsigned short Bs[2][128 * 32];
  __shared__ unsigned int msk[128][4];
  __shared__ float red[4];
  const int tid = threadIdx.x;
  int m0, n0, kb = 0, kc = 0, iters;
  if (T == 2) {
    // 1024 blocks: g = n + 4*kc (128 groups); same-g => same XCD (id%8 const)
    int id = blockIdx.x;
    int g = (id & 7) + 8 * (id >> 6);
    m0 = ((id >> 3) & 7) * 128;
    n0 = (g & 3) * 128;
    kc = g >> 2;                       // 32 k-splits
    kb = kc * 1568;
    iters = 49;
  } else if (T == 1) {
    // 3136 blocks: group = n-tile (391 used); 8 m-blocks per group on one XCD
    int id = blockIdx.x;
    int n = (id & 7) + 8 * (id >> 6);
    if (n >= 391) return;
    m0 = ((id >> 3) & 7) * 128;
    n0 = n * 128;
    iters = 16;
  } else {
    m0 = blockIdx.x * 128; n0 = blockIdx.y * 128;
    iters = K >> 5;
  }
  const int w = tid >> 6, l = tid & 63;
  const int wm = (w >> 1) * 64, wn = (w & 1) * 64;
  const int fr = l & 15, fo = (l >> 4) * 8;
  const int s0 = tid, s1 = tid + 256;
  // per-thread staging base pointers (k added per stage)
  const unsigned short* Ar0 = A  + (size_t)(m0 + (s0 >> 2)) * lda + (s0 & 3) * 8;
  const unsigned short* Ar1 = A  + (size_t)(m0 + (s1 >> 2)) * lda + (s1 & 3) * 8;
  const unsigned short* Br0 = Bw + (size_t)(n0 + (s0 >> 2)) * ldb + (s0 & 3) * 8;
  const unsigned short* Br1 = Bw + (size_t)(n0 + (s1 >> 2)) * ldb + (s1 & 3) * 8;
  f32x4 acc[4][4] = {};

#define STG128(IT, BUF) do { int kk_ = kb + (IT) * 32;        \
    GLD16(Ar0 + kk_, &As[BUF][s0 * 8]);                        \
    GLD16(Ar1 + kk_, &As[BUF][s1 * 8]);                        \
    GLD16(Br0 + kk_, &Bs[BUF][s0 * 8]);                        \
    GLD16(Br1 + kk_, &Bs[BUF][s1 * 8]); } while (0)

#define CMP128(BUF) do {                                       \
    const unsigned short *ap_[4], *bp_[4];                     \
    _Pragma("unroll") for (int i_ = 0; i_ < 4; ++i_) {         \
      ap_[i_] = &As[BUF][(wm + 16 * i_ + fr) * 32 + fo];       \
      bp_[i_] = &Bs[BUF][(wn + 16 * i_ + fr) * 32 + fo]; }     \
    _Pragma("unroll") for (int i_ = 0; i_ < 4; ++i_)           \
    _Pragma("unroll") for (int j_ = 0; j_ < 4; ++j_)           \
      acc[i_][j_] = mfma16(ap_[i_], bp_[j_], acc[i_][j_]); } while (0)

  // prologue: two stages in flight (iters >= 8 for all T)
  STG128(0, 0);
  STG128(1, 1);
  for (int it = 0; it < iters; it += 2) {
    // even iteration: buffer 0
    if (it + 1 < iters) asm volatile("s_waitcnt vmcnt(4)" ::: "memory");
    else                asm volatile("s_waitcnt vmcnt(0)" ::: "memory");
    PIPE_FENCE(); RAW_BAR(); PIPE_FENCE();
    CMP128(0);
    asm volatile("s_waitcnt lgkmcnt(0)" ::: "memory");
    PIPE_FENCE(); RAW_BAR(); PIPE_FENCE();
    if (it + 2 < iters) STG128(it + 2, 0);
    if (it + 1 >= iters) break;
    // odd iteration: buffer 1
    if (it + 2 < iters) asm volatile("s_waitcnt vmcnt(4)" ::: "memory");
    else                asm volatile("s_waitcnt vmcnt(0)" ::: "memory");
    PIPE_FENCE(); RAW_BAR(); PIPE_FENCE();
    CMP128(1);
    asm volatile("s_waitcnt lgkmcnt(0)" ::: "memory");
    PIPE_FENCE(); RAW_BAR(); PIPE_FENCE();
    if (it + 3 < iters) STG128(it + 3, 1);
  }
#undef STG128
#undef CMP128

  const int cr = (l >> 4) * 4, cc = l & 15;
  if (T == 0) {
    unsigned short* Cb = (unsigned short*)Cv;
#pragma unroll
    for (int j = 0; j < 4; ++j) {
      int n = n0 + wn + 16 * j + cc;
      float bv = bias[n];
#pragma unroll
      for (int i = 0; i < 4; ++i)
#pragma unroll
        for (int r = 0; r < 4; ++r) {
          int m = m0 + wm + 16 * i + cr + r;
          Cb[(size_t)m * ldc + n] = f2bf(acc[i][j][r] + bv);
        }
    }
  } else if (T == 2) {
    // slices 0-15 in bank0 (Cv), 16-31 in bank1 (loss param)
    float* Cp = ((kc < 16) ? (float*)Cv : loss) + (size_t)(kc & 15) * 524288;
#pragma unroll
    for (int i = 0; i < 4; ++i)
#pragma unroll
      for (int j = 0; j < 4; ++j) {
        int n = n0 + wn + 16 * j + cc;
#pragma unroll
        for (int r = 0; r < 4; ++r) {
          int m = m0 + wm + 16 * i + cr + r;
          Cp[(size_t)m * 512 + n] = acc[i][j][r];
        }
      }
  } else {
    // stage this block's mask tile: 128 rows x 4 words
    {
      int row = tid >> 1, p = tid & 1;
      *(uint2*)&msk[row][p * 2] =
          *(const uint2*)(xmask + (size_t)(m0 + row) * MW + (n0 >> 5) + p * 2);
    }
    __syncthreads();
    float ts = 0.f;
#pragma unroll
    for (int j = 0; j < 4; ++j) {
      int nl = wn + 16 * j + cc;
      int n = n0 + nl;
      if (n < Nvalid) {
        float bv = bias[n];
#pragma unroll
        for (int i = 0; i < 4; ++i)
#pragma unroll
          for (int r = 0; r < 4; ++r) {
            int ml = wm + 16 * i + cr + r;
            float lg = acc[i][j][r] + bv;
            float sp = fmaxf(lg, 0.f) + __logf(1.f + __expf(-fabsf(lg)));
            unsigned word = msk[ml][nl >> 5];
            ts += sp - (((word >> (nl & 31)) & 1u) ? lg : 0.f);
          }
      }
    }
    for (int off = 32; off > 0; off >>= 1) ts += __shfl_xor(ts, off);
    if (l == 0) red[w] = ts;
    __syncthreads();
    if (tid == 0) atomicAdd(loss, red[0] + red[1] + red[2] + red[3]);
  }
}

// ---------------------------------------------------------------------------
// gemm64<EPI>: 64x64 tile GLD16 bf16 GEMM, double-buffered counted-vmcnt
// EPI 0: f32 = acc+bias       1: bf16         2: gelu->bf16
//     3: z0 triple-write (z0f, z0b, ztb)      4: +te -> bf16 (qp)
//     5: ff2: +h2b residual, (v - z0f)^2 -> atomic loss
// ---------------------------------------------------------------------------
template<int EPI>
__global__ __launch_bounds__(256) void gemm64(
    const unsigned short* __restrict__ A, int lda,
    const unsigned short* __restrict__ Bw, int ldb,
    const float* __restrict__ bias, void* __restrict__ Cv, int ldc, int K,
    const void* __restrict__ R0, const void* __restrict__ R1, const void* __restrict__ R2,
    void* __restrict__ W0, void* __restrict__ W1, float* __restrict__ loss)
{
  __shared__ __align__(16) unsigned short As[2][64 * 32];
  __shared__ __align__(16) unsigned short Bs[2][64 * 32];
  __shared__ float red[4];
  const int tid = threadIdx.x;
  const int m0 = blockIdx.x * 64, n0 = blockIdx.y * 64;
  const int w = tid >> 6, l = tid & 63;
  const int wm = (w >> 1) * 32, wn = (w & 1) * 32;
  const int fr = l & 15, fo = (l >> 4) * 8;
  const int srow = tid >> 2, scol = (tid & 3) * 8;
  const unsigned short* Ar = A  + (size_t)(m0 + srow) * lda + scol;
  const unsigned short* Br = Bw + (size_t)(n0 + srow) * ldb + scol;
  const int iters = K >> 5;
  f32x4 acc[2][2] = {};

#define STG64(IT, BUF) do { int kk_ = (IT) * 32;               \
    GLD16(Ar + kk_, &As[BUF][tid * 8]);                        \
    GLD16(Br + kk_, &Bs[BUF][tid * 8]); } while (0)

#define CMP64(BUF) do {                                        \
    const unsigned short* a0_ = &As[BUF][(wm +      fr) * 32 + fo]; \
    const unsigned short* a1_ = &As[BUF][(wm + 16 + fr) * 32 + fo]; \
    const unsigned short* b0_ = &Bs[BUF][(wn +      fr) * 32 + fo]; \
    const unsigned short* b1_ = &Bs[BUF][(wn + 16 + fr) * 32 + fo]; \
    acc[0][0] = mfma16(a0_, b0_, acc[0][0]);                   \
    acc[0][1] = mfma16(a0_, b1_, acc[0][1]);                   \
    acc[1][0] = mfma16(a1_, b0_, acc[1][0]);                   \
    acc[1][1] = mfma16(a1_, b1_, acc[1][1]); } while (0)

  STG64(0, 0);
  STG64(1, 1);                         // iters >= 8 for all call sites
  for (int it = 0; it < iters; it += 2) {
    if (it + 1 < iters) asm volatile("s_waitcnt vmcnt(2)" ::: "memory");
    else                asm volatile("s_waitcnt vmcnt(0)" ::: "memory");
    PIPE_FENCE(); RAW_BAR(); PIPE_FENCE();
    CMP64(0);
    asm volatile("s_waitcnt lgkmcnt(0)" ::: "memory");
    PIPE_FENCE(); RAW_BAR(); PIPE_FENCE();
    if (it + 2 < iters) STG64(it + 2, 0);
    if (it + 1 >= iters) break;
    if (it + 2 < iters) asm volatile("s_waitcnt vmcnt(2)" ::: "memory");
    else                asm volatile("s_waitcnt vmcnt(0)" ::: "memory");
    PIPE_FENCE(); RAW_BAR(); PIPE_FENCE();
    CMP64(1);
    asm volatile("s_waitcnt lgkmcnt(0)" ::: "memory");
    PIPE_FENCE(); RAW_BAR(); PIPE_FENCE();
    if (it + 3 < iters) STG64(it + 3, 1);
  }
#undef STG64
#undef CMP64

  const int cr = (l >> 4) * 4, cc = l & 15;
  float ts = 0.f;
#pragma unroll
  for (int i = 0; i < 2; ++i)
#pragma unroll
    for (int j = 0; j < 2; ++j) {
      int n = n0 + wn + 16 * j + cc;
      float bv = bias[n];
#pragma unroll
      for (int r = 0; r < 4; ++r) {
        int m = m0 + wm + 16 * i + cr + r;
        float v = acc[i][j][r] + bv;
        size_t idx = (size_t)m * ldc + n;
        if (EPI == 0) ((float*)Cv)[idx] = v;
        if (EPI == 1) ((unsigned short*)Cv)[idx] = f2bf(v);
        if (EPI == 2) ((unsigned short*)Cv)[idx] = f2bf(gelu_f(v));
        if (EPI == 3) {
          ((float*)Cv)[idx] = v;
          ((unsigned short*)W0)[idx] = f2bf(v);
          float zt = ((const float*)R1)[m] * v +
                     ((const float*)R2)[m] * ((const float*)R0)[idx];
          ((unsigned short*)W1)[idx] = f2bf(zt);
        }
        if (EPI == 4) {
          v += ((const float*)R0)[idx];
          ((unsigned short*)Cv)[idx] = f2bf(v);
        }
        if (EPI == 5) {
          v += bf2f(((const unsigned short*)R0)[idx]);
          float d = v - ((const float*)R1)[idx];
          ts += d * d;
        }
      }
    }
  if (EPI == 5) {
    for (int off = 32; off > 0; off >>= 1) ts += __shfl_xor(ts, off);
    if (l == 0) red[w] = ts;
    __syncthreads();
    if (tid == 0) atomicAdd(loss, red[0] + red[1] + red[2] + red[3]);
  }
}

// H1b = gelu(sum_k P0[k]+P1[k] + enc_b1) -> bf16, 1024x512; 32-slice reduce
__global__ __launch_bounds__(256) void h1_epi(const float* __restrict__ P0,
                                              const float* __restrict__ P1,
                                              const float* __restrict__ b,
                                              unsigned short* __restrict__ H) {
  int i = blockIdx.x * 256 + threadIdx.x;
  float s = b[i & 511];
#pragma unroll
  for (int k = 0; k < 16; ++k) s += P0[(size_t)k * 524288 + i];
#pragma unroll
  for (int k = 0; k < 16; ++k) s += P1[(size_t)k * 524288 + i];
  H[i] = f2bf(gelu_f(s));
}

// te row + per-row schedule scalars
__global__ __launch_bounds__(256) void prep_te(
    const int* __restrict__ t,
    const float* __restrict__ te_w1, const float* __restrict__ te_b1,
    const float* __restrict__ te_w2, const float* __restrict__ te_b2,
    float* __restrict__ te, float* __restrict__ sab, float* __restrict__ s1ab)
{
  __shared__ float sj[32];
  int b = blockIdx.x, d = threadIdx.x;
  int ti = t[b];
  float tn = (float)ti / (float)Tt;
  if (d < 32) {
    float a = tn * te_w1[d] + te_b1[d];
    sj[d] = a / (1.f + __expf(-a));
  }
  if (d == 0) {
    double tt = (double)(ti + 1) / (double)Tt;
    double c  = cos((tt + 0.008) / 1.008 * M_PI * 0.5);
    double c0 = cos((0.008) / 1.008 * M_PI * 0.5);
    double ab = (c * c) / (c0 * c0);
    sab[b]  = (float)sqrt(ab);
    s1ab[b] = (float)sqrt(1.0 - ab);
  }
  __syncthreads();
  float accv = te_b2[d];
#pragma unroll
  for (int j = 0; j < 32; ++j) accv += sj[j] * te_w2[d * 32 + j];
  te[(size_t)b * 256 + d] = accv;
}

// gather neighbors -> bf16
__global__ __launch_bounds__(256) void gather_nb(
    const int* __restrict__ uid, const int* __restrict__ nidx,
    const float* __restrict__ emb, unsigned short* __restrict__ nb)
{
  int b = blockIdx.x, j = blockIdx.y, d = threadIdx.x;
  int idx = nidx[uid[b] * 20 + j];
  nb[((size_t)b * 20 + j) * 256 + d] = f2bf(emb[(size_t)idx * 256 + d]);
}

// cross-attention core: 20 keys, one wave per (b, head); kvh bf16
__global__ __launch_bounds__(256) void attn_k(
    const float* __restrict__ qh, const unsigned short* __restrict__ kvh,
    unsigned short* __restrict__ o)
{
  int b = blockIdx.x, tid = threadIdx.x;
  int h = tid >> 6, d = tid & 63;
  float qv = qh[(size_t)b * 256 + h * 64 + d];
  const unsigned short* kbase = kvh + (size_t)b * 20 * 512 + h * 64 + d;
  const unsigned short* vbase = kbase + 256;
  float s[20];
#pragma unroll
  for (int k = 0; k < 20; ++k) {
    float p = qv * bf2f(kbase[k * 512]);
    for (int off = 32; off > 0; off >>= 1) p += __shfl_xor(p, off);
    s[k] = p * 0.125f;
  }
  float mx = s[0];
#pragma unroll
  for (int k = 1; k < 20; ++k) mx = fmaxf(mx, s[k]);
  float sum = 0.f;
#pragma unroll
  for (int k = 0; k < 20; ++k) { s[k] = __expf(s[k] - mx); sum += s[k]; }
  float inv = 1.f / sum;
  float ov = 0.f;
#pragma unroll
  for (int k = 0; k < 20; ++k) ov += s[k] * bf2f(vbase[k * 512]);
  o[(size_t)b * 256 + h * 64 + d] = f2bf(ov * inv);
}

// LayerNorm(X + Y), bf16 in/out
__global__ __launch_bounds__(256) void ln_k(
    const unsigned short* __restrict__ X, const unsigned short* __restrict__ Y,
    const float* __restrict__ g, const float* __restrict__ bb,
    unsigned short* __restrict__ out)
{
  __shared__ float rs[4], rs2[4];
  int b = blockIdx.x, d = threadIdx.x;
  size_t i = (size_t)b * 256 + d;
  float v = bf2f(X[i]) + bf2f(Y[i]);
  float s = v, s2 = v * v;
  for (int off = 32; off > 0; off >>= 1) { s += __shfl_xor(s, off); s2 += __shfl_xor(s2, off); }
  int w = d >> 6, l = d & 63;
  if (l == 0) { rs[w] = s; rs2[w] = s2; }
  __syncthreads();
  s  = rs[0] + rs[1] + rs[2] + rs[3];
  s2 = rs2[0] + rs2[1] + rs2[2] + rs2[3];
  float mean = s * (1.f / 256.f);
  float var  = s2 * (1.f / 256.f) - mean * mean;
  out[i] = f2bf((v - mean) * rsqrtf(var + 1e-5f) * g[d] + bb[d]);
}

__global__ void final_k(const float* __restrict__ scal, float* __restrict__ out) {
  out[0] = scal[0] * (1.f / (1024.f * 256.f)) + 0.1f * scal[1] * (1.f / (1024.f * 50000.f));
}

// ---------------------------------------------------------------------------
extern "C" void kernel_launch(void* const* d_in, const int* in_sizes, int n_in,
                              void* d_out, int out_size, void* d_ws, size_t ws_size,
                              hipStream_t stream) {
  const float* x0      = (const float*)d_in[0];
  const int*   uid     = (const int*)  d_in[1];
  const int*   t       = (const int*)  d_in[2];
  const float* noise   = (const float*)d_in[3];
  const int*   nidx    = (const int*)  d_in[4];
  const float* item_emb= (const float*)d_in[5];
  const float* enc_w1  = (const float*)d_in[6];
  const float* enc_b1  = (const float*)d_in[7];
  const float* enc_w2  = (const float*)d_in[8];
  const float* enc_b2  = (const float*)d_in[9];
  const float* dec_w1  = (const float*)d_in[10];
  const float* dec_b1  = (const float*)d_in[11];
  const float* dec_w2  = (const float*)d_in[12];
  const float* dec_b2  = (const float*)d_in[13];
  const float* up_w    = (const float*)d_in[14];
  const float* up_b    = (const float*)d_in[15];
  const float* ip_w    = (const float*)d_in[16];
  const float* ip_b    = (const float*)d_in[17];
  const float* te_w1   = (const float*)d_in[18];
  const float* te_b1   = (const float*)d_in[19];
  const float* te_w2   = (const float*)d_in[20];
  const float* te_b2   = (const float*)d_in[21];
  const float* ca_wqkv = (const float*)d_in[22];
  const float* ca_bqkv = (const float*)d_in[23];
  const float* ca_wo   = (const float*)d_in[24];
  const float* ca_bo   = (const float*)d_in[25];
  const float* sa_wqkv = (const float*)d_in[26];
  const float* sa_bqkv = (const float*)d_in[27];
  const float* sa_wo   = (const float*)d_in[28];
  const float* sa_bo   = (const float*)d_in[29];
  const float* n1_g    = (const float*)d_in[30];
  const float* n1_b    = (const float*)d_in[31];
  const float* n2_g    = (const float*)d_in[32];
  const float* n2_b    = (const float*)d_in[33];
  const float* ff_w1   = (const float*)d_in[34];
  const float* ff_b1   = (const float*)d_in[35];
  const float* ff_w2   = (const float*)d_in[36];
  const float* ff_b2   = (const float*)d_in[37];
  (void)in_sizes; (void)n_in; (void)out_size; (void)ws_size;

  float* ws   = (float*)d_ws;
  float* scal = ws;                    // 4 (diff, recon)
  float* sab  = ws + 4;                // 1024
  float* s1ab = sab + 1024;
  float* te   = s1ab + 1024;           // 1024*256
  float* qhf  = te + 262144;           // 1024*256
  float* z0f  = qhf + 262144;          // 1024*256
  float* bkv  = z0f + 262144;          // 512
  float* bsa  = bkv + 512;             // 256
  unsigned int* xmask = (unsigned int*)(bsa + 256);           // 1024*MW
  // P-pool bank0: slices 0-15 (16 x 1024x512 f32 = 33,554,432 B) aliases
  // exactly [nbb | kvhb | f1b | Gb] (same byte size) — written post-h1_epi
  unsigned short* sh  = (unsigned short*)(xmask + 1024 * MW);
  float*          OUTp = (float*)sh;                          // 8,388,608 f32
  unsigned short* nbb  = sh;                                  // 20480*256
  unsigned short* kvhb = nbb + 5242880;                       // 20480*512
  unsigned short* f1b  = kvhb + 10485760;                     // 1024*512
  unsigned short* Gb   = f1b + 524288;                        // 1024*512
  unsigned short* x0b  = Gb + 524288;                         // 1024*KP (aliased w2n)
  unsigned short* w2n  = x0b;                                 // NPAD*512 <= x0b size
  unsigned short* w1b  = x0b + (size_t)1024 * KP;             // 512*KP
  unsigned short* H1b  = w1b + (size_t)512 * KP;              // 1024*512
  unsigned short* z0b  = H1b + 524288;
  unsigned short* ztb  = z0b + 262144;
  unsigned short* qpb  = ztb + 262144;
  unsigned short* ob   = qpb + 262144;
  unsigned short* cab  = ob  + 262144;
  unsigned short* hb   = cab + 262144;
  unsigned short* saob = hb  + 262144;
  unsigned short* h2b  = saob+ 262144;
  unsigned short* enc_w2b = h2b + 262144;                     // 131072
  unsigned short* up_wb   = enc_w2b + 131072;
  unsigned short* ca_wqb  = up_wb + 65536;
  unsigned short* ca_wob  = ca_wqb + 65536;
  unsigned short* ff_w1b  = ca_wob + 65536;
  unsigned short* ff_w2b  = ff_w1b + 131072;
  unsigned short* dec_w1b = ff_w2b + 131072;
  unsigned short* Wkv     = dec_w1b + 131072;
  unsigned short* Wsab    = Wkv + 131072;
  // P-pool bank1: slices 16-31, fresh tail region (33,554,432 B)
  float*          OUTp2   = (float*)(Wsab + 131072);          // 8,388,608 f32

  hipMemsetAsync(scal, 0, 4 * sizeof(float), stream);

  // independent prep
  prep_te<<<1024, 256, 0, stream>>>(t, te_w1, te_b1, te_w2, te_b2, te, sab, s1ab);
  bm_expand<<<dim3(25, 1024), 256, 0, stream>>>(x0, xmask, x0b);
  cvt_w1<<<dim3(25, 512), 256, 0, stream>>>(enc_w1, w1b);
  cvt_many<<<dim3(64, 7), 256, 0, stream>>>(enc_w2, up_w, ca_wqkv, ca_wo, ff_w1, ff_w2, dec_w1,
                                            enc_w2b, up_wb, ca_wqb, ca_wob, ff_w1b, ff_w2b, dec_w1b);
  compose_k<<<768, 256, 0, stream>>>(ca_wqkv, ca_bqkv, ip_w, ip_b,
                                     sa_wqkv, sa_bqkv, sa_wo, sa_bo,
                                     Wkv, bkv, Wsab, bsa);

  // encoder big GEMM: split-K 32 -> private partial slices (no atomics),
  // 1024 blocks = 4 blocks/CU, XCD-swizzled; bank1 passed via loss param
  gemm128<2><<<1024, 256, 0, stream>>>(
      x0b, KP, w1b, KP, nullptr, OUTp, 512, 1568, nullptr, OUTp2, 0);
  h1_epi<<<2048, 256, 0, stream>>>(OUTp, OUTp2, enc_b1, H1b);  // OUTp dead after

  // reuse x0b region for dec_w2 bf16 (x0b dead after enc GEMM)
  cvt_w2n<<<12500, 256, 0, stream>>>(dec_w2, w2n);

  // kv path (P-pool bank0 live again: OUTp dead)
  gather_nb<<<dim3(1024, 20), 256, 0, stream>>>(uid, nidx, item_emb, nbb);
  gemm128<0><<<dim3(160, 4), 256, 0, stream>>>(
      nbb, 256, Wkv, 256, bkv, kvhb, 512, 256, nullptr, nullptr, 0);

  // z0 GEMM + fused z_t
  gemm64<3><<<dim3(16, 4), 256, 0, stream>>>(
      H1b, 512, enc_w2b, 512, enc_b2, z0f, 256, 512, noise, sab, s1ab, z0b, ztb, nullptr);

  // q path
  gemm64<4><<<dim3(16, 4), 256, 0, stream>>>(
      ztb, 256, up_wb, 256, up_b, qpb, 256, 256, te, nullptr, nullptr, nullptr, nullptr, nullptr);
  gemm64<0><<<dim3(16, 4), 256, 0, stream>>>(
      qpb, 256, ca_wqb, 256, ca_bqkv, qhf, 256, 256,
      nullptr, nullptr, nullptr, nullptr, nullptr, nullptr);

  // attention + out-proj + LN1
  attn_k<<<1024, 256, 0, stream>>>(qhf, kvhb, ob);
  gemm64<1><<<dim3(16, 4), 256, 0, stream>>>(
      ob, 256, ca_wob, 256, ca_bo, cab, 256, 256,
      nullptr, nullptr, nullptr, nullptr, nullptr, nullptr);
  ln_k<<<1024, 256, 0, stream>>>(qpb, cab, n1_g, n1_b, hb);

  // self-attn (seq=1, composed) + LN2
  gemm64<1><<<dim3(16, 4), 256, 0, stream>>>(
      hb, 256, Wsab, 256, bsa, saob, 256, 256,
      nullptr, nullptr, nullptr, nullptr, nullptr, nullptr);
  ln_k<<<1024, 256, 0, stream>>>(hb, saob, n2_g, n2_b, h2b);

  // FF with fused residual + diffusion loss
  gemm64<2><<<dim3(16, 8), 256, 0, stream>>>(
      h2b, 256, ff_w1b, 256, ff_b1, f1b, 512, 256,
      nullptr, nullptr, nullptr, nullptr, nullptr, nullptr);
  gemm64<5><<<dim3(16, 4), 256, 0, stream>>>(
      f1b, 512, ff_w2b, 512, ff_b2, nullptr, 256, 512,
      h2b, z0f, nullptr, nullptr, nullptr, &scal[0]);

  // decoder: G = gelu(z0@dec_w1^T+b) bf16, then big GEMM + fused recon loss
  gemm64<2><<<dim3(16, 8), 256, 0, stream>>>(
      z0b, 256, dec_w1b, 256, dec_b1, Gb, 512, 256,
      nullptr, nullptr, nullptr, nullptr, nullptr, nullptr);
  gemm128<1><<<3136, 256, 0, stream>>>(
      Gb, 512, w2n, 512, dec_b2, nullptr, 0, 512, xmask, &scal[1], NI);

  final_k<<<1, 1, 0, stream>>>(scal, (float*)d_out);
}

// Round 3
// 877.735 us; speedup vs baseline: 1.0474x; 1.0379x over previous
//
#include <hip/hip_runtime.h>
#include <math.h>

#define NI   50000
#define Tt   1000
#define KP   50176              // 50000 padded: 32 chunks x 1568 (=49*32)
#define MW   1568               // mask words per row (KP/32)
#define NPAD 50048              // 391*128 n-pad for dec gemm

typedef __bf16 bf16x8 __attribute__((ext_vector_type(8)));
typedef float  f32x4  __attribute__((ext_vector_type(4)));

__device__ __forceinline__ unsigned short f2bf(float f) {
  unsigned u = __float_as_uint(f);
  u += 0x7FFFu + ((u >> 16) & 1u);   // RNE
  return (unsigned short)(u >> 16);
}
__device__ __forceinline__ float bf2f(unsigned short u) {
  return __uint_as_float(((unsigned)u) << 16);
}
__device__ __forceinline__ unsigned pack2(float a, float b) {
  return (unsigned)f2bf(a) | ((unsigned)f2bf(b) << 16);
}
__device__ __forceinline__ f32x4 mfma16(const unsigned short* a, const unsigned short* b, f32x4 c) {
  typedef unsigned short u16x8 __attribute__((ext_vector_type(8)));
  u16x8 av = *(const u16x8*)a;
  u16x8 bv = *(const u16x8*)b;
  return __builtin_amdgcn_mfma_f32_16x16x32_bf16(
      __builtin_bit_cast(bf16x8, av), __builtin_bit_cast(bf16x8, bv), c, 0, 0, 0);
}
__device__ __forceinline__ float gelu_f(float x) {
  return 0.5f * x * (1.f + erff(x * 0.70710678118654752f));
}

#define GLD16(gsrc, ldst) __builtin_amdgcn_global_load_lds( \
    (const __attribute__((address_space(1))) unsigned int*)(const void*)(gsrc), \
    (__attribute__((address_space(3))) unsigned int*)(void*)(ldst), 16, 0, 0)

#define PIPE_FENCE() __builtin_amdgcn_sched_barrier(0)
#define RAW_BAR()    __builtin_amdgcn_s_barrier()

// ---------------------------------------------------------------------------
// bm_expand: x0 f32 -> xmask bits only (A-matrix lives as bits now)
// grid (25, 1024): y = row, x = 2048-elem chunk
// ---------------------------------------------------------------------------
__global__ __launch_bounds__(256) void bm_expand(
    const float* __restrict__ x0, unsigned int* __restrict__ xmask)
{
  __shared__ unsigned int nib[256];
  int r = blockIdx.y, tid = threadIdx.x;
  int c0 = blockIdx.x * 2048;
  int k = c0 + tid * 8;
  const float* row = x0 + (size_t)r * NI;
  float4 a = make_float4(0.f, 0.f, 0.f, 0.f), b = a;
  if (k + 8 <= NI) {                   // NI % 8 == 0
    a = *(const float4*)(row + k);
    b = *(const float4*)(row + k + 4);
  }
  unsigned bits8 =
      (a.x != 0.f ? 1u : 0u)  | (a.y != 0.f ? 2u : 0u)  |
      (a.z != 0.f ? 4u : 0u)  | (a.w != 0.f ? 8u : 0u)  |
      (b.x != 0.f ? 16u : 0u) | (b.y != 0.f ? 32u : 0u) |
      (b.z != 0.f ? 64u : 0u) | (b.w != 0.f ? 128u : 0u);
  nib[tid] = bits8;
  __syncthreads();
  if (tid < 64) {
    unsigned wv = nib[tid * 4] | (nib[tid * 4 + 1] << 8) |
                  (nib[tid * 4 + 2] << 16) | (nib[tid * 4 + 3] << 24);
    int widx = (c0 >> 5) + tid;
    if (widx < MW) xmask[(size_t)r * MW + widx] = wv;
  }
}

// enc_w1 (512 x 50000 f32) -> bf16 (512 x KP), k-pad zeroed
__global__ __launch_bounds__(256) void cvt_w1(const float* __restrict__ src,
                                              unsigned short* __restrict__ dst) {
  int c = blockIdx.x * 2048 + threadIdx.x * 8;
  if (c >= KP) return;
  int r = blockIdx.y;
  const float* s = src + (size_t)r * NI;
  uint4 o;
  if (c + 8 <= NI) {
    float4 a = *(const float4*)(s + c), b = *(const float4*)(s + c + 4);
    o.x = pack2(a.x, a.y); o.y = pack2(a.z, a.w);
    o.z = pack2(b.x, b.y); o.w = pack2(b.z, b.w);
  } else {
    float v[8];
#pragma unroll
    for (int i = 0; i < 8; ++i) v[i] = (c + i < NI) ? s[c + i] : 0.f;
    o.x = pack2(v[0], v[1]); o.y = pack2(v[2], v[3]);
    o.z = pack2(v[4], v[5]); o.w = pack2(v[6], v[7]);
  }
  *(uint4*)(dst + (size_t)r * KP + c) = o;
}

// dec_w2 (50000 x 512 f32) -> bf16 straight cvt
__global__ __launch_bounds__(256) void cvt_w2n(const float* __restrict__ src,
                                               unsigned short* __restrict__ dst) {
  size_t idx = ((size_t)blockIdx.x * 256 + threadIdx.x) * 8;   // 12500 blocks exact
  float4 a = *(const float4*)(src + idx), b = *(const float4*)(src + idx + 4);
  uint4 o;
  o.x = pack2(a.x, a.y); o.y = pack2(a.z, a.w);
  o.z = pack2(b.x, b.y); o.w = pack2(b.z, b.w);
  *(uint4*)(dst + idx) = o;
}

// batch-convert 7 small weights f32->bf16
__global__ __launch_bounds__(256) void cvt_many(
    const float* s0, const float* s1, const float* s2, const float* s3,
    const float* s4, const float* s5, const float* s6,
    unsigned short* d0, unsigned short* d1, unsigned short* d2, unsigned short* d3,
    unsigned short* d4, unsigned short* d5, unsigned short* d6)
{
  const float* srcs[7] = {s0, s1, s2, s3, s4, s5, s6};
  unsigned short* dsts[7] = {d0, d1, d2, d3, d4, d5, d6};
  const int ns[7] = {131072, 65536, 65536, 65536, 131072, 131072, 131072};
  int j = blockIdx.y;
  int i = (blockIdx.x * 256 + threadIdx.x) * 8;
  if (i >= ns[j]) return;
  float4 a = *(const float4*)(srcs[j] + i), b = *(const float4*)(srcs[j] + i + 4);
  uint4 o;
  o.x = pack2(a.x, a.y); o.y = pack2(a.z, a.w);
  o.z = pack2(b.x, b.y); o.w = pack2(b.z, b.w);
  *(uint4*)(dsts[j] + i) = o;
}

// compose fused weights (kv-path and seq1-selfattn), bf16 outputs
__global__ __launch_bounds__(256) void compose_k(
    const float* __restrict__ ca_wqkv, const float* __restrict__ ca_bqkv,
    const float* __restrict__ ip_w, const float* __restrict__ ip_b,
    const float* __restrict__ sa_wqkv, const float* __restrict__ sa_bqkv,
    const float* __restrict__ sa_wo, const float* __restrict__ sa_bo,
    unsigned short* __restrict__ Wkv, float* __restrict__ bkv,
    unsigned short* __restrict__ Wsa, float* __restrict__ bsa)
{
  int b = blockIdx.x, k = threadIdx.x;
  if (b < 512) {
    const float* wrow = ca_wqkv + (size_t)(256 + b) * 256;
    float s = 0.f;
    for (int c = 0; c < 256; ++c) s += wrow[c] * ip_w[c * 256 + k];
    Wkv[b * 256 + k] = f2bf(s);
    if (k == 0) {
      float sb = 0.f;
      for (int c = 0; c < 256; ++c) sb += wrow[c] * ip_b[c];
      bkv[b] = sb + ca_bqkv[256 + b];
    }
  } else {
    int i = b - 512;
    const float* worow = sa_wo + (size_t)i * 256;
    float s = 0.f;
    for (int c = 0; c < 256; ++c) s += worow[c] * sa_wqkv[(512 + c) * 256 + k];
    Wsa[i * 256 + k] = f2bf(s);
    if (k == 0) {
      float sb = 0.f;
      for (int c = 0; c < 256; ++c) sb += worow[c] * sa_bqkv[512 + c];
      bsa[i] = sb + sa_bo[i];
    }
  }
}

// ---------------------------------------------------------------------------
// enc_gemm: C_partial[kc] = x0(bits)[1024 x kslice] @ w1b^T[512 x kslice]
// A expanded from xmask bits -> LDS in-register (no A HBM stream);
// B double-buffered GLD16 with counted vmcnt(2).
// 1024 blocks: g = n + 4*kc (128 groups); same-g => same XCD (id%8 const)
// ---------------------------------------------------------------------------
__global__ __launch_bounds__(256) void enc_gemm(
    const unsigned int* __restrict__ xmask,
    const unsigned short* __restrict__ Bw,
    float* __restrict__ P0, float* __restrict__ P1)
{
  __shared__ __align__(16) unsigned short As[128 * 32];
  __shared__ __align__(16) unsigned short Bs[2][128 * 32];
  const int tid = threadIdx.x;
  const int id = blockIdx.x;
  const int g = (id & 7) + 8 * (id >> 6);
  const int m0 = ((id >> 3) & 7) * 128;
  const int n0 = (g & 3) * 128;
  const int kc = g >> 2;                 // 0..31
  const int kb = kc * 1568;
  const int w = tid >> 6, l = tid & 63;
  const int wm = (w >> 1) * 64, wn = (w & 1) * 64;
  const int fr = l & 15, fo = (l >> 4) * 8;
  const int s0 = tid, s1 = tid + 256;
  const unsigned short* Br0 = Bw + (size_t)(n0 + (s0 >> 2)) * KP + kb + (s0 & 3) * 8;
  const unsigned short* Br1 = Bw + (size_t)(n0 + (s1 >> 2)) * KP + kb + (s1 & 3) * 8;
  const int arow = tid >> 1, ahalf = tid & 1;    // 2 threads per A-row, 16 bits each
  const unsigned int* mrowp = xmask + (size_t)(m0 + arow) * MW + (kb >> 5);
  f32x4 acc[4][4] = {};

#define EXPANDA(VW) do {                                                     \
    unsigned bits_ = ((VW) >> (ahalf * 16)) & 0xFFFFu;                       \
    uint4 q0_, q1_;                                                          \
    q0_.x = (bits_ & 1u     ? 0x3F80u : 0u) | (bits_ & 2u     ? 0x3F800000u : 0u); \
    q0_.y = (bits_ & 4u     ? 0x3F80u : 0u) | (bits_ & 8u     ? 0x3F800000u : 0u); \
    q0_.z = (bits_ & 16u    ? 0x3F80u : 0u) | (bits_ & 32u    ? 0x3F800000u : 0u); \
    q0_.w = (bits_ & 64u    ? 0x3F80u : 0u) | (bits_ & 128u   ? 0x3F800000u : 0u); \
    q1_.x = (bits_ & 256u   ? 0x3F80u : 0u) | (bits_ & 512u   ? 0x3F800000u : 0u); \
    q1_.y = (bits_ & 1024u  ? 0x3F80u : 0u) | (bits_ & 2048u  ? 0x3F800000u : 0u); \
    q1_.z = (bits_ & 4096u  ? 0x3F80u : 0u) | (bits_ & 8192u  ? 0x3F800000u : 0u); \
    q1_.w = (bits_ & 16384u ? 0x3F80u : 0u) | (bits_ & 32768u ? 0x3F800000u : 0u); \
    *(uint4*)&As[arow * 32 + ahalf * 16]     = q0_;                          \
    *(uint4*)&As[arow * 32 + ahalf * 16 + 8] = q1_;                          \
  } while (0)

#define CMPE(BUF) do {                                                       \
    const unsigned short *ap_[4], *bp_[4];                                   \
    _Pragma("unroll") for (int i_ = 0; i_ < 4; ++i_) {                       \
      ap_[i_] = &As[(wm + 16 * i_ + fr) * 32 + fo];                          \
      bp_[i_] = &Bs[BUF][(wn + 16 * i_ + fr) * 32 + fo]; }                   \
    _Pragma("unroll") for (int i_ = 0; i_ < 4; ++i_)                         \
    _Pragma("unroll") for (int j_ = 0; j_ < 4; ++j_)                         \
      acc[i_][j_] = mfma16(ap_[i_], bp_[j_], acc[i_][j_]); } while (0)

  // prologue: A(0) expand, B(0)->Bs0, B(1)->Bs1
  {
    unsigned vm = mrowp[0];
    GLD16(Br0,      &Bs[0][s0 * 8]);
    GLD16(Br1,      &Bs[0][s1 * 8]);
    GLD16(Br0 + 32, &Bs[1][s0 * 8]);
    GLD16(Br1 + 32, &Bs[1][s1 * 8]);
    EXPANDA(vm);
    asm volatile("s_waitcnt vmcnt(2) lgkmcnt(0)" ::: "memory");
    PIPE_FENCE(); RAW_BAR(); PIPE_FENCE();
  }
  for (int it = 0; it < 49; ++it) {
    unsigned vnext = 0;
    if (it < 48) vnext = mrowp[it + 1];      // issued early; lands under MFMA
    CMPE(it & 1);
    if (it == 48) break;
    PIPE_FENCE(); RAW_BAR(); PIPE_FENCE();   // LDS consumed; safe to overwrite
    if (it < 47) {
      GLD16(Br0 + (it + 2) * 32, &Bs[it & 1][s0 * 8]);
      GLD16(Br1 + (it + 2) * 32, &Bs[it & 1][s1 * 8]);
    }
    EXPANDA(vnext);
    if (it < 47) asm volatile("s_waitcnt vmcnt(2) lgkmcnt(0)" ::: "memory");
    else         asm volatile("s_waitcnt vmcnt(0) lgkmcnt(0)" ::: "memory");
    PIPE_FENCE(); RAW_BAR(); PIPE_FENCE();
  }
#undef EXPANDA
#undef CMPE

  const int cr = (l >> 4) * 4, cc = l & 15;
  float* Cp = ((kc < 16) ? P0 : P1) + (size_t)(kc & 15) * 524288;
#pragma unroll
  for (int i = 0; i < 4; ++i)
#pragma unroll
    for (int j = 0; j < 4; ++j) {
      int n = n0 + wn + 16 * j + cc;
#pragma unroll
      for (int r = 0; r < 4; ++r) {
        int m = m0 + wm + 16 * i + cr + r;
        Cp[(size_t)m * 512 + n] = acc[i][j][r];
      }
    }
}

// ---------------------------------------------------------------------------
// gemm128<T>: 128x128 tile, pure GLD16 staging (m97 structure, single-buffer)
// T0: C bf16 = acc + bias (grid (mx,ny))
// T1: dec recon loss, linear grid 3136, XCD-swizzled, n-groups of 8 m-blocks
// ---------------------------------------------------------------------------
template<int T>
__global__ __launch_bounds__(256) void gemm128(
    const unsigned short* __restrict__ A, int lda,
    const unsigned short* __restrict__ Bw, int ldb,
    const float* __restrict__ bias, void* __restrict__ Cv, int ldc, int K,
    const unsigned int* __restrict__ xmask, float* __restrict__ loss, int Nvalid)
{
  __shared__ __align__(16) unsigned short As[128 * 32];
  __shared__ __align__(16) unsigned short Bs[128 * 32];
  __shared__ unsigned int msk[128][4];
  __shared__ float red[4];
  const int tid = threadIdx.x;
  int m0, n0, iters;
  if (T == 1) {
    // 3136 blocks: group = n-tile (391 used); 8 m-blocks per group on one XCD
    int id = blockIdx.x;
    int n = (id & 7) + 8 * (id >> 6);
    if (n >= 391) return;
    m0 = ((id >> 3) & 7) * 128;
    n0 = n * 128;
    iters = 16;
  } else {
    m0 = blockIdx.x * 128; n0 = blockIdx.y * 128;
    iters = K >> 5;
  }
  const int w = tid >> 6, l = tid & 63;
  const int wm = (w >> 1) * 64, wn = (w & 1) * 64;
  const int fr = l & 15, fo = (l >> 4) * 8;
  const int s0 = tid, s1 = tid + 256;
  f32x4 acc[4][4] = {};
  for (int it = 0; it < iters; ++it) {
    int k0 = it * 32;
    __syncthreads();
    GLD16(A  + (size_t)(m0 + (s0 >> 2)) * lda + k0 + (s0 & 3) * 8, &As[s0 * 8]);
    GLD16(A  + (size_t)(m0 + (s1 >> 2)) * lda + k0 + (s1 & 3) * 8, &As[s1 * 8]);
    GLD16(Bw + (size_t)(n0 + (s0 >> 2)) * ldb + k0 + (s0 & 3) * 8, &Bs[s0 * 8]);
    GLD16(Bw + (size_t)(n0 + (s1 >> 2)) * ldb + k0 + (s1 & 3) * 8, &Bs[s1 * 8]);
    __syncthreads();
    const unsigned short *ap[4], *bp[4];
#pragma unroll
    for (int i = 0; i < 4; ++i) {
      ap[i] = &As[(wm + 16 * i + fr) * 32 + fo];
      bp[i] = &Bs[(wn + 16 * i + fr) * 32 + fo];
    }
#pragma unroll
    for (int i = 0; i < 4; ++i)
#pragma unroll
      for (int j = 0; j < 4; ++j)
        acc[i][j] = mfma16(ap[i], bp[j], acc[i][j]);
  }
  const int cr = (l >> 4) * 4, cc = l & 15;
  if (T == 0) {
    unsigned short* Cb = (unsigned short*)Cv;
#pragma unroll
    for (int j = 0; j < 4; ++j) {
      int n = n0 + wn + 16 * j + cc;
      float bv = bias[n];
#pragma unroll
      for (int i = 0; i < 4; ++i)
#pragma unroll
        for (int r = 0; r < 4; ++r) {
          int m = m0 + wm + 16 * i + cr + r;
          Cb[(size_t)m * ldc + n] = f2bf(acc[i][j][r] + bv);
        }
    }
  } else {
    // stage this block's mask tile: 128 rows x 4 words
    {
      int row = tid >> 1, p = tid & 1;
      *(uint2*)&msk[row][p * 2] =
          *(const uint2*)(xmask + (size_t)(m0 + row) * MW + (n0 >> 5) + p * 2);
    }
    __syncthreads();
    float ts = 0.f;
#pragma unroll
    for (int j = 0; j < 4; ++j) {
      int nl = wn + 16 * j + cc;
      int n = n0 + nl;
      if (n < Nvalid) {
        float bv = bias[n];
#pragma unroll
        for (int i = 0; i < 4; ++i)
#pragma unroll
          for (int r = 0; r < 4; ++r) {
            int ml = wm + 16 * i + cr + r;
            float lg = acc[i][j][r] + bv;
            float sp = fmaxf(lg, 0.f) + __logf(1.f + __expf(-fabsf(lg)));
            unsigned word = msk[ml][nl >> 5];
            ts += sp - (((word >> (nl & 31)) & 1u) ? lg : 0.f);
          }
      }
    }
    for (int off = 32; off > 0; off >>= 1) ts += __shfl_xor(ts, off);
    if (l == 0) red[w] = ts;
    __syncthreads();
    if (tid == 0) atomicAdd(loss, red[0] + red[1] + red[2] + red[3]);
  }
}

// ---------------------------------------------------------------------------
// gemm64<EPI>: 64x64 tile GLD16 bf16 GEMM for the mid-chain (single-buffer)
// EPI 0: f32 = acc+bias       1: bf16         2: gelu->bf16
//     3: z0 triple-write (z0f, z0b, ztb)      4: +te -> bf16 (qp)
//     5: ff2: +h2b residual, (v - z0f)^2 -> atomic loss
// ---------------------------------------------------------------------------
template<int EPI>
__global__ __launch_bounds__(256) void gemm64(
    const unsigned short* __restrict__ A, int lda,
    const unsigned short* __restrict__ Bw, int ldb,
    const float* __restrict__ bias, void* __restrict__ Cv, int ldc, int K,
    const void* __restrict__ R0, const void* __restrict__ R1, const void* __restrict__ R2,
    void* __restrict__ W0, void* __restrict__ W1, float* __restrict__ loss)
{
  __shared__ __align__(16) unsigned short As[64 * 32];
  __shared__ __align__(16) unsigned short Bs[64 * 32];
  __shared__ float red[4];
  const int tid = threadIdx.x;
  const int m0 = blockIdx.x * 64, n0 = blockIdx.y * 64;
  const int w = tid >> 6, l = tid & 63;
  const int wm = (w >> 1) * 32, wn = (w & 1) * 32;
  const int fr = l & 15, fo = (l >> 4) * 8;
  const int srow = tid >> 2, scol = (tid & 3) * 8;
  f32x4 acc[2][2] = {};
  for (int k0 = 0; k0 < K; k0 += 32) {
    __syncthreads();
    GLD16(A  + (size_t)(m0 + srow) * lda + k0 + scol, &As[tid * 8]);
    GLD16(Bw + (size_t)(n0 + srow) * ldb + k0 + scol, &Bs[tid * 8]);
    __syncthreads();
    const unsigned short* ap0 = &As[(wm +      fr) * 32 + fo];
    const unsigned short* ap1 = &As[(wm + 16 + fr) * 32 + fo];
    const unsigned short* bp0 = &Bs[(wn +      fr) * 32 + fo];
    const unsigned short* bp1 = &Bs[(wn + 16 + fr) * 32 + fo];
    acc[0][0] = mfma16(ap0, bp0, acc[0][0]);
    acc[0][1] = mfma16(ap0, bp1, acc[0][1]);
    acc[1][0] = mfma16(ap1, bp0, acc[1][0]);
    acc[1][1] = mfma16(ap1, bp1, acc[1][1]);
  }
  const int cr = (l >> 4) * 4, cc = l & 15;
  float ts = 0.f;
#pragma unroll
  for (int i = 0; i < 2; ++i)
#pragma unroll
    for (int j = 0; j < 2; ++j) {
      int n = n0 + wn + 16 * j + cc;
      float bv = bias[n];
#pragma unroll
      for (int r = 0; r < 4; ++r) {
        int m = m0 + wm + 16 * i + cr + r;
        float v = acc[i][j][r] + bv;
        size_t idx = (size_t)m * ldc + n;
        if (EPI == 0) ((float*)Cv)[idx] = v;
        if (EPI == 1) ((unsigned short*)Cv)[idx] = f2bf(v);
        if (EPI == 2) ((unsigned short*)Cv)[idx] = f2bf(gelu_f(v));
        if (EPI == 3) {
          ((float*)Cv)[idx] = v;
          ((unsigned short*)W0)[idx] = f2bf(v);
          float zt = ((const float*)R1)[m] * v +
                     ((const float*)R2)[m] * ((const float*)R0)[idx];
          ((unsigned short*)W1)[idx] = f2bf(zt);
        }
        if (EPI == 4) {
          v += ((const float*)R0)[idx];
          ((unsigned short*)Cv)[idx] = f2bf(v);
        }
        if (EPI == 5) {
          v += bf2f(((const unsigned short*)R0)[idx]);
          float d = v - ((const float*)R1)[idx];
          ts += d * d;
        }
      }
    }
  if (EPI == 5) {
    for (int off = 32; off > 0; off >>= 1) ts += __shfl_xor(ts, off);
    if (l == 0) red[w] = ts;
    __syncthreads();
    if (tid == 0) atomicAdd(loss, red[0] + red[1] + red[2] + red[3]);
  }
}

// H1b = gelu(sum_k P0[k]+P1[k] + enc_b1) -> bf16, 1024x512; 32-slice reduce
__global__ __launch_bounds__(256) void h1_epi(const float* __restrict__ P0,
                                              const float* __restrict__ P1,
                                              const float* __restrict__ b,
                                              unsigned short* __restrict__ H) {
  int i = blockIdx.x * 256 + threadIdx.x;
  float s = b[i & 511];
#pragma unroll
  for (int k = 0; k < 16; ++k) s += P0[(size_t)k * 524288 + i];
#pragma unroll
  for (int k = 0; k < 16; ++k) s += P1[(size_t)k * 524288 + i];
  H[i] = f2bf(gelu_f(s));
}

// te row + per-row schedule scalars
__global__ __launch_bounds__(256) void prep_te(
    const int* __restrict__ t,
    const float* __restrict__ te_w1, const float* __restrict__ te_b1,
    const float* __restrict__ te_w2, const float* __restrict__ te_b2,
    float* __restrict__ te, float* __restrict__ sab, float* __restrict__ s1ab)
{
  __shared__ float sj[32];
  int b = blockIdx.x, d = threadIdx.x;
  int ti = t[b];
  float tn = (float)ti / (float)Tt;
  if (d < 32) {
    float a = tn * te_w1[d] + te_b1[d];
    sj[d] = a / (1.f + __expf(-a));
  }
  if (d == 0) {
    double tt = (double)(ti + 1) / (double)Tt;
    double c  = cos((tt + 0.008) / 1.008 * M_PI * 0.5);
    double c0 = cos((0.008) / 1.008 * M_PI * 0.5);
    double ab = (c * c) / (c0 * c0);
    sab[b]  = (float)sqrt(ab);
    s1ab[b] = (float)sqrt(1.0 - ab);
  }
  __syncthreads();
  float accv = te_b2[d];
#pragma unroll
  for (int j = 0; j < 32; ++j) accv += sj[j] * te_w2[d * 32 + j];
  te[(size_t)b * 256 + d] = accv;
}

// gather neighbors -> bf16
__global__ __launch_bounds__(256) void gather_nb(
    const int* __restrict__ uid, const int* __restrict__ nidx,
    const float* __restrict__ emb, unsigned short* __restrict__ nb)
{
  int b = blockIdx.x, j = blockIdx.y, d = threadIdx.x;
  int idx = nidx[uid[b] * 20 + j];
  nb[((size_t)b * 20 + j) * 256 + d] = f2bf(emb[(size_t)idx * 256 + d]);
}

// cross-attention core: 20 keys, one wave per (b, head); kvh bf16
__global__ __launch_bounds__(256) void attn_k(
    const float* __restrict__ qh, const unsigned short* __restrict__ kvh,
    unsigned short* __restrict__ o)
{
  int b = blockIdx.x, tid = threadIdx.x;
  int h = tid >> 6, d = tid & 63;
  float qv = qh[(size_t)b * 256 + h * 64 + d];
  const unsigned short* kbase = kvh + (size_t)b * 20 * 512 + h * 64 + d;
  const unsigned short* vbase = kbase + 256;
  float s[20];
#pragma unroll
  for (int k = 0; k < 20; ++k) {
    float p = qv * bf2f(kbase[k * 512]);
    for (int off = 32; off > 0; off >>= 1) p += __shfl_xor(p, off);
    s[k] = p * 0.125f;
  }
  float mx = s[0];
#pragma unroll
  for (int k = 1; k < 20; ++k) mx = fmaxf(mx, s[k]);
  float sum = 0.f;
#pragma unroll
  for (int k = 0; k < 20; ++k) { s[k] = __expf(s[k] - mx); sum += s[k]; }
  float inv = 1.f / sum;
  float ov = 0.f;
#pragma unroll
  for (int k = 0; k < 20; ++k) ov += s[k] * bf2f(vbase[k * 512]);
  o[(size_t)b * 256 + h * 64 + d] = f2bf(ov * inv);
}

// LayerNorm(X + Y), bf16 in/out
__global__ __launch_bounds__(256) void ln_k(
    const unsigned short* __restrict__ X, const unsigned short* __restrict__ Y,
    const float* __restrict__ g, const float* __restrict__ bb,
    unsigned short* __restrict__ out)
{
  __shared__ float rs[4], rs2[4];
  int b = blockIdx.x, d = threadIdx.x;
  size_t i = (size_t)b * 256 + d;
  float v = bf2f(X[i]) + bf2f(Y[i]);
  float s = v, s2 = v * v;
  for (int off = 32; off > 0; off >>= 1) { s += __shfl_xor(s, off); s2 += __shfl_xor(s2, off); }
  int w = d >> 6, l = d & 63;
  if (l == 0) { rs[w] = s; rs2[w] = s2; }
  __syncthreads();
  s  = rs[0] + rs[1] + rs[2] + rs[3];
  s2 = rs2[0] + rs2[1] + rs2[2] + rs2[3];
  float mean = s * (1.f / 256.f);
  float var  = s2 * (1.f / 256.f) - mean * mean;
  out[i] = f2bf((v - mean) * rsqrtf(var + 1e-5f) * g[d] + bb[d]);
}

__global__ void final_k(const float* __restrict__ scal, float* __restrict__ out) {
  out[0] = scal[0] * (1.f / (1024.f * 256.f)) + 0.1f * scal[1] * (1.f / (1024.f * 50000.f));
}

// ---------------------------------------------------------------------------
extern "C" void kernel_launch(void* const* d_in, const int* in_sizes, int n_in,
                              void* d_out, int out_size, void* d_ws, size_t ws_size,
                              hipStream_t stream) {
  const float* x0      = (const float*)d_in[0];
  const int*   uid     = (const int*)  d_in[1];
  const int*   t       = (const int*)  d_in[2];
  const float* noise   = (const float*)d_in[3];
  const int*   nidx    = (const int*)  d_in[4];
  const float* item_emb= (const float*)d_in[5];
  const float* enc_w1  = (const float*)d_in[6];
  const float* enc_b1  = (const float*)d_in[7];
  const float* enc_w2  = (const float*)d_in[8];
  const float* enc_b2  = (const float*)d_in[9];
  const float* dec_w1  = (const float*)d_in[10];
  const float* dec_b1  = (const float*)d_in[11];
  const float* dec_w2  = (const float*)d_in[12];
  const float* dec_b2  = (const float*)d_in[13];
  const float* up_w    = (const float*)d_in[14];
  const float* up_b    = (const float*)d_in[15];
  const float* ip_w    = (const float*)d_in[16];
  const float* ip_b    = (const float*)d_in[17];
  const float* te_w1   = (const float*)d_in[18];
  const float* te_b1   = (const float*)d_in[19];
  const float* te_w2   = (const float*)d_in[20];
  const float* te_b2   = (const float*)d_in[21];
  const float* ca_wqkv = (const float*)d_in[22];
  const float* ca_bqkv = (const float*)d_in[23];
  const float* ca_wo   = (const float*)d_in[24];
  const float* ca_bo   = (const float*)d_in[25];
  const float* sa_wqkv = (const float*)d_in[26];
  const float* sa_bqkv = (const float*)d_in[27];
  const float* sa_wo   = (const float*)d_in[28];
  const float* sa_bo   = (const float*)d_in[29];
  const float* n1_g    = (const float*)d_in[30];
  const float* n1_b    = (const float*)d_in[31];
  const float* n2_g    = (const float*)d_in[32];
  const float* n2_b    = (const float*)d_in[33];
  const float* ff_w1   = (const float*)d_in[34];
  const float* ff_b1   = (const float*)d_in[35];
  const float* ff_w2   = (const float*)d_in[36];
  const float* ff_b2   = (const float*)d_in[37];
  (void)in_sizes; (void)n_in; (void)out_size; (void)ws_size;

  float* ws   = (float*)d_ws;
  float* scal = ws;                    // 4 (diff, recon)
  float* sab  = ws + 4;                // 1024
  float* s1ab = sab + 1024;
  float* te   = s1ab + 1024;           // 1024*256
  float* qhf  = te + 262144;           // 1024*256
  float* z0f  = qhf + 262144;          // 1024*256
  float* bkv  = z0f + 262144;          // 512
  float* bsa  = bkv + 512;             // 256
  unsigned int* xmask = (unsigned int*)(bsa + 256);           // 1024*MW
  // P-pool bank0: slices 0-15 (16 x 1024x512 f32 = 33,554,432 B) aliases
  // exactly [nbb | kvhb | f1b | Gb] (same byte size) — written post-h1_epi
  unsigned short* sh  = (unsigned short*)(xmask + 1024 * MW);
  float*          OUTp = (float*)sh;                          // 8,388,608 f32
  unsigned short* nbb  = sh;                                  // 20480*256
  unsigned short* kvhb = nbb + 5242880;                       // 20480*512
  unsigned short* f1b  = kvhb + 10485760;                     // 1024*512
  unsigned short* Gb   = f1b + 524288;                        // 1024*512
  unsigned short* x0b  = Gb + 524288;                         // region kept (w2n alias)
  unsigned short* w2n  = x0b;                                 // NPAD*512 <= region size
  unsigned short* w1b  = x0b + (size_t)1024 * KP;             // 512*KP
  unsigned short* H1b  = w1b + (size_t)512 * KP;              // 1024*512
  unsigned short* z0b  = H1b + 524288;
  unsigned short* ztb  = z0b + 262144;
  unsigned short* qpb  = ztb + 262144;
  unsigned short* ob   = qpb + 262144;
  unsigned short* cab  = ob  + 262144;
  unsigned short* hb   = cab + 262144;
  unsigned short* saob = hb  + 262144;
  unsigned short* h2b  = saob+ 262144;
  unsigned short* enc_w2b = h2b + 262144;                     // 131072
  unsigned short* up_wb   = enc_w2b + 131072;
  unsigned short* ca_wqb  = up_wb + 65536;
  unsigned short* ca_wob  = ca_wqb + 65536;
  unsigned short* ff_w1b  = ca_wob + 65536;
  unsigned short* ff_w2b  = ff_w1b + 131072;
  unsigned short* dec_w1b = ff_w2b + 131072;
  unsigned short* Wkv     = dec_w1b + 131072;
  unsigned short* Wsab    = Wkv + 131072;
  // P-pool bank1: slices 16-31, fresh tail region (33,554,432 B)
  float*          OUTp2   = (float*)(Wsab + 131072);          // 8,388,608 f32

  hipMemsetAsync(scal, 0, 4 * sizeof(float), stream);

  // independent prep
  prep_te<<<1024, 256, 0, stream>>>(t, te_w1, te_b1, te_w2, te_b2, te, sab, s1ab);
  bm_expand<<<dim3(25, 1024), 256, 0, stream>>>(x0, xmask);
  cvt_w1<<<dim3(25, 512), 256, 0, stream>>>(enc_w1, w1b);
  cvt_many<<<dim3(64, 7), 256, 0, stream>>>(enc_w2, up_w, ca_wqkv, ca_wo, ff_w1, ff_w2, dec_w1,
                                            enc_w2b, up_wb, ca_wqb, ca_wob, ff_w1b, ff_w2b, dec_w1b);
  compose_k<<<768, 256, 0, stream>>>(ca_wqkv, ca_bqkv, ip_w, ip_b,
                                     sa_wqkv, sa_bqkv, sa_wo, sa_bo,
                                     Wkv, bkv, Wsab, bsa);

  // encoder big GEMM: A expanded from bits in-kernel; split-K 32 private slices
  enc_gemm<<<1024, 256, 0, stream>>>(xmask, w1b, OUTp, OUTp2);
  h1_epi<<<2048, 256, 0, stream>>>(OUTp, OUTp2, enc_b1, H1b);  // OUTp dead after

  // reuse x0b region for dec_w2 bf16
  cvt_w2n<<<12500, 256, 0, stream>>>(dec_w2, w2n);

  // kv path (P-pool bank0 live again: OUTp dead)
  gather_nb<<<dim3(1024, 20), 256, 0, stream>>>(uid, nidx, item_emb, nbb);
  gemm128<0><<<dim3(160, 4), 256, 0, stream>>>(
      nbb, 256, Wkv, 256, bkv, kvhb, 512, 256, nullptr, nullptr, 0);

  // z0 GEMM + fused z_t
  gemm64<3><<<dim3(16, 4), 256, 0, stream>>>(
      H1b, 512, enc_w2b, 512, enc_b2, z0f, 256, 512, noise, sab, s1ab, z0b, ztb, nullptr);

  // q path
  gemm64<4><<<dim3(16, 4), 256, 0, stream>>>(
      ztb, 256, up_wb, 256, up_b, qpb, 256, 256, te, nullptr, nullptr, nullptr, nullptr, nullptr);
  gemm64<0><<<dim3(16, 4), 256, 0, stream>>>(
      qpb, 256, ca_wqb, 256, ca_bqkv, qhf, 256, 256,
      nullptr, nullptr, nullptr, nullptr, nullptr, nullptr);

  // attention + out-proj + LN1
  attn_k<<<1024, 256, 0, stream>>>(qhf, kvhb, ob);
  gemm64<1><<<dim3(16, 4), 256, 0, stream>>>(
      ob, 256, ca_wob, 256, ca_bo, cab, 256, 256,
      nullptr, nullptr, nullptr, nullptr, nullptr, nullptr);
  ln_k<<<1024, 256, 0, stream>>>(qpb, cab, n1_g, n1_b, hb);

  // self-attn (seq=1, composed) + LN2
  gemm64<1><<<dim3(16, 4), 256, 0, stream>>>(
      hb, 256, Wsab, 256, bsa, saob, 256, 256,
      nullptr, nullptr, nullptr, nullptr, nullptr, nullptr);
  ln_k<<<1024, 256, 0, stream>>>(hb, saob, n2_g, n2_b, h2b);

  // FF with fused residual + diffusion loss
  gemm64<2><<<dim3(16, 8), 256, 0, stream>>>(
      h2b, 256, ff_w1b, 256, ff_b1, f1b, 512, 256,
      nullptr, nullptr, nullptr, nullptr, nullptr, nullptr);
  gemm64<5><<<dim3(16, 4), 256, 0, stream>>>(
      f1b, 512, ff_w2b, 512, ff_b2, nullptr, 256, 512,
      h2b, z0f, nullptr, nullptr, nullptr, &scal[0]);

  // decoder: G = gelu(z0@dec_w1^T+b) bf16, then big GEMM + fused recon loss
  gemm64<2><<<dim3(16, 8), 256, 0, stream>>>(
      z0b, 256, dec_w1b, 256, dec_b1, Gb, 512, 256,
      nullptr, nullptr, nullptr, nullptr, nullptr, nullptr);
  gemm128<1><<<3136, 256, 0, stream>>>(
      Gb, 512, w2n, 512, dec_b2, nullptr, 0, 512, xmask, &scal[1], NI);

  final_k<<<1, 1, 0, stream>>>(scal, (float*)d_out);
}

// Round 4
// 855.590 us; speedup vs baseline: 1.0745x; 1.0259x over previous
//
#include <hip/hip_runtime.h>
#include <math.h>

#define NI   50000
#define Tt   1000
#define KP   50176              // 50000 padded: 32 chunks x 1568 (=49*32)
#define MW   1568               // mask words per row (KP/32)
#define NPAD 50048              // 391*128 n-pad for dec gemm

typedef __bf16 bf16x8 __attribute__((ext_vector_type(8)));
typedef float  f32x4  __attribute__((ext_vector_type(4)));

__device__ __forceinline__ unsigned short f2bf(float f) {
  unsigned u = __float_as_uint(f);
  u += 0x7FFFu + ((u >> 16) & 1u);   // RNE
  return (unsigned short)(u >> 16);
}
__device__ __forceinline__ float bf2f(unsigned short u) {
  return __uint_as_float(((unsigned)u) << 16);
}
__device__ __forceinline__ unsigned pack2(float a, float b) {
  return (unsigned)f2bf(a) | ((unsigned)f2bf(b) << 16);
}
__device__ __forceinline__ f32x4 mfma16(const unsigned short* a, const unsigned short* b, f32x4 c) {
  typedef unsigned short u16x8 __attribute__((ext_vector_type(8)));
  u16x8 av = *(const u16x8*)a;
  u16x8 bv = *(const u16x8*)b;
  return __builtin_amdgcn_mfma_f32_16x16x32_bf16(
      __builtin_bit_cast(bf16x8, av), __builtin_bit_cast(bf16x8, bv), c, 0, 0, 0);
}
__device__ __forceinline__ float gelu_f(float x) {
  return 0.5f * x * (1.f + erff(x * 0.70710678118654752f));
}

#define GLD16(gsrc, ldst) __builtin_amdgcn_global_load_lds( \
    (const __attribute__((address_space(1))) unsigned int*)(const void*)(gsrc), \
    (__attribute__((address_space(3))) unsigned int*)(void*)(ldst), 16, 0, 0)
#define GLD4(gsrc, ldst) __builtin_amdgcn_global_load_lds( \
    (const __attribute__((address_space(1))) unsigned int*)(const void*)(gsrc), \
    (__attribute__((address_space(3))) unsigned int*)(void*)(ldst), 4, 0, 0)

#define PIPE_FENCE() __builtin_amdgcn_sched_barrier(0)
#define RAW_BAR()    __builtin_amdgcn_s_barrier()

// ---------------------------------------------------------------------------
// mega_prep: all independent preparation fused into one dispatch.
// Block ranges:
//   [0,        25600)  bm_expand   (x0 -> xmask bits)
//   [25600,    38400)  cvt_w1      (enc_w1 f32 -> bf16, k-pad 0)
//   [38400,    50900)  cvt_w2n     (dec_w2 f32 -> bf16)
//   [50900,    51348)  cvt_many    (7 small weights)
//   [51348,    52116)  compose_k   (fused kv / sa weights)
//   [52116,    53140)  prep_te     (te rows + schedule scalars)
// ---------------------------------------------------------------------------
#define MB_BM   25600
#define MB_W1   38400
#define MB_W2N  50900
#define MB_MANY 51348
#define MB_COMP 52116
#define MB_TE   53140

__global__ __launch_bounds__(256) void mega_prep(
    const float* __restrict__ x0, unsigned int* __restrict__ xmask,
    const float* __restrict__ enc_w1, unsigned short* __restrict__ w1b,
    const float* __restrict__ dec_w2, unsigned short* __restrict__ w2n,
    const float* s0, const float* s1, const float* s2, const float* s3,
    const float* s4, const float* s5, const float* s6,
    unsigned short* d0, unsigned short* d1, unsigned short* d2, unsigned short* d3,
    unsigned short* d4, unsigned short* d5, unsigned short* d6,
    const float* __restrict__ ca_wqkv, const float* __restrict__ ca_bqkv,
    const float* __restrict__ ip_w, const float* __restrict__ ip_b,
    const float* __restrict__ sa_wqkv, const float* __restrict__ sa_bqkv,
    const float* __restrict__ sa_wo, const float* __restrict__ sa_bo,
    unsigned short* __restrict__ Wkv, float* __restrict__ bkv,
    unsigned short* __restrict__ Wsa, float* __restrict__ bsa,
    const int* __restrict__ t,
    const float* __restrict__ te_w1, const float* __restrict__ te_b1,
    const float* __restrict__ te_w2, const float* __restrict__ te_b2,
    float* __restrict__ te, float* __restrict__ sab, float* __restrict__ s1ab)
{
  __shared__ unsigned int nib[256];
  __shared__ float sj[32];
  const int id = blockIdx.x, tid = threadIdx.x;

  if (id < MB_BM) {
    // ---- bm_expand ----
    int r = id / 25, chunk = id % 25;
    int c0 = chunk * 2048;
    int k = c0 + tid * 8;
    const float* row = x0 + (size_t)r * NI;
    float4 a = make_float4(0.f, 0.f, 0.f, 0.f), b = a;
    if (k + 8 <= NI) {
      a = *(const float4*)(row + k);
      b = *(const float4*)(row + k + 4);
    }
    unsigned bits8 =
        (a.x != 0.f ? 1u : 0u)  | (a.y != 0.f ? 2u : 0u)  |
        (a.z != 0.f ? 4u : 0u)  | (a.w != 0.f ? 8u : 0u)  |
        (b.x != 0.f ? 16u : 0u) | (b.y != 0.f ? 32u : 0u) |
        (b.z != 0.f ? 64u : 0u) | (b.w != 0.f ? 128u : 0u);
    nib[tid] = bits8;
    __syncthreads();
    if (tid < 64) {
      unsigned wv = nib[tid * 4] | (nib[tid * 4 + 1] << 8) |
                    (nib[tid * 4 + 2] << 16) | (nib[tid * 4 + 3] << 24);
      int widx = (c0 >> 5) + tid;
      if (widx < MW) xmask[(size_t)r * MW + widx] = wv;
    }
  } else if (id < MB_W1) {
    // ---- cvt_w1 ----
    int q = id - MB_BM;
    int r = q / 25, chunk = q % 25;
    int c = chunk * 2048 + tid * 8;
    if (c >= KP) return;
    const float* s = enc_w1 + (size_t)r * NI;
    uint4 o;
    if (c + 8 <= NI) {
      float4 a = *(const float4*)(s + c), b = *(const float4*)(s + c + 4);
      o.x = pack2(a.x, a.y); o.y = pack2(a.z, a.w);
      o.z = pack2(b.x, b.y); o.w = pack2(b.z, b.w);
    } else {
      float v[8];
#pragma unroll
      for (int i = 0; i < 8; ++i) v[i] = (c + i < NI) ? s[c + i] : 0.f;
      o.x = pack2(v[0], v[1]); o.y = pack2(v[2], v[3]);
      o.z = pack2(v[4], v[5]); o.w = pack2(v[6], v[7]);
    }
    *(uint4*)(w1b + (size_t)r * KP + c) = o;
  } else if (id < MB_W2N) {
    // ---- cvt_w2n ----
    size_t idx = ((size_t)(id - MB_W1) * 256 + tid) * 8;
    float4 a = *(const float4*)(dec_w2 + idx), b = *(const float4*)(dec_w2 + idx + 4);
    uint4 o;
    o.x = pack2(a.x, a.y); o.y = pack2(a.z, a.w);
    o.z = pack2(b.x, b.y); o.w = pack2(b.z, b.w);
    *(uint4*)(w2n + idx) = o;
  } else if (id < MB_MANY) {
    // ---- cvt_many ----
    const float* srcs[7] = {s0, s1, s2, s3, s4, s5, s6};
    unsigned short* dsts[7] = {d0, d1, d2, d3, d4, d5, d6};
    const int ns[7] = {131072, 65536, 65536, 65536, 131072, 131072, 131072};
    int q = id - MB_W2N;
    int j = q >> 6;
    int i = ((q & 63) * 256 + tid) * 8;
    if (i >= ns[j]) return;
    float4 a = *(const float4*)(srcs[j] + i), b = *(const float4*)(srcs[j] + i + 4);
    uint4 o;
    o.x = pack2(a.x, a.y); o.y = pack2(a.z, a.w);
    o.z = pack2(b.x, b.y); o.w = pack2(b.z, b.w);
    *(uint4*)(dsts[j] + i) = o;
  } else if (id < MB_COMP) {
    // ---- compose_k ----
    int b = id - MB_MANY, k = tid;
    if (b < 512) {
      const float* wrow = ca_wqkv + (size_t)(256 + b) * 256;
      float s = 0.f;
      for (int c = 0; c < 256; ++c) s += wrow[c] * ip_w[c * 256 + k];
      Wkv[b * 256 + k] = f2bf(s);
      if (k == 0) {
        float sb = 0.f;
        for (int c = 0; c < 256; ++c) sb += wrow[c] * ip_b[c];
        bkv[b] = sb + ca_bqkv[256 + b];
      }
    } else {
      int i = b - 512;
      const float* worow = sa_wo + (size_t)i * 256;
      float s = 0.f;
      for (int c = 0; c < 256; ++c) s += worow[c] * sa_wqkv[(512 + c) * 256 + k];
      Wsa[i * 256 + k] = f2bf(s);
      if (k == 0) {
        float sb = 0.f;
        for (int c = 0; c < 256; ++c) sb += worow[c] * sa_bqkv[512 + c];
        bsa[i] = sb + sa_bo[i];
      }
    }
  } else {
    // ---- prep_te ----
    int b = id - MB_COMP, d = tid;
    int ti = t[b];
    float tn = (float)ti / (float)Tt;
    if (d < 32) {
      float a = tn * te_w1[d] + te_b1[d];
      sj[d] = a / (1.f + __expf(-a));
    }
    if (d == 0) {
      double tt = (double)(ti + 1) / (double)Tt;
      double c  = cos((tt + 0.008) / 1.008 * M_PI * 0.5);
      double c0 = cos((0.008) / 1.008 * M_PI * 0.5);
      double ab = (c * c) / (c0 * c0);
      sab[b]  = (float)sqrt(ab);
      s1ab[b] = (float)sqrt(1.0 - ab);
    }
    __syncthreads();
    float accv = te_b2[d];
#pragma unroll
    for (int j = 0; j < 32; ++j) accv += sj[j] * te_w2[d * 32 + j];
    te[(size_t)b * 256 + d] = accv;
  }
}

// ---------------------------------------------------------------------------
// enc_gemm: C_partial[kc] = x0(bits)[1024 x kslice] @ w1b^T[512 x kslice]
// A-fragments built via 256-entry LDS LUT (byte -> 8 bf16); per-iter mask
// words (64/wave) staged to LDS with GLD4 alongside B (GLD16), double-
// buffered, counted vmcnt(3). No in-loop VALU expansion, no As buffer.
// 1024 blocks: g = n + 4*kc (128 groups); same-g => same XCD (id%8 const)
// ---------------------------------------------------------------------------
__global__ __launch_bounds__(256) void enc_gemm(
    const unsigned int* __restrict__ xmask,
    const unsigned short* __restrict__ Bw,
    float* __restrict__ P0, float* __restrict__ P1)
{
  __shared__ __align__(16) unsigned short Bs[2][128 * 32];
  __shared__ __align__(16) unsigned short lut[256][8];
  __shared__ unsigned int mskb[2][4][64];
  const int tid = threadIdx.x;
  const int id = blockIdx.x;
  const int g = (id & 7) + 8 * (id >> 6);
  const int m0 = ((id >> 3) & 7) * 128;
  const int n0 = (g & 3) * 128;
  const int kc = g >> 2;                 // 0..31
  const int kb = kc * 1568;
  const int w = tid >> 6, l = tid & 63;
  const int wm = (w >> 1) * 64, wn = (w & 1) * 64;
  const int fr = l & 15, fo = (l >> 4) * 8;
  const int s0 = tid, s1 = tid + 256;
  const unsigned short* Br0 = Bw + (size_t)(n0 + (s0 >> 2)) * KP + kb + (s0 & 3) * 8;
  const unsigned short* Br1 = Bw + (size_t)(n0 + (s1 >> 2)) * KP + kb + (s1 & 3) * 8;
  // per-lane mask source: wave w stages words for rows m0+wm .. m0+wm+63
  const unsigned int* msrc = xmask + (size_t)(m0 + wm + l) * MW + (kb >> 5);
  f32x4 acc[4][4] = {};

  // LUT init: entry tid = 8 bf16 decoded from bits of tid
  {
    unsigned b = (unsigned)tid;
    uint4 q;
    q.x = (b & 1u   ? 0x3F80u : 0u) | (b & 2u   ? 0x3F800000u : 0u);
    q.y = (b & 4u   ? 0x3F80u : 0u) | (b & 8u   ? 0x3F800000u : 0u);
    q.z = (b & 16u  ? 0x3F80u : 0u) | (b & 32u  ? 0x3F800000u : 0u);
    q.w = (b & 64u  ? 0x3F80u : 0u) | (b & 128u ? 0x3F800000u : 0u);
    *(uint4*)&lut[tid][0] = q;
  }

#define STGE(IT, BUF) do {                                   \
    GLD4(msrc + (IT), &mskb[BUF][w][0]);                     \
    GLD16(Br0 + (IT) * 32, &Bs[BUF][s0 * 8]);                \
    GLD16(Br1 + (IT) * 32, &Bs[BUF][s1 * 8]); } while (0)

#define CMPE(BUF) do {                                                       \
    unsigned w0_ = mskb[BUF][w][fr];                                         \
    unsigned w1_ = mskb[BUF][w][16 + fr];                                    \
    unsigned w2_ = mskb[BUF][w][32 + fr];                                    \
    unsigned w3_ = mskb[BUF][w][48 + fr];                                    \
    const unsigned short* ap_[4];                                            \
    ap_[0] = &lut[(w0_ >> fo) & 0xFF][0];                                    \
    ap_[1] = &lut[(w1_ >> fo) & 0xFF][0];                                    \
    ap_[2] = &lut[(w2_ >> fo) & 0xFF][0];                                    \
    ap_[3] = &lut[(w3_ >> fo) & 0xFF][0];                                    \
    const unsigned short* bp_[4];                                            \
    _Pragma("unroll") for (int j_ = 0; j_ < 4; ++j_)                         \
      bp_[j_] = &Bs[BUF][(wn + 16 * j_ + fr) * 32 + fo];                     \
    _Pragma("unroll") for (int i_ = 0; i_ < 4; ++i_)                         \
    _Pragma("unroll") for (int j_ = 0; j_ < 4; ++j_)                         \
      acc[i_][j_] = mfma16(ap_[i_], bp_[j_], acc[i_][j_]); } while (0)

  // prologue: stages 0 and 1 in flight; wait stage0 (+LUT writes), barrier
  STGE(0, 0);
  STGE(1, 1);
  asm volatile("s_waitcnt vmcnt(3) lgkmcnt(0)" ::: "memory");
  PIPE_FENCE(); RAW_BAR(); PIPE_FENCE();
  for (int it = 0; it < 49; ++it) {
    CMPE(it & 1);
    if (it == 48) break;
    PIPE_FENCE(); RAW_BAR(); PIPE_FENCE();   // buf consumed by all waves
    if (it < 47) {
      STGE(it + 2, it & 1);
      asm volatile("s_waitcnt vmcnt(3) lgkmcnt(0)" ::: "memory");
    } else {
      asm volatile("s_waitcnt vmcnt(0) lgkmcnt(0)" ::: "memory");
    }
    PIPE_FENCE(); RAW_BAR(); PIPE_FENCE();
  }
#undef STGE
#undef CMPE

  const int cr = (l >> 4) * 4, cc = l & 15;
  float* Cp = ((kc < 16) ? P0 : P1) + (size_t)(kc & 15) * 524288;
#pragma unroll
  for (int i = 0; i < 4; ++i)
#pragma unroll
    for (int j = 0; j < 4; ++j) {
      int n = n0 + wn + 16 * j + cc;
#pragma unroll
      for (int r = 0; r < 4; ++r) {
        int m = m0 + wm + 16 * i + cr + r;
        Cp[(size_t)m * 512 + n] = acc[i][j][r];
      }
    }
}

// ---------------------------------------------------------------------------
// gemm128<T>: 128x128 tile, pure GLD16 staging (m97 structure, single-buffer)
// T0: C bf16 = acc + bias (grid (mx,ny))
// T1: dec recon loss, linear grid 3136, XCD-swizzled, n-groups of 8 m-blocks
// ---------------------------------------------------------------------------
template<int T>
__global__ __launch_bounds__(256) void gemm128(
    const unsigned short* __restrict__ A, int lda,
    const unsigned short* __restrict__ Bw, int ldb,
    const float* __restrict__ bias, void* __restrict__ Cv, int ldc, int K,
    const unsigned int* __restrict__ xmask, float* __restrict__ loss, int Nvalid)
{
  __shared__ __align__(16) unsigned short As[128 * 32];
  __shared__ __align__(16) unsigned short Bs[128 * 32];
  __shared__ unsigned int msk[128][4];
  __shared__ float red[4];
  const int tid = threadIdx.x;
  int m0, n0, iters;
  if (T == 1) {
    // 3136 blocks: group = n-tile (391 used); 8 m-blocks per group on one XCD
    int id = blockIdx.x;
    int n = (id & 7) + 8 * (id >> 6);
    if (n >= 391) return;
    m0 = ((id >> 3) & 7) * 128;
    n0 = n * 128;
    iters = 16;
  } else {
    m0 = blockIdx.x * 128; n0 = blockIdx.y * 128;
    iters = K >> 5;
  }
  const int w = tid >> 6, l = tid & 63;
  const int wm = (w >> 1) * 64, wn = (w & 1) * 64;
  const int fr = l & 15, fo = (l >> 4) * 8;
  const int s0 = tid, s1 = tid + 256;
  f32x4 acc[4][4] = {};
  for (int it = 0; it < iters; ++it) {
    int k0 = it * 32;
    __syncthreads();
    GLD16(A  + (size_t)(m0 + (s0 >> 2)) * lda + k0 + (s0 & 3) * 8, &As[s0 * 8]);
    GLD16(A  + (size_t)(m0 + (s1 >> 2)) * lda + k0 + (s1 & 3) * 8, &As[s1 * 8]);
    GLD16(Bw + (size_t)(n0 + (s0 >> 2)) * ldb + k0 + (s0 & 3) * 8, &Bs[s0 * 8]);
    GLD16(Bw + (size_t)(n0 + (s1 >> 2)) * ldb + k0 + (s1 & 3) * 8, &Bs[s1 * 8]);
    __syncthreads();
    const unsigned short *ap[4], *bp[4];
#pragma unroll
    for (int i = 0; i < 4; ++i) {
      ap[i] = &As[(wm + 16 * i + fr) * 32 + fo];
      bp[i] = &Bs[(wn + 16 * i + fr) * 32 + fo];
    }
#pragma unroll
    for (int i = 0; i < 4; ++i)
#pragma unroll
      for (int j = 0; j < 4; ++j)
        acc[i][j] = mfma16(ap[i], bp[j], acc[i][j]);
  }
  const int cr = (l >> 4) * 4, cc = l & 15;
  if (T == 0) {
    unsigned short* Cb = (unsigned short*)Cv;
#pragma unroll
    for (int j = 0; j < 4; ++j) {
      int n = n0 + wn + 16 * j + cc;
      float bv = bias[n];
#pragma unroll
      for (int i = 0; i < 4; ++i)
#pragma unroll
        for (int r = 0; r < 4; ++r) {
          int m = m0 + wm + 16 * i + cr + r;
          Cb[(size_t)m * ldc + n] = f2bf(acc[i][j][r] + bv);
        }
    }
  } else {
    // stage this block's mask tile: 128 rows x 4 words
    {
      int row = tid >> 1, p = tid & 1;
      *(uint2*)&msk[row][p * 2] =
          *(const uint2*)(xmask + (size_t)(m0 + row) * MW + (n0 >> 5) + p * 2);
    }
    __syncthreads();
    float ts = 0.f;
#pragma unroll
    for (int j = 0; j < 4; ++j) {
      int nl = wn + 16 * j + cc;
      int n = n0 + nl;
      if (n < Nvalid) {
        float bv = bias[n];
#pragma unroll
        for (int i = 0; i < 4; ++i)
#pragma unroll
          for (int r = 0; r < 4; ++r) {
            int ml = wm + 16 * i + cr + r;
            float lg = acc[i][j][r] + bv;
            float sp = fmaxf(lg, 0.f) + __logf(1.f + __expf(-fabsf(lg)));
            unsigned word = msk[ml][nl >> 5];
            ts += sp - (((word >> (nl & 31)) & 1u) ? lg : 0.f);
          }
      }
    }
    for (int off = 32; off > 0; off >>= 1) ts += __shfl_xor(ts, off);
    if (l == 0) red[w] = ts;
    __syncthreads();
    if (tid == 0) atomicAdd(loss, red[0] + red[1] + red[2] + red[3]);
  }
}

// ---------------------------------------------------------------------------
// gemm64<EPI>: 64x64 tile GLD16 bf16 GEMM for the mid-chain (single-buffer)
// EPI 0: f32 = acc+bias       1: bf16         2: gelu->bf16
//     3: z0 triple-write (z0f, z0b, ztb)      4: +te -> bf16 (qp)
//     5: ff2: +h2b residual, (v - z0f)^2 -> atomic loss
// ---------------------------------------------------------------------------
template<int EPI>
__global__ __launch_bounds__(256) void gemm64(
    const unsigned short* __restrict__ A, int lda,
    const unsigned short* __restrict__ Bw, int ldb,
    const float* __restrict__ bias, void* __restrict__ Cv, int ldc, int K,
    const void* __restrict__ R0, const void* __restrict__ R1, const void* __restrict__ R2,
    void* __restrict__ W0, void* __restrict__ W1, float* __restrict__ loss)
{
  __shared__ __align__(16) unsigned short As[64 * 32];
  __shared__ __align__(16) unsigned short Bs[64 * 32];
  __shared__ float red[4];
  const int tid = threadIdx.x;
  const int m0 = blockIdx.x * 64, n0 = blockIdx.y * 64;
  const int w = tid >> 6, l = tid & 63;
  const int wm = (w >> 1) * 32, wn = (w & 1) * 32;
  const int fr = l & 15, fo = (l >> 4) * 8;
  const int srow = tid >> 2, scol = (tid & 3) * 8;
  f32x4 acc[2][2] = {};
  for (int k0 = 0; k0 < K; k0 += 32) {
    __syncthreads();
    GLD16(A  + (size_t)(m0 + srow) * lda + k0 + scol, &As[tid * 8]);
    GLD16(Bw + (size_t)(n0 + srow) * ldb + k0 + scol, &Bs[tid * 8]);
    __syncthreads();
    const unsigned short* ap0 = &As[(wm +      fr) * 32 + fo];
    const unsigned short* ap1 = &As[(wm + 16 + fr) * 32 + fo];
    const unsigned short* bp0 = &Bs[(wn +      fr) * 32 + fo];
    const unsigned short* bp1 = &Bs[(wn + 16 + fr) * 32 + fo];
    acc[0][0] = mfma16(ap0, bp0, acc[0][0]);
    acc[0][1] = mfma16(ap0, bp1, acc[0][1]);
    acc[1][0] = mfma16(ap1, bp0, acc[1][0]);
    acc[1][1] = mfma16(ap1, bp1, acc[1][1]);
  }
  const int cr = (l >> 4) * 4, cc = l & 15;
  float ts = 0.f;
#pragma unroll
  for (int i = 0; i < 2; ++i)
#pragma unroll
    for (int j = 0; j < 2; ++j) {
      int n = n0 + wn + 16 * j + cc;
      float bv = bias[n];
#pragma unroll
      for (int r = 0; r < 4; ++r) {
        int m = m0 + wm + 16 * i + cr + r;
        float v = acc[i][j][r] + bv;
        size_t idx = (size_t)m * ldc + n;
        if (EPI == 0) ((float*)Cv)[idx] = v;
        if (EPI == 1) ((unsigned short*)Cv)[idx] = f2bf(v);
        if (EPI == 2) ((unsigned short*)Cv)[idx] = f2bf(gelu_f(v));
        if (EPI == 3) {
          ((float*)Cv)[idx] = v;
          ((unsigned short*)W0)[idx] = f2bf(v);
          float zt = ((const float*)R1)[m] * v +
                     ((const float*)R2)[m] * ((const float*)R0)[idx];
          ((unsigned short*)W1)[idx] = f2bf(zt);
        }
        if (EPI == 4) {
          v += ((const float*)R0)[idx];
          ((unsigned short*)Cv)[idx] = f2bf(v);
        }
        if (EPI == 5) {
          v += bf2f(((const unsigned short*)R0)[idx]);
          float d = v - ((const float*)R1)[idx];
          ts += d * d;
        }
      }
    }
  if (EPI == 5) {
    for (int off = 32; off > 0; off >>= 1) ts += __shfl_xor(ts, off);
    if (l == 0) red[w] = ts;
    __syncthreads();
    if (tid == 0) atomicAdd(loss, red[0] + red[1] + red[2] + red[3]);
  }
}

// H1b = gelu(sum_k P0[k]+P1[k] + enc_b1) -> bf16, 1024x512; 32-slice reduce
__global__ __launch_bounds__(256) void h1_epi(const float* __restrict__ P0,
                                              const float* __restrict__ P1,
                                              const float* __restrict__ b,
                                              unsigned short* __restrict__ H) {
  int i = blockIdx.x * 256 + threadIdx.x;
  float s = b[i & 511];
#pragma unroll
  for (int k = 0; k < 16; ++k) s += P0[(size_t)k * 524288 + i];
#pragma unroll
  for (int k = 0; k < 16; ++k) s += P1[(size_t)k * 524288 + i];
  H[i] = f2bf(gelu_f(s));
}

// gather neighbors -> bf16
__global__ __launch_bounds__(256) void gather_nb(
    const int* __restrict__ uid, const int* __restrict__ nidx,
    const float* __restrict__ emb, unsigned short* __restrict__ nb)
{
  int b = blockIdx.x, j = blockIdx.y, d = threadIdx.x;
  int idx = nidx[uid[b] * 20 + j];
  nb[((size_t)b * 20 + j) * 256 + d] = f2bf(emb[(size_t)idx * 256 + d]);
}

// cross-attention core: 20 keys, one wave per (b, head); kvh bf16
__global__ __launch_bounds__(256) void attn_k(
    const float* __restrict__ qh, const unsigned short* __restrict__ kvh,
    unsigned short* __restrict__ o)
{
  int b = blockIdx.x, tid = threadIdx.x;
  int h = tid >> 6, d = tid & 63;
  float qv = qh[(size_t)b * 256 + h * 64 + d];
  const unsigned short* kbase = kvh + (size_t)b * 20 * 512 + h * 64 + d;
  const unsigned short* vbase = kbase + 256;
  float s[20];
#pragma unroll
  for (int k = 0; k < 20; ++k) {
    float p = qv * bf2f(kbase[k * 512]);
    for (int off = 32; off > 0; off >>= 1) p += __shfl_xor(p, off);
    s[k] = p * 0.125f;
  }
  float mx = s[0];
#pragma unroll
  for (int k = 1; k < 20; ++k) mx = fmaxf(mx, s[k]);
  float sum = 0.f;
#pragma unroll
  for (int k = 0; k < 20; ++k) { s[k] = __expf(s[k] - mx); sum += s[k]; }
  float inv = 1.f / sum;
  float ov = 0.f;
#pragma unroll
  for (int k = 0; k < 20; ++k) ov += s[k] * bf2f(vbase[k * 512]);
  o[(size_t)b * 256 + h * 64 + d] = f2bf(ov * inv);
}

// LayerNorm(X + Y), bf16 in/out
__global__ __launch_bounds__(256) void ln_k(
    const unsigned short* __restrict__ X, const unsigned short* __restrict__ Y,
    const float* __restrict__ g, const float* __restrict__ bb,
    unsigned short* __restrict__ out)
{
  __shared__ float rs[4], rs2[4];
  int b = blockIdx.x, d = threadIdx.x;
  size_t i = (size_t)b * 256 + d;
  float v = bf2f(X[i]) + bf2f(Y[i]);
  float s = v, s2 = v * v;
  for (int off = 32; off > 0; off >>= 1) { s += __shfl_xor(s, off); s2 += __shfl_xor(s2, off); }
  int w = d >> 6, l = d & 63;
  if (l == 0) { rs[w] = s; rs2[w] = s2; }
  __syncthreads();
  s  = rs[0] + rs[1] + rs[2] + rs[3];
  s2 = rs2[0] + rs2[1] + rs2[2] + rs2[3];
  float mean = s * (1.f / 256.f);
  float var  = s2 * (1.f / 256.f) - mean * mean;
  out[i] = f2bf((v - mean) * rsqrtf(var + 1e-5f) * g[d] + bb[d]);
}

__global__ void final_k(const float* __restrict__ scal, float* __restrict__ out) {
  out[0] = scal[0] * (1.f / (1024.f * 256.f)) + 0.1f * scal[1] * (1.f / (1024.f * 50000.f));
}

// ---------------------------------------------------------------------------
extern "C" void kernel_launch(void* const* d_in, const int* in_sizes, int n_in,
                              void* d_out, int out_size, void* d_ws, size_t ws_size,
                              hipStream_t stream) {
  const float* x0      = (const float*)d_in[0];
  const int*   uid     = (const int*)  d_in[1];
  const int*   t       = (const int*)  d_in[2];
  const float* noise   = (const float*)d_in[3];
  const int*   nidx    = (const int*)  d_in[4];
  const float* item_emb= (const float*)d_in[5];
  const float* enc_w1  = (const float*)d_in[6];
  const float* enc_b1  = (const float*)d_in[7];
  const float* enc_w2  = (const float*)d_in[8];
  const float* enc_b2  = (const float*)d_in[9];
  const float* dec_w1  = (const float*)d_in[10];
  const float* dec_b1  = (const float*)d_in[11];
  const float* dec_w2  = (const float*)d_in[12];
  const float* dec_b2  = (const float*)d_in[13];
  const float* up_w    = (const float*)d_in[14];
  const float* up_b    = (const float*)d_in[15];
  const float* ip_w    = (const float*)d_in[16];
  const float* ip_b    = (const float*)d_in[17];
  const float* te_w1   = (const float*)d_in[18];
  const float* te_b1   = (const float*)d_in[19];
  const float* te_w2   = (const float*)d_in[20];
  const float* te_b2   = (const float*)d_in[21];
  const float* ca_wqkv = (const float*)d_in[22];
  const float* ca_bqkv = (const float*)d_in[23];
  const float* ca_wo   = (const float*)d_in[24];
  const float* ca_bo   = (const float*)d_in[25];
  const float* sa_wqkv = (const float*)d_in[26];
  const float* sa_bqkv = (const float*)d_in[27];
  const float* sa_wo   = (const float*)d_in[28];
  const float* sa_bo   = (const float*)d_in[29];
  const float* n1_g    = (const float*)d_in[30];
  const float* n1_b    = (const float*)d_in[31];
  const float* n2_g    = (const float*)d_in[32];
  const float* n2_b    = (const float*)d_in[33];
  const float* ff_w1   = (const float*)d_in[34];
  const float* ff_b1   = (const float*)d_in[35];
  const float* ff_w2   = (const float*)d_in[36];
  const float* ff_b2   = (const float*)d_in[37];
  (void)in_sizes; (void)n_in; (void)out_size; (void)ws_size;

  float* ws   = (float*)d_ws;
  float* scal = ws;                    // 4 (diff, recon)
  float* sab  = ws + 4;                // 1024
  float* s1ab = sab + 1024;
  float* te   = s1ab + 1024;           // 1024*256
  float* qhf  = te + 262144;           // 1024*256
  float* z0f  = qhf + 262144;          // 1024*256
  float* bkv  = z0f + 262144;          // 512
  float* bsa  = bkv + 512;             // 256
  unsigned int* xmask = (unsigned int*)(bsa + 256);           // 1024*MW
  // P-pool bank0: slices 0-15 (16 x 1024x512 f32 = 33,554,432 B) aliases
  // exactly [nbb | kvhb | f1b | Gb] (same byte size) — written post-h1_epi
  unsigned short* sh  = (unsigned short*)(xmask + 1024 * MW);
  float*          OUTp = (float*)sh;                          // 8,388,608 f32
  unsigned short* nbb  = sh;                                  // 20480*256
  unsigned short* kvhb = nbb + 5242880;                       // 20480*512
  unsigned short* f1b  = kvhb + 10485760;                     // 1024*512
  unsigned short* Gb   = f1b + 524288;                        // 1024*512
  unsigned short* x0b  = Gb + 524288;                         // region kept (w2n alias)
  unsigned short* w2n  = x0b;                                 // NPAD*512 <= region size
  unsigned short* w1b  = x0b + (size_t)1024 * KP;             // 512*KP
  unsigned short* H1b  = w1b + (size_t)512 * KP;              // 1024*512
  unsigned short* z0b  = H1b + 524288;
  unsigned short* ztb  = z0b + 262144;
  unsigned short* qpb  = ztb + 262144;
  unsigned short* ob   = qpb + 262144;
  unsigned short* cab  = ob  + 262144;
  unsigned short* hb   = cab + 262144;
  unsigned short* saob = hb  + 262144;
  unsigned short* h2b  = saob+ 262144;
  unsigned short* enc_w2b = h2b + 262144;                     // 131072
  unsigned short* up_wb   = enc_w2b + 131072;
  unsigned short* ca_wqb  = up_wb + 65536;
  unsigned short* ca_wob  = ca_wqb + 65536;
  unsigned short* ff_w1b  = ca_wob + 65536;
  unsigned short* ff_w2b  = ff_w1b + 131072;
  unsigned short* dec_w1b = ff_w2b + 131072;
  unsigned short* Wkv     = dec_w1b + 131072;
  unsigned short* Wsab    = Wkv + 131072;
  // P-pool bank1: slices 16-31, fresh tail region (33,554,432 B)
  float*          OUTp2   = (float*)(Wsab + 131072);          // 8,388,608 f32

  hipMemsetAsync(scal, 0, 4 * sizeof(float), stream);

  // all independent prep in ONE dispatch
  mega_prep<<<MB_TE, 256, 0, stream>>>(
      x0, xmask, enc_w1, w1b, dec_w2, w2n,
      enc_w2, up_w, ca_wqkv, ca_wo, ff_w1, ff_w2, dec_w1,
      enc_w2b, up_wb, ca_wqb, ca_wob, ff_w1b, ff_w2b, dec_w1b,
      ca_wqkv, ca_bqkv, ip_w, ip_b, sa_wqkv, sa_bqkv, sa_wo, sa_bo,
      Wkv, bkv, Wsab, bsa,
      t, te_w1, te_b1, te_w2, te_b2, te, sab, s1ab);

  // encoder big GEMM: LUT-A from bits; split-K 32 private slices
  enc_gemm<<<1024, 256, 0, stream>>>(xmask, w1b, OUTp, OUTp2);
  h1_epi<<<2048, 256, 0, stream>>>(OUTp, OUTp2, enc_b1, H1b);  // OUTp dead after

  // kv path (P-pool bank0 live again: OUTp dead)
  gather_nb<<<dim3(1024, 20), 256, 0, stream>>>(uid, nidx, item_emb, nbb);
  gemm128<0><<<dim3(160, 4), 256, 0, stream>>>(
      nbb, 256, Wkv, 256, bkv, kvhb, 512, 256, nullptr, nullptr, 0);

  // z0 GEMM + fused z_t
  gemm64<3><<<dim3(16, 4), 256, 0, stream>>>(
      H1b, 512, enc_w2b, 512, enc_b2, z0f, 256, 512, noise, sab, s1ab, z0b, ztb, nullptr);

  // q path
  gemm64<4><<<dim3(16, 4), 256, 0, stream>>>(
      ztb, 256, up_wb, 256, up_b, qpb, 256, 256, te, nullptr, nullptr, nullptr, nullptr, nullptr);
  gemm64<0><<<dim3(16, 4), 256, 0, stream>>>(
      qpb, 256, ca_wqb, 256, ca_bqkv, qhf, 256, 256,
      nullptr, nullptr, nullptr, nullptr, nullptr, nullptr);

  // attention + out-proj + LN1
  attn_k<<<1024, 256, 0, stream>>>(qhf, kvhb, ob);
  gemm64<1><<<dim3(16, 4), 256, 0, stream>>>(
      ob, 256, ca_wob, 256, ca_bo, cab, 256, 256,
      nullptr, nullptr, nullptr, nullptr, nullptr, nullptr);
  ln_k<<<1024, 256, 0, stream>>>(qpb, cab, n1_g, n1_b, hb);

  // self-attn (seq=1, composed) + LN2
  gemm64<1><<<dim3(16, 4), 256, 0, stream>>>(
      hb, 256, Wsab, 256, bsa, saob, 256, 256,
      nullptr, nullptr, nullptr, nullptr, nullptr, nullptr);
  ln_k<<<1024, 256, 0, stream>>>(hb, saob, n2_g, n2_b, h2b);

  // FF with fused residual + diffusion loss
  gemm64<2><<<dim3(16, 8), 256, 0, stream>>>(
      h2b, 256, ff_w1b, 256, ff_b1, f1b, 512, 256,
      nullptr, nullptr, nullptr, nullptr, nullptr, nullptr);
  gemm64<5><<<dim3(16, 4), 256, 0, stream>>>(
      f1b, 512, ff_w2b, 512, ff_b2, nullptr, 256, 512,
      h2b, z0f, nullptr, nullptr, nullptr, &scal[0]);

  // decoder: G = gelu(z0@dec_w1^T+b) bf16, then big GEMM + fused recon loss
  gemm64<2><<<dim3(16, 8), 256, 0, stream>>>(
      z0b, 256, dec_w1b, 256, dec_b1, Gb, 512, 256,
      nullptr, nullptr, nullptr, nullptr, nullptr, nullptr);
  gemm128<1><<<3136, 256, 0, stream>>>(
      Gb, 512, w2n, 512, dec_b2, nullptr, 0, 512, xmask, &scal[1], NI);

  final_k<<<1, 1, 0, stream>>>(scal, (float*)d_out);
}

// Round 6
// 827.718 us; speedup vs baseline: 1.1107x; 1.0337x over previous
//
#include <hip/hip_runtime.h>
#include <math.h>

#define NI   50000
#define Tt   1000
#define KP   50176              // 50000 padded: 32 chunks x 1568 (=49*32)
#define MW   1568               // mask words per row (KP/32)
#define NPAD 50048              // 391*128 n-pad for dec gemm

typedef __bf16 bf16x8 __attribute__((ext_vector_type(8)));
typedef float  f32x4  __attribute__((ext_vector_type(4)));

__device__ __forceinline__ unsigned short f2bf(float f) {
  unsigned u = __float_as_uint(f);
  u += 0x7FFFu + ((u >> 16) & 1u);   // RNE
  return (unsigned short)(u >> 16);
}
__device__ __forceinline__ float bf2f(unsigned short u) {
  return __uint_as_float(((unsigned)u) << 16);
}
__device__ __forceinline__ unsigned pack2(float a, float b) {
  return (unsigned)f2bf(a) | ((unsigned)f2bf(b) << 16);
}
__device__ __forceinline__ f32x4 mfma16(const unsigned short* a, const unsigned short* b, f32x4 c) {
  typedef unsigned short u16x8 __attribute__((ext_vector_type(8)));
  u16x8 av = *(const u16x8*)a;
  u16x8 bv = *(const u16x8*)b;
  return __builtin_amdgcn_mfma_f32_16x16x32_bf16(
      __builtin_bit_cast(bf16x8, av), __builtin_bit_cast(bf16x8, bv), c, 0, 0, 0);
}
__device__ __forceinline__ float gelu_f(float x) {
  return 0.5f * x * (1.f + erff(x * 0.70710678118654752f));
}

#define GLD16(gsrc, ldst) __builtin_amdgcn_global_load_lds( \
    (const __attribute__((address_space(1))) unsigned int*)(const void*)(gsrc), \
    (__attribute__((address_space(3))) unsigned int*)(void*)(ldst), 16, 0, 0)
#define GLD4(gsrc, ldst) __builtin_amdgcn_global_load_lds( \
    (const __attribute__((address_space(1))) unsigned int*)(const void*)(gsrc), \
    (__attribute__((address_space(3))) unsigned int*)(void*)(ldst), 4, 0, 0)

#define PIPE_FENCE() __builtin_amdgcn_sched_barrier(0)
#define RAW_BAR()    __builtin_amdgcn_s_barrier()

// ---------------------------------------------------------------------------
// prep_crit: only what enc_fused depends on.
//   [0, 800)    bm_tile: x0 -> xmask (row-major) + xmaskT (word-major)
//               32 rows x 2048 cols per block (32 rowgroups x 25 chunks)
//   [800, 1312) cvt_w1: enc_w1 row -> bf16 (fat: 25 chunks/block)
// ---------------------------------------------------------------------------
__global__ __launch_bounds__(256) void prep_crit(
    const float* __restrict__ x0, unsigned int* __restrict__ xmask,
    unsigned int* __restrict__ xmaskT,
    const float* __restrict__ enc_w1, unsigned short* __restrict__ w1b)
{
  __shared__ unsigned int T[32][64];
  __shared__ unsigned int nib[256];
  const int id = blockIdx.x, tid = threadIdx.x;
  if (id < 800) {
    int rg = id / 25, ch = id % 25;
    int r0 = rg * 32, c0 = ch * 2048, c0w = ch * 64;
    for (int rr = 0; rr < 32; ++rr) {
      int k = c0 + tid * 8;
      const float* row = x0 + (size_t)(r0 + rr) * NI;
      float4 a = make_float4(0.f, 0.f, 0.f, 0.f), b = a;
      if (k + 8 <= NI) {
        a = *(const float4*)(row + k);
        b = *(const float4*)(row + k + 4);
      }
      unsigned bits8 =
          (a.x != 0.f ? 1u : 0u)  | (a.y != 0.f ? 2u : 0u)  |
          (a.z != 0.f ? 4u : 0u)  | (a.w != 0.f ? 8u : 0u)  |
          (b.x != 0.f ? 16u : 0u) | (b.y != 0.f ? 32u : 0u) |
          (b.z != 0.f ? 64u : 0u) | (b.w != 0.f ? 128u : 0u);
      nib[tid] = bits8;
      __syncthreads();
      if (tid < 64) {
        T[rr][tid] = nib[tid * 4] | (nib[tid * 4 + 1] << 8) |
                     (nib[tid * 4 + 2] << 16) | (nib[tid * 4 + 3] << 24);
      }
      __syncthreads();
    }
    // write xmask rows: thread t -> row t>>3, word-group t&7 (8 words)
    {
      int rr = tid >> 3, wg = (tid & 7) * 8;
      if (c0w + wg < MW) {            // chunk 24: wg>=32 entirely out of range
        unsigned* dst = xmask + (size_t)(r0 + rr) * MW + c0w + wg;
        uint4 q0 = make_uint4(T[rr][wg], T[rr][wg+1], T[rr][wg+2], T[rr][wg+3]);
        uint4 q1 = make_uint4(T[rr][wg+4], T[rr][wg+5], T[rr][wg+6], T[rr][wg+7]);
        *(uint4*)dst = q0; *(uint4*)(dst + 4) = q1;
      }
    }
    // write xmaskT cols: thread t -> word t>>2, row-group t&3 (8 rows)
    {
      int ww = tid >> 2, rg8 = (tid & 3) * 8;
      if (c0w + ww < MW) {
        unsigned* dst = xmaskT + (size_t)(c0w + ww) * 1024 + r0 + rg8;
        uint4 q0 = make_uint4(T[rg8][ww], T[rg8+1][ww], T[rg8+2][ww], T[rg8+3][ww]);
        uint4 q1 = make_uint4(T[rg8+4][ww], T[rg8+5][ww], T[rg8+6][ww], T[rg8+7][ww]);
        *(uint4*)dst = q0; *(uint4*)(dst + 4) = q1;
      }
    }
  } else {
    int r = id - 800;
    const float* s = enc_w1 + (size_t)r * NI;
    for (int ch = 0; ch < 25; ++ch) {
      int c = ch * 2048 + tid * 8;
      if (c >= KP) continue;
      uint4 o;
      if (c + 8 <= NI) {
        float4 a = *(const float4*)(s + c), b = *(const float4*)(s + c + 4);
        o.x = pack2(a.x, a.y); o.y = pack2(a.z, a.w);
        o.z = pack2(b.x, b.y); o.w = pack2(b.z, b.w);
      } else {
        float v[8];
#pragma unroll
        for (int i = 0; i < 8; ++i) v[i] = (c + i < NI) ? s[c + i] : 0.f;
        o.x = pack2(v[0], v[1]); o.y = pack2(v[2], v[3]);
        o.z = pack2(v[4], v[5]); o.w = pack2(v[6], v[7]);
      }
      *(uint4*)(w1b + (size_t)r * KP + c) = o;
    }
  }
}

// ---------------------------------------------------------------------------
// enc_fused: enc GEMM (blocks [0,1024)) + independent late prep fused in.
// enc: C_partial[kc] = x0(bits) @ w1b^T, BK=64 (24 full iters + BK32 tail),
//   B double-buffered 2-half LDS (round-4 addressing per half, no swizzle),
//   mask via contiguous GLD4 from xmaskT, counted vmcnt(5/3/0).
// trailing blocks:
//   [1024, 2592) cvt_w2n   (dec_w2 -> bf16, grid-stride)
//   [2592, 3040) cvt_many  (7 small weights)
//   [3040, 3808) compose_k (fused kv / sa weights)
//   [3808, 4832) prep_te   (te rows + schedule scalars)
// ---------------------------------------------------------------------------
#define EF_ENC  1024
#define EF_W2N  2592
#define EF_MANY 3040
#define EF_COMP 3808
#define EF_TE   4832

__global__ __launch_bounds__(256) void enc_fused(
    const unsigned int* __restrict__ xmaskT,
    const unsigned short* __restrict__ Bw,
    float* __restrict__ P0, float* __restrict__ P1,
    const float* __restrict__ dec_w2, unsigned short* __restrict__ w2n,
    const float* s0a, const float* s1a, const float* s2a, const float* s3a,
    const float* s4a, const float* s5a, const float* s6a,
    unsigned short* d0a, unsigned short* d1a, unsigned short* d2a, unsigned short* d3a,
    unsigned short* d4a, unsigned short* d5a, unsigned short* d6a,
    const float* __restrict__ ca_wqkv, const float* __restrict__ ca_bqkv,
    const float* __restrict__ ip_w, const float* __restrict__ ip_b,
    const float* __restrict__ sa_wqkv, const float* __restrict__ sa_bqkv,
    const float* __restrict__ sa_wo, const float* __restrict__ sa_bo,
    unsigned short* __restrict__ Wkv, float* __restrict__ bkv,
    unsigned short* __restrict__ Wsa, float* __restrict__ bsa,
    const int* __restrict__ t,
    const float* __restrict__ te_w1, const float* __restrict__ te_b1,
    const float* __restrict__ te_w2, const float* __restrict__ te_b2,
    float* __restrict__ te, float* __restrict__ sab, float* __restrict__ s1ab)
{
  __shared__ __align__(16) unsigned short BsE[2][2][128 * 32];   // 32 KB
  __shared__ __align__(16) unsigned short lut[256][8];           // 4 KB
  __shared__ unsigned int mskb[2][2][128];                       // 2 KB
  __shared__ float sj[32];
  const int id = blockIdx.x, tid = threadIdx.x;

  if (id < EF_ENC) {
    const int g = (id & 7) + 8 * (id >> 6);
    const int m0 = ((id >> 3) & 7) * 128;
    const int n0 = (g & 3) * 128;
    const int kc = g >> 2;                 // 0..31
    const int kb = kc * 1568;
    const int kw0 = kc * 49;
    const int w = tid >> 6, l = tid & 63;
    const int wm = (w >> 1) * 64, wn = (w & 1) * 64;
    const int fr = l & 15, fo = (l >> 4) * 8;
    const int s0 = tid, s1 = tid + 256;
    const unsigned short* Br0 = Bw + (size_t)(n0 + (s0 >> 2)) * KP + kb + (s0 & 3) * 8;
    const unsigned short* Br1 = Bw + (size_t)(n0 + (s1 >> 2)) * KP + kb + (s1 & 3) * 8;
    f32x4 acc[4][4] = {};

    // LUT init: entry tid = 8 bf16 decoded from bits of tid
    {
      unsigned b = (unsigned)tid;
      uint4 q;
      q.x = (b & 1u   ? 0x3F80u : 0u) | (b & 2u   ? 0x3F800000u : 0u);
      q.y = (b & 4u   ? 0x3F80u : 0u) | (b & 8u   ? 0x3F800000u : 0u);
      q.z = (b & 16u  ? 0x3F80u : 0u) | (b & 32u  ? 0x3F800000u : 0u);
      q.w = (b & 64u  ? 0x3F80u : 0u) | (b & 128u ? 0x3F800000u : 0u);
      *(uint4*)&lut[tid][0] = q;
    }

    // full stage IT in [0,24): 1 GLD4 (mask, contiguous) + 4 GLD16 (B halves)
#define STGF(IT, BUF) do {                                                  \
    GLD4(xmaskT + (size_t)(kw0 + (IT) * 2 + (w & 1)) * 1024                 \
                + m0 + (w >> 1) * 64 + l,                                   \
         &mskb[BUF][w & 1][(w >> 1) * 64]);                                 \
    GLD16(Br0 + (IT) * 64,      &BsE[BUF][0][s0 * 8]);                      \
    GLD16(Br1 + (IT) * 64,      &BsE[BUF][0][s1 * 8]);                      \
    GLD16(Br0 + (IT) * 64 + 32, &BsE[BUF][1][s0 * 8]);                      \
    GLD16(Br1 + (IT) * 64 + 32, &BsE[BUF][1][s1 * 8]); } while (0)

    // tail stage (k 1536..1567, word 48): 1 GLD4 + 2 GLD16 (half 0)
#define STGT(BUF) do {                                                      \
    GLD4(xmaskT + (size_t)(kw0 + 48) * 1024 + m0 + (w & 1) * 64 + l,        \
         &mskb[BUF][0][(w & 1) * 64]);                                      \
    GLD16(Br0 + 24 * 64, &BsE[BUF][0][s0 * 8]);                             \
    GLD16(Br1 + 24 * 64, &BsE[BUF][0][s1 * 8]); } while (0)

#define CMPH(BUF, KK) do {                                                  \
    const unsigned short *ap_[4], *bp_[4];                                  \
    _Pragma("unroll") for (int i_ = 0; i_ < 4; ++i_)                        \
      ap_[i_] = &lut[(mskb[BUF][KK][wm + 16 * i_ + fr] >> fo) & 0xFF][0];   \
    _Pragma("unroll") for (int j_ = 0; j_ < 4; ++j_)                        \
      bp_[j_] = &BsE[BUF][KK][(wn + 16 * j_ + fr) * 32 + fo];               \
    _Pragma("unroll") for (int i_ = 0; i_ < 4; ++i_)                        \
    _Pragma("unroll") for (int j_ = 0; j_ < 4; ++j_)                        \
      acc[i_][j_] = mfma16(ap_[i_], bp_[j_], acc[i_][j_]); } while (0)

    STGF(0, 0);
    STGF(1, 1);
    asm volatile("s_waitcnt vmcnt(5) lgkmcnt(0)" ::: "memory");
    PIPE_FENCE(); RAW_BAR(); PIPE_FENCE();
    for (int it = 0; it < 24; ++it) {
      CMPH(it & 1, 0);
      CMPH(it & 1, 1);
      PIPE_FENCE(); RAW_BAR(); PIPE_FENCE();
      if (it < 22) {
        STGF(it + 2, it & 1);
        asm volatile("s_waitcnt vmcnt(5)" ::: "memory");
      } else if (it == 22) {
        STGT(0);
        asm volatile("s_waitcnt vmcnt(3)" ::: "memory");
      } else {
        asm volatile("s_waitcnt vmcnt(0)" ::: "memory");
      }
      PIPE_FENCE(); RAW_BAR(); PIPE_FENCE();
    }
    CMPH(0, 0);                         // tail: k 1536..1567 in buf0 half0
#undef STGF
#undef STGT
#undef CMPH

    const int cr = (l >> 4) * 4, cc = l & 15;
    float* Cp = ((kc < 16) ? P0 : P1) + (size_t)(kc & 15) * 524288;
#pragma unroll
    for (int i = 0; i < 4; ++i)
#pragma unroll
      for (int j = 0; j < 4; ++j) {
        int n = n0 + wn + 16 * j + cc;
#pragma unroll
        for (int r = 0; r < 4; ++r) {
          int m = m0 + wm + 16 * i + cr + r;
          Cp[(size_t)m * 512 + n] = acc[i][j][r];
        }
      }
  } else if (id < EF_W2N) {
    // ---- cvt_w2n (grid-stride) ----
    size_t b2 = id - EF_ENC;
    for (size_t e = (b2 * 256 + tid) * 8; e < 25600000u; e += (size_t)1568 * 256 * 8) {
      float4 a = *(const float4*)(dec_w2 + e), b = *(const float4*)(dec_w2 + e + 4);
      uint4 o;
      o.x = pack2(a.x, a.y); o.y = pack2(a.z, a.w);
      o.z = pack2(b.x, b.y); o.w = pack2(b.z, b.w);
      *(uint4*)(w2n + e) = o;
    }
  } else if (id < EF_MANY) {
    // ---- cvt_many ----
    const float* srcs[7] = {s0a, s1a, s2a, s3a, s4a, s5a, s6a};
    unsigned short* dsts[7] = {d0a, d1a, d2a, d3a, d4a, d5a, d6a};
    const int ns[7] = {131072, 65536, 65536, 65536, 131072, 131072, 131072};
    int q = id - EF_W2N;
    int j = q >> 6;
    int i = ((q & 63) * 256 + tid) * 8;
    if (i >= ns[j]) return;
    float4 a = *(const float4*)(srcs[j] + i), b = *(const float4*)(srcs[j] + i + 4);
    uint4 o;
    o.x = pack2(a.x, a.y); o.y = pack2(a.z, a.w);
    o.z = pack2(b.x, b.y); o.w = pack2(b.z, b.w);
    *(uint4*)(dsts[j] + i) = o;
  } else if (id < EF_COMP) {
    // ---- compose_k ----
    int b = id - EF_MANY, k = tid;
    if (b < 512) {
      const float* wrow = ca_wqkv + (size_t)(256 + b) * 256;
      float s = 0.f;
      for (int c = 0; c < 256; ++c) s += wrow[c] * ip_w[c * 256 + k];
      Wkv[b * 256 + k] = f2bf(s);
      if (k == 0) {
        float sb = 0.f;
        for (int c = 0; c < 256; ++c) sb += wrow[c] * ip_b[c];
        bkv[b] = sb + ca_bqkv[256 + b];
      }
    } else {
      int i = b - 512;
      const float* worow = sa_wo + (size_t)i * 256;
      float s = 0.f;
      for (int c = 0; c < 256; ++c) s += worow[c] * sa_wqkv[(512 + c) * 256 + k];
      Wsa[i * 256 + k] = f2bf(s);
      if (k == 0) {
        float sb = 0.f;
        for (int c = 0; c < 256; ++c) sb += worow[c] * sa_bqkv[512 + c];
        bsa[i] = sb + sa_bo[i];
      }
    }
  } else {
    // ---- prep_te ----
    int b = id - EF_COMP, d = tid;
    int ti = t[b];
    float tn = (float)ti / (float)Tt;
    if (d < 32) {
      float a = tn * te_w1[d] + te_b1[d];
      sj[d] = a / (1.f + __expf(-a));
    }
    if (d == 0) {
      double tt = (double)(ti + 1) / (double)Tt;
      double c  = cos((tt + 0.008) / 1.008 * M_PI * 0.5);
      double c0 = cos((0.008) / 1.008 * M_PI * 0.5);
      double ab = (c * c) / (c0 * c0);
      sab[b]  = (float)sqrt(ab);
      s1ab[b] = (float)sqrt(1.0 - ab);
    }
    __syncthreads();
    float accv = te_b2[d];
#pragma unroll
    for (int j = 0; j < 32; ++j) accv += sj[j] * te_w2[d * 32 + j];
    te[(size_t)b * 256 + d] = accv;
  }
}

// ---------------------------------------------------------------------------
// gemm128<T>: 128x128 tile, pure GLD16 staging (m97 structure, single-buffer)
// T0: C bf16 = acc + bias (grid (mx,ny))
// T1: dec recon loss, linear grid 3136, XCD-swizzled, n-groups of 8 m-blocks
// ---------------------------------------------------------------------------
template<int T>
__global__ __launch_bounds__(256) void gemm128(
    const unsigned short* __restrict__ A, int lda,
    const unsigned short* __restrict__ Bw, int ldb,
    const float* __restrict__ bias, void* __restrict__ Cv, int ldc, int K,
    const unsigned int* __restrict__ xmask, float* __restrict__ loss, int Nvalid)
{
  __shared__ __align__(16) unsigned short As[128 * 32];
  __shared__ __align__(16) unsigned short Bs[128 * 32];
  __shared__ unsigned int msk[128][4];
  __shared__ float red[4];
  const int tid = threadIdx.x;
  int m0, n0, iters;
  if (T == 1) {
    int id = blockIdx.x;
    int n = (id & 7) + 8 * (id >> 6);
    if (n >= 391) return;
    m0 = ((id >> 3) & 7) * 128;
    n0 = n * 128;
    iters = 16;
  } else {
    m0 = blockIdx.x * 128; n0 = blockIdx.y * 128;
    iters = K >> 5;
  }
  const int w = tid >> 6, l = tid & 63;
  const int wm = (w >> 1) * 64, wn = (w & 1) * 64;
  const int fr = l & 15, fo = (l >> 4) * 8;
  const int s0 = tid, s1 = tid + 256;
  f32x4 acc[4][4] = {};
  for (int it = 0; it < iters; ++it) {
    int k0 = it * 32;
    __syncthreads();
    GLD16(A  + (size_t)(m0 + (s0 >> 2)) * lda + k0 + (s0 & 3) * 8, &As[s0 * 8]);
    GLD16(A  + (size_t)(m0 + (s1 >> 2)) * lda + k0 + (s1 & 3) * 8, &As[s1 * 8]);
    GLD16(Bw + (size_t)(n0 + (s0 >> 2)) * ldb + k0 + (s0 & 3) * 8, &Bs[s0 * 8]);
    GLD16(Bw + (size_t)(n0 + (s1 >> 2)) * ldb + k0 + (s1 & 3) * 8, &Bs[s1 * 8]);
    __syncthreads();
    const unsigned short *ap[4], *bp[4];
#pragma unroll
    for (int i = 0; i < 4; ++i) {
      ap[i] = &As[(wm + 16 * i + fr) * 32 + fo];
      bp[i] = &Bs[(wn + 16 * i + fr) * 32 + fo];
    }
#pragma unroll
    for (int i = 0; i < 4; ++i)
#pragma unroll
      for (int j = 0; j < 4; ++j)
        acc[i][j] = mfma16(ap[i], bp[j], acc[i][j]);
  }
  const int cr = (l >> 4) * 4, cc = l & 15;
  if (T == 0) {
    unsigned short* Cb = (unsigned short*)Cv;
#pragma unroll
    for (int j = 0; j < 4; ++j) {
      int n = n0 + wn + 16 * j + cc;
      float bv = bias[n];
#pragma unroll
      for (int i = 0; i < 4; ++i)
#pragma unroll
        for (int r = 0; r < 4; ++r) {
          int m = m0 + wm + 16 * i + cr + r;
          Cb[(size_t)m * ldc + n] = f2bf(acc[i][j][r] + bv);
        }
    }
  } else {
    {
      int row = tid >> 1, p = tid & 1;
      *(uint2*)&msk[row][p * 2] =
          *(const uint2*)(xmask + (size_t)(m0 + row) * MW + (n0 >> 5) + p * 2);
    }
    __syncthreads();
    float ts = 0.f;
#pragma unroll
    for (int j = 0; j < 4; ++j) {
      int nl = wn + 16 * j + cc;
      int n = n0 + nl;
      if (n < Nvalid) {
        float bv = bias[n];
#pragma unroll
        for (int i = 0; i < 4; ++i)
#pragma unroll
          for (int r = 0; r < 4; ++r) {
            int ml = wm + 16 * i + cr + r;
            float lg = acc[i][j][r] + bv;
            float sp = fmaxf(lg, 0.f) + __logf(1.f + __expf(-fabsf(lg)));
            unsigned word = msk[ml][nl >> 5];
            ts += sp - (((word >> (nl & 31)) & 1u) ? lg : 0.f);
          }
      }
    }
    for (int off = 32; off > 0; off >>= 1) ts += __shfl_xor(ts, off);
    if (l == 0) red[w] = ts;
    __syncthreads();
    if (tid == 0) atomicAdd(loss, red[0] + red[1] + red[2] + red[3]);
  }
}

// ---------------------------------------------------------------------------
// gemm64<EPI>: 64x64 tile GLD16 bf16 GEMM for the mid-chain (single-buffer)
// EPI 0: f32 = acc+bias       1: bf16         2: gelu->bf16
//     3: z0 triple-write (z0f, z0b, ztb)      4: +te -> bf16 (qp)
//     5: ff2: +h2b residual, (v - z0f)^2 -> atomic loss
// ---------------------------------------------------------------------------
template<int EPI>
__global__ __launch_bounds__(256) void gemm64(
    const unsigned short* __restrict__ A, int lda,
    const unsigned short* __restrict__ Bw, int ldb,
    const float* __restrict__ bias, void* __restrict__ Cv, int ldc, int K,
    const void* __restrict__ R0, const void* __restrict__ R1, const void* __restrict__ R2,
    void* __restrict__ W0, void* __restrict__ W1, float* __restrict__ loss)
{
  __shared__ __align__(16) unsigned short As[64 * 32];
  __shared__ __align__(16) unsigned short Bs[64 * 32];
  __shared__ float red[4];
  const int tid = threadIdx.x;
  const int m0 = blockIdx.x * 64, n0 = blockIdx.y * 64;
  const int w = tid >> 6, l = tid & 63;
  const int wm = (w >> 1) * 32, wn = (w & 1) * 32;
  const int fr = l & 15, fo = (l >> 4) * 8;
  const int srow = tid >> 2, scol = (tid & 3) * 8;
  f32x4 acc[2][2] = {};
  for (int k0 = 0; k0 < K; k0 += 32) {
    __syncthreads();
    GLD16(A  + (size_t)(m0 + srow) * lda + k0 + scol, &As[tid * 8]);
    GLD16(Bw + (size_t)(n0 + srow) * ldb + k0 + scol, &Bs[tid * 8]);
    __syncthreads();
    const unsigned short* ap0 = &As[(wm +      fr) * 32 + fo];
    const unsigned short* ap1 = &As[(wm + 16 + fr) * 32 + fo];
    const unsigned short* bp0 = &Bs[(wn +      fr) * 32 + fo];
    const unsigned short* bp1 = &Bs[(wn + 16 + fr) * 32 + fo];
    acc[0][0] = mfma16(ap0, bp0, acc[0][0]);
    acc[0][1] = mfma16(ap0, bp1, acc[0][1]);
    acc[1][0] = mfma16(ap1, bp0, acc[1][0]);
    acc[1][1] = mfma16(ap1, bp1, acc[1][1]);
  }
  const int cr = (l >> 4) * 4, cc = l & 15;
  float ts = 0.f;
#pragma unroll
  for (int i = 0; i < 2; ++i)
#pragma unroll
    for (int j = 0; j < 2; ++j) {
      int n = n0 + wn + 16 * j + cc;
      float bv = bias[n];
#pragma unroll
      for (int r = 0; r < 4; ++r) {
        int m = m0 + wm + 16 * i + cr + r;
        float v = acc[i][j][r] + bv;
        size_t idx = (size_t)m * ldc + n;
        if (EPI == 0) ((float*)Cv)[idx] = v;
        if (EPI == 1) ((unsigned short*)Cv)[idx] = f2bf(v);
        if (EPI == 2) ((unsigned short*)Cv)[idx] = f2bf(gelu_f(v));
        if (EPI == 3) {
          ((float*)Cv)[idx] = v;
          ((unsigned short*)W0)[idx] = f2bf(v);
          float zt = ((const float*)R1)[m] * v +
                     ((const float*)R2)[m] * ((const float*)R0)[idx];
          ((unsigned short*)W1)[idx] = f2bf(zt);
        }
        if (EPI == 4) {
          v += ((const float*)R0)[idx];
          ((unsigned short*)Cv)[idx] = f2bf(v);
        }
        if (EPI == 5) {
          v += bf2f(((const unsigned short*)R0)[idx]);
          float d = v - ((const float*)R1)[idx];
          ts += d * d;
        }
      }
    }
  if (EPI == 5) {
    for (int off = 32; off > 0; off >>= 1) ts += __shfl_xor(ts, off);
    if (l == 0) red[w] = ts;
    __syncthreads();
    if (tid == 0) atomicAdd(loss, red[0] + red[1] + red[2] + red[3]);
  }
}

// H1b = gelu(sum_k P0[k]+P1[k] + enc_b1) -> bf16, 1024x512; 32-slice reduce
__global__ __launch_bounds__(256) void h1_epi(const float* __restrict__ P0,
                                              const float* __restrict__ P1,
                                              const float* __restrict__ b,
                                              unsigned short* __restrict__ H) {
  int i = blockIdx.x * 256 + threadIdx.x;
  float s = b[i & 511];
#pragma unroll
  for (int k = 0; k < 16; ++k) s += P0[(size_t)k * 524288 + i];
#pragma unroll
  for (int k = 0; k < 16; ++k) s += P1[(size_t)k * 524288 + i];
  H[i] = f2bf(gelu_f(s));
}

// gather neighbors -> bf16 (fat: one block per batch row, 20 neighbors)
__global__ __launch_bounds__(256) void gather_nb(
    const int* __restrict__ uid, const int* __restrict__ nidx,
    const float* __restrict__ emb, unsigned short* __restrict__ nb)
{
  int b = blockIdx.x, d = threadIdx.x;
  const int* np = nidx + uid[b] * 20;
#pragma unroll
  for (int j = 0; j < 20; ++j) {
    int idx = np[j];
    nb[((size_t)b * 20 + j) * 256 + d] = f2bf(emb[(size_t)idx * 256 + d]);
  }
}

// cross-attention core: 20 keys, one wave per (b, head); kvh bf16
__global__ __launch_bounds__(256) void attn_k(
    const float* __restrict__ qh, const unsigned short* __restrict__ kvh,
    unsigned short* __restrict__ o)
{
  int b = blockIdx.x, tid = threadIdx.x;
  int h = tid >> 6, d = tid & 63;
  float qv = qh[(size_t)b * 256 + h * 64 + d];
  const unsigned short* kbase = kvh + (size_t)b * 20 * 512 + h * 64 + d;
  const unsigned short* vbase = kbase + 256;
  float s[20];
#pragma unroll
  for (int k = 0; k < 20; ++k) {
    float p = qv * bf2f(kbase[k * 512]);
    for (int off = 32; off > 0; off >>= 1) p += __shfl_xor(p, off);
    s[k] = p * 0.125f;
  }
  float mx = s[0];
#pragma unroll
  for (int k = 1; k < 20; ++k) mx = fmaxf(mx, s[k]);
  float sum = 0.f;
#pragma unroll
  for (int k = 0; k < 20; ++k) { s[k] = __expf(s[k] - mx); sum += s[k]; }
  float inv = 1.f / sum;
  float ov = 0.f;
#pragma unroll
  for (int k = 0; k < 20; ++k) ov += s[k] * bf2f(vbase[k * 512]);
  o[(size_t)b * 256 + h * 64 + d] = f2bf(ov * inv);
}

// LayerNorm(X + Y), bf16 in/out
__global__ __launch_bounds__(256) void ln_k(
    const unsigned short* __restrict__ X, const unsigned short* __restrict__ Y,
    const float* __restrict__ g, const float* __restrict__ bb,
    unsigned short* __restrict__ out)
{
  __shared__ float rs[4], rs2[4];
  int b = blockIdx.x, d = threadIdx.x;
  size_t i = (size_t)b * 256 + d;
  float v = bf2f(X[i]) + bf2f(Y[i]);
  float s = v, s2 = v * v;
  for (int off = 32; off > 0; off >>= 1) { s += __shfl_xor(s, off); s2 += __shfl_xor(s2, off); }
  int w = d >> 6, l = d & 63;
  if (l == 0) { rs[w] = s; rs2[w] = s2; }
  __syncthreads();
  s  = rs[0] + rs[1] + rs[2] + rs[3];
  s2 = rs2[0] + rs2[1] + rs2[2] + rs2[3];
  float mean = s * (1.f / 256.f);
  float var  = s2 * (1.f / 256.f) - mean * mean;
  out[i] = f2bf((v - mean) * rsqrtf(var + 1e-5f) * g[d] + bb[d]);
}

__global__ void final_k(const float* __restrict__ scal, float* __restrict__ out) {
  out[0] = scal[0] * (1.f / (1024.f * 256.f)) + 0.1f * scal[1] * (1.f / (1024.f * 50000.f));
}

// ---------------------------------------------------------------------------
extern "C" void kernel_launch(void* const* d_in, const int* in_sizes, int n_in,
                              void* d_out, int out_size, void* d_ws, size_t ws_size,
                              hipStream_t stream) {
  const float* x0      = (const float*)d_in[0];
  const int*   uid     = (const int*)  d_in[1];
  const int*   t       = (const int*)  d_in[2];
  const float* noise   = (const float*)d_in[3];
  const int*   nidx    = (const int*)  d_in[4];
  const float* item_emb= (const float*)d_in[5];
  const float* enc_w1  = (const float*)d_in[6];
  const float* enc_b1  = (const float*)d_in[7];
  const float* enc_w2  = (const float*)d_in[8];
  const float* enc_b2  = (const float*)d_in[9];
  const float* dec_w1  = (const float*)d_in[10];
  const float* dec_b1  = (const float*)d_in[11];
  const float* dec_w2  = (const float*)d_in[12];
  const float* dec_b2  = (const float*)d_in[13];
  const float* up_w    = (const float*)d_in[14];
  const float* up_b    = (const float*)d_in[15];
  const float* ip_w    = (const float*)d_in[16];
  const float* ip_b    = (const float*)d_in[17];
  const float* te_w1   = (const float*)d_in[18];
  const float* te_b1   = (const float*)d_in[19];
  const float* te_w2   = (const float*)d_in[20];
  const float* te_b2   = (const float*)d_in[21];
  const float* ca_wqkv = (const float*)d_in[22];
  const float* ca_bqkv = (const float*)d_in[23];
  const float* ca_wo   = (const float*)d_in[24];
  const float* ca_bo   = (const float*)d_in[25];
  const float* sa_wqkv = (const float*)d_in[26];
  const float* sa_bqkv = (const float*)d_in[27];
  const float* sa_wo   = (const float*)d_in[28];
  const float* sa_bo   = (const float*)d_in[29];
  const float* n1_g    = (const float*)d_in[30];
  const float* n1_b    = (const float*)d_in[31];
  const float* n2_g    = (const float*)d_in[32];
  const float* n2_b    = (const float*)d_in[33];
  const float* ff_w1   = (const float*)d_in[34];
  const float* ff_b1   = (const float*)d_in[35];
  const float* ff_w2   = (const float*)d_in[36];
  const float* ff_b2   = (const float*)d_in[37];
  (void)in_sizes; (void)n_in; (void)out_size; (void)ws_size;

  float* ws   = (float*)d_ws;
  float* scal = ws;                    // 4 (diff, recon)
  float* sab  = ws + 4;                // 1024
  float* s1ab = sab + 1024;
  float* te   = s1ab + 1024;           // 1024*256
  float* qhf  = te + 262144;           // 1024*256
  float* z0f  = qhf + 262144;          // 1024*256
  float* bkv  = z0f + 262144;          // 512
  float* bsa  = bkv + 512;             // 256
  unsigned int* xmask = (unsigned int*)(bsa + 256);           // 1024*MW
  // P-pool bank0: slices 0-15 (33,554,432 B) aliases [nbb|kvhb|f1b|Gb]
  unsigned short* sh  = (unsigned short*)(xmask + 1024 * MW);
  float*          OUTp = (float*)sh;                          // 8,388,608 f32
  unsigned short* nbb  = sh;                                  // 20480*256
  unsigned short* kvhb = nbb + 5242880;                       // 20480*512
  unsigned short* f1b  = kvhb + 10485760;                     // 1024*512
  unsigned short* Gb   = f1b + 524288;                        // 1024*512
  unsigned short* x0b  = Gb + 524288;                         // dead region: holds w2n + xmaskT
  unsigned short* w2n  = x0b;                                 // 25.6M shorts
  unsigned int*   xmaskT = (unsigned int*)(x0b + 26214400);   // MW*1024 words (6.4 MB)
  unsigned short* w1b  = x0b + (size_t)1024 * KP;             // 512*KP
  unsigned short* H1b  = w1b + (size_t)512 * KP;              // 1024*512
  unsigned short* z0b  = H1b + 524288;
  unsigned short* ztb  = z0b + 262144;
  unsigned short* qpb  = ztb + 262144;
  unsigned short* ob   = qpb + 262144;
  unsigned short* cab  = ob  + 262144;
  unsigned short* hb   = cab + 262144;
  unsigned short* saob = hb  + 262144;
  unsigned short* h2b  = saob+ 262144;
  unsigned short* enc_w2b = h2b + 262144;                     // 131072
  unsigned short* up_wb   = enc_w2b + 131072;
  unsigned short* ca_wqb  = up_wb + 65536;
  unsigned short* ca_wob  = ca_wqb + 65536;
  unsigned short* ff_w1b  = ca_wob + 65536;
  unsigned short* ff_w2b  = ff_w1b + 131072;
  unsigned short* dec_w1b = ff_w2b + 131072;
  unsigned short* Wkv     = dec_w1b + 131072;
  unsigned short* Wsab    = Wkv + 131072;
  // P-pool bank1: slices 16-31
  float*          OUTp2   = (float*)(Wsab + 131072);          // 8,388,608 f32

  hipMemsetAsync(scal, 0, 4 * sizeof(float), stream);

  // critical prep: bits (both layouts) + w1 bf16
  prep_crit<<<1312, 256, 0, stream>>>(x0, xmask, xmaskT, enc_w1, w1b);

  // enc GEMM (BK=64, transposed-mask GLD4) + all independent late prep fused
  enc_fused<<<EF_TE, 256, 0, stream>>>(
      xmaskT, w1b, OUTp, OUTp2,
      dec_w2, w2n,
      enc_w2, up_w, ca_wqkv, ca_wo, ff_w1, ff_w2, dec_w1,
      enc_w2b, up_wb, ca_wqb, ca_wob, ff_w1b, ff_w2b, dec_w1b,
      ca_wqkv, ca_bqkv, ip_w, ip_b, sa_wqkv, sa_bqkv, sa_wo, sa_bo,
      Wkv, bkv, Wsab, bsa,
      t, te_w1, te_b1, te_w2, te_b2, te, sab, s1ab);
  h1_epi<<<2048, 256, 0, stream>>>(OUTp, OUTp2, enc_b1, H1b);  // OUTp dead after

  // kv path (P-pool bank0 live again: OUTp dead)
  gather_nb<<<1024, 256, 0, stream>>>(uid, nidx, item_emb, nbb);
  gemm128<0><<<dim3(160, 4), 256, 0, stream>>>(
      nbb, 256, Wkv, 256, bkv, kvhb, 512, 256, nullptr, nullptr, 0);

  // z0 GEMM + fused z_t
  gemm64<3><<<dim3(16, 4), 256, 0, stream>>>(
      H1b, 512, enc_w2b, 512, enc_b2, z0f, 256, 512, noise, sab, s1ab, z0b, ztb, nullptr);

  // q path
  gemm64<4><<<dim3(16, 4), 256, 0, stream>>>(
      ztb, 256, up_wb, 256, up_b, qpb, 256, 256, te, nullptr, nullptr, nullptr, nullptr, nullptr);
  gemm64<0><<<dim3(16, 4), 256, 0, stream>>>(
      qpb, 256, ca_wqb, 256, ca_bqkv, qhf, 256, 256,
      nullptr, nullptr, nullptr, nullptr, nullptr, nullptr);

  // attention + out-proj + LN1
  attn_k<<<1024, 256, 0, stream>>>(qhf, kvhb, ob);
  gemm64<1><<<dim3(16, 4), 256, 0, stream>>>(
      ob, 256, ca_wob, 256, ca_bo, cab, 256, 256,
      nullptr, nullptr, nullptr, nullptr, nullptr, nullptr);
  ln_k<<<1024, 256, 0, stream>>>(qpb, cab, n1_g, n1_b, hb);

  // self-attn (seq=1, composed) + LN2
  gemm64<1><<<dim3(16, 4), 256, 0, stream>>>(
      hb, 256, Wsab, 256, bsa, saob, 256, 256,
      nullptr, nullptr, nullptr, nullptr, nullptr, nullptr);
  ln_k<<<1024, 256, 0, stream>>>(hb, saob, n2_g, n2_b, h2b);

  // FF with fused residual + diffusion loss
  gemm64<2><<<dim3(16, 8), 256, 0, stream>>>(
      h2b, 256, ff_w1b, 256, ff_b1, f1b, 512, 256,
      nullptr, nullptr, nullptr, nullptr, nullptr, nullptr);
  gemm64<5><<<dim3(16, 4), 256, 0, stream>>>(
      f1b, 512, ff_w2b, 512, ff_b2, nullptr, 256, 512,
      h2b, z0f, nullptr, nullptr, nullptr, &scal[0]);

  // decoder: G = gelu(z0@dec_w1^T+b) bf16, then big GEMM + fused recon loss
  gemm64<2><<<dim3(16, 8), 256, 0, stream>>>(
      z0b, 256, dec_w1b, 256, dec_b1, Gb, 512, 256,
      nullptr, nullptr, nullptr, nullptr, nullptr, nullptr);
  gemm128<1><<<3136, 256, 0, stream>>>(
      Gb, 512, w2n, 512, dec_b2, nullptr, 0, 512, xmask, &scal[1], NI);

  final_k<<<1, 1, 0, stream>>>(scal, (float*)d_out);
}

// Round 7
// 810.644 us; speedup vs baseline: 1.1341x; 1.0211x over previous
//
#include <hip/hip_runtime.h>
#include <math.h>

#define NI   50000
#define Tt   1000
#define KP   50176              // 50000 padded: 32 chunks x 1568 (=49*32)
#define MW   1568               // mask words per row (KP/32)
#define NPAD 50048              // 391*128 n-pad for dec gemm

typedef __bf16 bf16x8 __attribute__((ext_vector_type(8)));
typedef float  f32x4  __attribute__((ext_vector_type(4)));

__device__ __forceinline__ unsigned short f2bf(float f) {
  unsigned u = __float_as_uint(f);
  u += 0x7FFFu + ((u >> 16) & 1u);   // RNE
  return (unsigned short)(u >> 16);
}
__device__ __forceinline__ float bf2f(unsigned short u) {
  return __uint_as_float(((unsigned)u) << 16);
}
__device__ __forceinline__ unsigned pack2(float a, float b) {
  return (unsigned)f2bf(a) | ((unsigned)f2bf(b) << 16);
}
__device__ __forceinline__ f32x4 mfma16(const unsigned short* a, const unsigned short* b, f32x4 c) {
  typedef unsigned short u16x8 __attribute__((ext_vector_type(8)));
  u16x8 av = *(const u16x8*)a;
  u16x8 bv = *(const u16x8*)b;
  return __builtin_amdgcn_mfma_f32_16x16x32_bf16(
      __builtin_bit_cast(bf16x8, av), __builtin_bit_cast(bf16x8, bv), c, 0, 0, 0);
}
__device__ __forceinline__ float gelu_f(float x) {
  return 0.5f * x * (1.f + erff(x * 0.70710678118654752f));
}

#define GLD16(gsrc, ldst) __builtin_amdgcn_global_load_lds( \
    (const __attribute__((address_space(1))) unsigned int*)(const void*)(gsrc), \
    (__attribute__((address_space(3))) unsigned int*)(void*)(ldst), 16, 0, 0)
#define GLD4(gsrc, ldst) __builtin_amdgcn_global_load_lds( \
    (const __attribute__((address_space(1))) unsigned int*)(const void*)(gsrc), \
    (__attribute__((address_space(3))) unsigned int*)(void*)(ldst), 4, 0, 0)

#define PIPE_FENCE() __builtin_amdgcn_sched_barrier(0)
#define RAW_BAR()    __builtin_amdgcn_s_barrier()

// ---------------------------------------------------------------------------
// prep_crit (thin-block, barrier-light):
//   [0, 6272)      bm: one thread = one mask word (8 indep float4 loads).
//                  block = 32 rows x 8 words; xmask written from regs;
//                  ONE barrier for the 32x8 LDS transpose -> xmaskT.
//                  grid 32 rowgroups x 196 wordchunks.
//   [6272, 19072)  cvt_w1: thin (row, chunk) blocks, 2048 cols each.
// ---------------------------------------------------------------------------
#define PC_BM 6272
#define PC_W1 19072

__global__ __launch_bounds__(256) void prep_crit(
    const float* __restrict__ x0, unsigned int* __restrict__ xmask,
    unsigned int* __restrict__ xmaskT,
    const float* __restrict__ enc_w1, unsigned short* __restrict__ w1b)
{
  __shared__ unsigned int T[32][8];
  const int id = blockIdx.x, tid = threadIdx.x;
  if (id < PC_BM) {
    const int rg = id / 196, wc = id % 196;
    const int r0 = rg * 32, w0 = wc * 8;
    const int rr = tid >> 3, wd = tid & 7;
    const int row = r0 + rr;
    const int gw = w0 + wd;              // global word index, < MW always
    const int cb = gw * 32;              // col base
    const float* rp = x0 + (size_t)row * NI + cb;
    unsigned wv = 0;
    if (cb + 32 <= NI) {
#pragma unroll
      for (int k = 0; k < 8; ++k) {
        float4 v = *(const float4*)(rp + k * 4);
        wv |= (v.x != 0.f ? 1u : 0u) << (k * 4) |
              (v.y != 0.f ? 2u : 0u) << (k * 4) |
              (v.z != 0.f ? 4u : 0u) << (k * 4) |
              (v.w != 0.f ? 8u : 0u) << (k * 4);
      }
    } else {
      for (int k = 0; k < 32; ++k)
        if (cb + k < NI && rp[k] != 0.f) wv |= 1u << k;
    }
    T[rr][wd] = wv;
    xmask[(size_t)row * MW + gw] = wv;   // row-major, straight from regs
    __syncthreads();
    // transpose writeout: 32 threads per word-column, 128 B contiguous
    int wq = tid >> 5, r2 = tid & 31;
    xmaskT[(size_t)(w0 + wq) * 1024 + r0 + r2] = T[r2][wq];
  } else {
    int q = id - PC_BM;
    int r = q / 25, ch = q % 25;
    int c = ch * 2048 + tid * 8;
    if (c >= KP) return;
    const float* s = enc_w1 + (size_t)r * NI;
    uint4 o;
    if (c + 8 <= NI) {
      float4 a = *(const float4*)(s + c), b = *(const float4*)(s + c + 4);
      o.x = pack2(a.x, a.y); o.y = pack2(a.z, a.w);
      o.z = pack2(b.x, b.y); o.w = pack2(b.z, b.w);
    } else {
      float v[8];
#pragma unroll
      for (int i = 0; i < 8; ++i) v[i] = (c + i < NI) ? s[c + i] : 0.f;
      o.x = pack2(v[0], v[1]); o.y = pack2(v[2], v[3]);
      o.z = pack2(v[4], v[5]); o.w = pack2(v[6], v[7]);
    }
    *(uint4*)(w1b + (size_t)r * KP + c) = o;
  }
}

// ---------------------------------------------------------------------------
// enc_fused: enc GEMM (blocks [0,1024)) + independent late prep fused in.
// enc: C_partial[kc] = x0(bits) @ w1b^T, BK=64 (24 full iters + BK32 tail),
//   B double-buffered 2-half LDS, mask via contiguous GLD4 from xmaskT,
//   counted vmcnt(5/3/0).
// trailing blocks:
//   [1024, 2592) cvt_w2n   (dec_w2 -> bf16, grid-stride)
//   [2592, 3040) cvt_many  (7 small weights)
//   [3040, 3808) compose_k (fused kv / sa weights)
//   [3808, 4832) prep_te   (te rows + schedule scalars)
// ---------------------------------------------------------------------------
#define EF_ENC  1024
#define EF_W2N  2592
#define EF_MANY 3040
#define EF_COMP 3808
#define EF_TE   4832

__global__ __launch_bounds__(256) void enc_fused(
    const unsigned int* __restrict__ xmaskT,
    const unsigned short* __restrict__ Bw,
    float* __restrict__ P0, float* __restrict__ P1,
    const float* __restrict__ dec_w2, unsigned short* __restrict__ w2n,
    const float* s0a, const float* s1a, const float* s2a, const float* s3a,
    const float* s4a, const float* s5a, const float* s6a,
    unsigned short* d0a, unsigned short* d1a, unsigned short* d2a, unsigned short* d3a,
    unsigned short* d4a, unsigned short* d5a, unsigned short* d6a,
    const float* __restrict__ ca_wqkv, const float* __restrict__ ca_bqkv,
    const float* __restrict__ ip_w, const float* __restrict__ ip_b,
    const float* __restrict__ sa_wqkv, const float* __restrict__ sa_bqkv,
    const float* __restrict__ sa_wo, const float* __restrict__ sa_bo,
    unsigned short* __restrict__ Wkv, float* __restrict__ bkv,
    unsigned short* __restrict__ Wsa, float* __restrict__ bsa,
    const int* __restrict__ t,
    const float* __restrict__ te_w1, const float* __restrict__ te_b1,
    const float* __restrict__ te_w2, const float* __restrict__ te_b2,
    float* __restrict__ te, float* __restrict__ sab, float* __restrict__ s1ab)
{
  __shared__ __align__(16) unsigned short BsE[2][2][128 * 32];   // 32 KB
  __shared__ __align__(16) unsigned short lut[256][8];           // 4 KB
  __shared__ unsigned int mskb[2][2][128];                       // 2 KB
  __shared__ float sj[32];
  const int id = blockIdx.x, tid = threadIdx.x;

  if (id < EF_ENC) {
    const int g = (id & 7) + 8 * (id >> 6);
    const int m0 = ((id >> 3) & 7) * 128;
    const int n0 = (g & 3) * 128;
    const int kc = g >> 2;                 // 0..31
    const int kb = kc * 1568;
    const int kw0 = kc * 49;
    const int w = tid >> 6, l = tid & 63;
    const int wm = (w >> 1) * 64, wn = (w & 1) * 64;
    const int fr = l & 15, fo = (l >> 4) * 8;
    const int s0 = tid, s1 = tid + 256;
    const unsigned short* Br0 = Bw + (size_t)(n0 + (s0 >> 2)) * KP + kb + (s0 & 3) * 8;
    const unsigned short* Br1 = Bw + (size_t)(n0 + (s1 >> 2)) * KP + kb + (s1 & 3) * 8;
    f32x4 acc[4][4] = {};

    // LUT init: entry tid = 8 bf16 decoded from bits of tid
    {
      unsigned b = (unsigned)tid;
      uint4 q;
      q.x = (b & 1u   ? 0x3F80u : 0u) | (b & 2u   ? 0x3F800000u : 0u);
      q.y = (b & 4u   ? 0x3F80u : 0u) | (b & 8u   ? 0x3F800000u : 0u);
      q.z = (b & 16u  ? 0x3F80u : 0u) | (b & 32u  ? 0x3F800000u : 0u);
      q.w = (b & 64u  ? 0x3F80u : 0u) | (b & 128u ? 0x3F800000u : 0u);
      *(uint4*)&lut[tid][0] = q;
    }

    // full stage IT in [0,24): 1 GLD4 (mask, contiguous) + 4 GLD16 (B halves)
#define STGF(IT, BUF) do {                                                  \
    GLD4(xmaskT + (size_t)(kw0 + (IT) * 2 + (w & 1)) * 1024                 \
                + m0 + (w >> 1) * 64 + l,                                   \
         &mskb[BUF][w & 1][(w >> 1) * 64]);                                 \
    GLD16(Br0 + (IT) * 64,      &BsE[BUF][0][s0 * 8]);                      \
    GLD16(Br1 + (IT) * 64,      &BsE[BUF][0][s1 * 8]);                      \
    GLD16(Br0 + (IT) * 64 + 32, &BsE[BUF][1][s0 * 8]);                      \
    GLD16(Br1 + (IT) * 64 + 32, &BsE[BUF][1][s1 * 8]); } while (0)

    // tail stage (k 1536..1567, word 48): 1 GLD4 + 2 GLD16 (half 0)
#define STGT(BUF) do {                                                      \
    GLD4(xmaskT + (size_t)(kw0 + 48) * 1024 + m0 + (w & 1) * 64 + l,        \
         &mskb[BUF][0][(w & 1) * 64]);                                      \
    GLD16(Br0 + 24 * 64, &BsE[BUF][0][s0 * 8]);                             \
    GLD16(Br1 + 24 * 64, &BsE[BUF][0][s1 * 8]); } while (0)

#define CMPH(BUF, KK) do {                                                  \
    const unsigned short *ap_[4], *bp_[4];                                  \
    _Pragma("unroll") for (int i_ = 0; i_ < 4; ++i_)                        \
      ap_[i_] = &lut[(mskb[BUF][KK][wm + 16 * i_ + fr] >> fo) & 0xFF][0];   \
    _Pragma("unroll") for (int j_ = 0; j_ < 4; ++j_)                        \
      bp_[j_] = &BsE[BUF][KK][(wn + 16 * j_ + fr) * 32 + fo];               \
    _Pragma("unroll") for (int i_ = 0; i_ < 4; ++i_)                        \
    _Pragma("unroll") for (int j_ = 0; j_ < 4; ++j_)                        \
      acc[i_][j_] = mfma16(ap_[i_], bp_[j_], acc[i_][j_]); } while (0)

    STGF(0, 0);
    STGF(1, 1);
    asm volatile("s_waitcnt vmcnt(5) lgkmcnt(0)" ::: "memory");
    PIPE_FENCE(); RAW_BAR(); PIPE_FENCE();
    for (int it = 0; it < 24; ++it) {
      CMPH(it & 1, 0);
      CMPH(it & 1, 1);
      PIPE_FENCE(); RAW_BAR(); PIPE_FENCE();
      if (it < 22) {
        STGF(it + 2, it & 1);
        asm volatile("s_waitcnt vmcnt(5)" ::: "memory");
      } else if (it == 22) {
        STGT(0);
        asm volatile("s_waitcnt vmcnt(3)" ::: "memory");
      } else {
        asm volatile("s_waitcnt vmcnt(0)" ::: "memory");
      }
      PIPE_FENCE(); RAW_BAR(); PIPE_FENCE();
    }
    CMPH(0, 0);                         // tail: k 1536..1567 in buf0 half0
#undef STGF
#undef STGT
#undef CMPH

    const int cr = (l >> 4) * 4, cc = l & 15;
    float* Cp = ((kc < 16) ? P0 : P1) + (size_t)(kc & 15) * 524288;
#pragma unroll
    for (int i = 0; i < 4; ++i)
#pragma unroll
      for (int j = 0; j < 4; ++j) {
        int n = n0 + wn + 16 * j + cc;
#pragma unroll
        for (int r = 0; r < 4; ++r) {
          int m = m0 + wm + 16 * i + cr + r;
          Cp[(size_t)m * 512 + n] = acc[i][j][r];
        }
      }
  } else if (id < EF_W2N) {
    // ---- cvt_w2n (grid-stride) ----
    size_t b2 = id - EF_ENC;
    for (size_t e = (b2 * 256 + tid) * 8; e < 25600000u; e += (size_t)1568 * 256 * 8) {
      float4 a = *(const float4*)(dec_w2 + e), b = *(const float4*)(dec_w2 + e + 4);
      uint4 o;
      o.x = pack2(a.x, a.y); o.y = pack2(a.z, a.w);
      o.z = pack2(b.x, b.y); o.w = pack2(b.z, b.w);
      *(uint4*)(w2n + e) = o;
    }
  } else if (id < EF_MANY) {
    // ---- cvt_many ----
    const float* srcs[7] = {s0a, s1a, s2a, s3a, s4a, s5a, s6a};
    unsigned short* dsts[7] = {d0a, d1a, d2a, d3a, d4a, d5a, d6a};
    const int ns[7] = {131072, 65536, 65536, 65536, 131072, 131072, 131072};
    int q = id - EF_W2N;
    int j = q >> 6;
    int i = ((q & 63) * 256 + tid) * 8;
    if (i >= ns[j]) return;
    float4 a = *(const float4*)(srcs[j] + i), b = *(const float4*)(srcs[j] + i + 4);
    uint4 o;
    o.x = pack2(a.x, a.y); o.y = pack2(a.z, a.w);
    o.z = pack2(b.x, b.y); o.w = pack2(b.z, b.w);
    *(uint4*)(dsts[j] + i) = o;
  } else if (id < EF_COMP) {
    // ---- compose_k ----
    int b = id - EF_MANY, k = tid;
    if (b < 512) {
      const float* wrow = ca_wqkv + (size_t)(256 + b) * 256;
      float s = 0.f;
      for (int c = 0; c < 256; ++c) s += wrow[c] * ip_w[c * 256 + k];
      Wkv[b * 256 + k] = f2bf(s);
      if (k == 0) {
        float sb = 0.f;
        for (int c = 0; c < 256; ++c) sb += wrow[c] * ip_b[c];
        bkv[b] = sb + ca_bqkv[256 + b];
      }
    } else {
      int i = b - 512;
      const float* worow = sa_wo + (size_t)i * 256;
      float s = 0.f;
      for (int c = 0; c < 256; ++c) s += worow[c] * sa_wqkv[(512 + c) * 256 + k];
      Wsa[i * 256 + k] = f2bf(s);
      if (k == 0) {
        float sb = 0.f;
        for (int c = 0; c < 256; ++c) sb += worow[c] * sa_bqkv[512 + c];
        bsa[i] = sb + sa_bo[i];
      }
    }
  } else {
    // ---- prep_te ----
    int b = id - EF_COMP, d = tid;
    int ti = t[b];
    float tn = (float)ti / (float)Tt;
    if (d < 32) {
      float a = tn * te_w1[d] + te_b1[d];
      sj[d] = a / (1.f + __expf(-a));
    }
    if (d == 0) {
      double tt = (double)(ti + 1) / (double)Tt;
      double c  = cos((tt + 0.008) / 1.008 * M_PI * 0.5);
      double c0 = cos((0.008) / 1.008 * M_PI * 0.5);
      double ab = (c * c) / (c0 * c0);
      sab[b]  = (float)sqrt(ab);
      s1ab[b] = (float)sqrt(1.0 - ab);
    }
    __syncthreads();
    float accv = te_b2[d];
#pragma unroll
    for (int j = 0; j < 32; ++j) accv += sj[j] * te_w2[d * 32 + j];
    te[(size_t)b * 256 + d] = accv;
  }
}

// ---------------------------------------------------------------------------
// gemm128<T>: 128x128 tile, pure GLD16 staging (m97 structure, single-buffer)
// T0: C bf16 = acc + bias (grid (mx,ny))
// T1: dec recon loss, linear grid 3136, XCD-swizzled, n-groups of 8 m-blocks
// ---------------------------------------------------------------------------
template<int T>
__global__ __launch_bounds__(256) void gemm128(
    const unsigned short* __restrict__ A, int lda,
    const unsigned short* __restrict__ Bw, int ldb,
    const float* __restrict__ bias, void* __restrict__ Cv, int ldc, int K,
    const unsigned int* __restrict__ xmask, float* __restrict__ loss, int Nvalid)
{
  __shared__ __align__(16) unsigned short As[128 * 32];
  __shared__ __align__(16) unsigned short Bs[128 * 32];
  __shared__ unsigned int msk[128][4];
  __shared__ float red[4];
  const int tid = threadIdx.x;
  int m0, n0, iters;
  if (T == 1) {
    int id = blockIdx.x;
    int n = (id & 7) + 8 * (id >> 6);
    if (n >= 391) return;
    m0 = ((id >> 3) & 7) * 128;
    n0 = n * 128;
    iters = 16;
  } else {
    m0 = blockIdx.x * 128; n0 = blockIdx.y * 128;
    iters = K >> 5;
  }
  const int w = tid >> 6, l = tid & 63;
  const int wm = (w >> 1) * 64, wn = (w & 1) * 64;
  const int fr = l & 15, fo = (l >> 4) * 8;
  const int s0 = tid, s1 = tid + 256;
  f32x4 acc[4][4] = {};
  for (int it = 0; it < iters; ++it) {
    int k0 = it * 32;
    __syncthreads();
    GLD16(A  + (size_t)(m0 + (s0 >> 2)) * lda + k0 + (s0 & 3) * 8, &As[s0 * 8]);
    GLD16(A  + (size_t)(m0 + (s1 >> 2)) * lda + k0 + (s1 & 3) * 8, &As[s1 * 8]);
    GLD16(Bw + (size_t)(n0 + (s0 >> 2)) * ldb + k0 + (s0 & 3) * 8, &Bs[s0 * 8]);
    GLD16(Bw + (size_t)(n0 + (s1 >> 2)) * ldb + k0 + (s1 & 3) * 8, &Bs[s1 * 8]);
    __syncthreads();
    const unsigned short *ap[4], *bp[4];
#pragma unroll
    for (int i = 0; i < 4; ++i) {
      ap[i] = &As[(wm + 16 * i + fr) * 32 + fo];
      bp[i] = &Bs[(wn + 16 * i + fr) * 32 + fo];
    }
#pragma unroll
    for (int i = 0; i < 4; ++i)
#pragma unroll
      for (int j = 0; j < 4; ++j)
        acc[i][j] = mfma16(ap[i], bp[j], acc[i][j]);
  }
  const int cr = (l >> 4) * 4, cc = l & 15;
  if (T == 0) {
    unsigned short* Cb = (unsigned short*)Cv;
#pragma unroll
    for (int j = 0; j < 4; ++j) {
      int n = n0 + wn + 16 * j + cc;
      float bv = bias[n];
#pragma unroll
      for (int i = 0; i < 4; ++i)
#pragma unroll
        for (int r = 0; r < 4; ++r) {
          int m = m0 + wm + 16 * i + cr + r;
          Cb[(size_t)m * ldc + n] = f2bf(acc[i][j][r] + bv);
        }
    }
  } else {
    {
      int row = tid >> 1, p = tid & 1;
      *(uint2*)&msk[row][p * 2] =
          *(const uint2*)(xmask + (size_t)(m0 + row) * MW + (n0 >> 5) + p * 2);
    }
    __syncthreads();
    float ts = 0.f;
#pragma unroll
    for (int j = 0; j < 4; ++j) {
      int nl = wn + 16 * j + cc;
      int n = n0 + nl;
      if (n < Nvalid) {
        float bv = bias[n];
#pragma unroll
        for (int i = 0; i < 4; ++i)
#pragma unroll
          for (int r = 0; r < 4; ++r) {
            int ml = wm + 16 * i + cr + r;
            float lg = acc[i][j][r] + bv;
            float sp = fmaxf(lg, 0.f) + __logf(1.f + __expf(-fabsf(lg)));
            unsigned word = msk[ml][nl >> 5];
            ts += sp - (((word >> (nl & 31)) & 1u) ? lg : 0.f);
          }
      }
    }
    for (int off = 32; off > 0; off >>= 1) ts += __shfl_xor(ts, off);
    if (l == 0) red[w] = ts;
    __syncthreads();
    if (tid == 0) atomicAdd(loss, red[0] + red[1] + red[2] + red[3]);
  }
}

// ---------------------------------------------------------------------------
// gemm64<EPI>: 64x64 tile GLD16 bf16 GEMM for the mid-chain (single-buffer)
// EPI 0: f32 = acc+bias       1: bf16         2: gelu->bf16
//     3: z0 triple-write (z0f, z0b, ztb)      4: +te -> bf16 (qp)
//     5: ff2: +h2b residual, (v - z0f)^2 -> atomic loss
// ---------------------------------------------------------------------------
template<int EPI>
__global__ __launch_bounds__(256) void gemm64(
    const unsigned short* __restrict__ A, int lda,
    const unsigned short* __restrict__ Bw, int ldb,
    const float* __restrict__ bias, void* __restrict__ Cv, int ldc, int K,
    const void* __restrict__ R0, const void* __restrict__ R1, const void* __restrict__ R2,
    void* __restrict__ W0, void* __restrict__ W1, float* __restrict__ loss)
{
  __shared__ __align__(16) unsigned short As[64 * 32];
  __shared__ __align__(16) unsigned short Bs[64 * 32];
  __shared__ float red[4];
  const int tid = threadIdx.x;
  const int m0 = blockIdx.x * 64, n0 = blockIdx.y * 64;
  const int w = tid >> 6, l = tid & 63;
  const int wm = (w >> 1) * 32, wn = (w & 1) * 32;
  const int fr = l & 15, fo = (l >> 4) * 8;
  const int srow = tid >> 2, scol = (tid & 3) * 8;
  f32x4 acc[2][2] = {};
  for (int k0 = 0; k0 < K; k0 += 32) {
    __syncthreads();
    GLD16(A  + (size_t)(m0 + srow) * lda + k0 + scol, &As[tid * 8]);
    GLD16(Bw + (size_t)(n0 + srow) * ldb + k0 + scol, &Bs[tid * 8]);
    __syncthreads();
    const unsigned short* ap0 = &As[(wm +      fr) * 32 + fo];
    const unsigned short* ap1 = &As[(wm + 16 + fr) * 32 + fo];
    const unsigned short* bp0 = &Bs[(wn +      fr) * 32 + fo];
    const unsigned short* bp1 = &Bs[(wn + 16 + fr) * 32 + fo];
    acc[0][0] = mfma16(ap0, bp0, acc[0][0]);
    acc[0][1] = mfma16(ap0, bp1, acc[0][1]);
    acc[1][0] = mfma16(ap1, bp0, acc[1][0]);
    acc[1][1] = mfma16(ap1, bp1, acc[1][1]);
  }
  const int cr = (l >> 4) * 4, cc = l & 15;
  float ts = 0.f;
#pragma unroll
  for (int i = 0; i < 2; ++i)
#pragma unroll
    for (int j = 0; j < 2; ++j) {
      int n = n0 + wn + 16 * j + cc;
      float bv = bias[n];
#pragma unroll
      for (int r = 0; r < 4; ++r) {
        int m = m0 + wm + 16 * i + cr + r;
        float v = acc[i][j][r] + bv;
        size_t idx = (size_t)m * ldc + n;
        if (EPI == 0) ((float*)Cv)[idx] = v;
        if (EPI == 1) ((unsigned short*)Cv)[idx] = f2bf(v);
        if (EPI == 2) ((unsigned short*)Cv)[idx] = f2bf(gelu_f(v));
        if (EPI == 3) {
          ((float*)Cv)[idx] = v;
          ((unsigned short*)W0)[idx] = f2bf(v);
          float zt = ((const float*)R1)[m] * v +
                     ((const float*)R2)[m] * ((const float*)R0)[idx];
          ((unsigned short*)W1)[idx] = f2bf(zt);
        }
        if (EPI == 4) {
          v += ((const float*)R0)[idx];
          ((unsigned short*)Cv)[idx] = f2bf(v);
        }
        if (EPI == 5) {
          v += bf2f(((const unsigned short*)R0)[idx]);
          float d = v - ((const float*)R1)[idx];
          ts += d * d;
        }
      }
    }
  if (EPI == 5) {
    for (int off = 32; off > 0; off >>= 1) ts += __shfl_xor(ts, off);
    if (l == 0) red[w] = ts;
    __syncthreads();
    if (tid == 0) atomicAdd(loss, red[0] + red[1] + red[2] + red[3]);
  }
}

// H1b = gelu(sum_k P0[k]+P1[k] + enc_b1) -> bf16, 1024x512; 32-slice reduce
__global__ __launch_bounds__(256) void h1_epi(const float* __restrict__ P0,
                                              const float* __restrict__ P1,
                                              const float* __restrict__ b,
                                              unsigned short* __restrict__ H) {
  int i = blockIdx.x * 256 + threadIdx.x;
  float s = b[i & 511];
#pragma unroll
  for (int k = 0; k < 16; ++k) s += P0[(size_t)k * 524288 + i];
#pragma unroll
  for (int k = 0; k < 16; ++k) s += P1[(size_t)k * 524288 + i];
  H[i] = f2bf(gelu_f(s));
}

// gather neighbors -> bf16 (fat: one block per batch row, 20 neighbors)
__global__ __launch_bounds__(256) void gather_nb(
    const int* __restrict__ uid, const int* __restrict__ nidx,
    const float* __restrict__ emb, unsigned short* __restrict__ nb)
{
  int b = blockIdx.x, d = threadIdx.x;
  const int* np = nidx + uid[b] * 20;
#pragma unroll
  for (int j = 0; j < 20; ++j) {
    int idx = np[j];
    nb[((size_t)b * 20 + j) * 256 + d] = f2bf(emb[(size_t)idx * 256 + d]);
  }
}

// cross-attention core: 20 keys, one wave per (b, head); kvh bf16
__global__ __launch_bounds__(256) void attn_k(
    const float* __restrict__ qh, const unsigned short* __restrict__ kvh,
    unsigned short* __restrict__ o)
{
  int b = blockIdx.x, tid = threadIdx.x;
  int h = tid >> 6, d = tid & 63;
  float qv = qh[(size_t)b * 256 + h * 64 + d];
  const unsigned short* kbase = kvh + (size_t)b * 20 * 512 + h * 64 + d;
  const unsigned short* vbase = kbase + 256;
  float s[20];
#pragma unroll
  for (int k = 0; k < 20; ++k) {
    float p = qv * bf2f(kbase[k * 512]);
    for (int off = 32; off > 0; off >>= 1) p += __shfl_xor(p, off);
    s[k] = p * 0.125f;
  }
  float mx = s[0];
#pragma unroll
  for (int k = 1; k < 20; ++k) mx = fmaxf(mx, s[k]);
  float sum = 0.f;
#pragma unroll
  for (int k = 0; k < 20; ++k) { s[k] = __expf(s[k] - mx); sum += s[k]; }
  float inv = 1.f / sum;
  float ov = 0.f;
#pragma unroll
  for (int k = 0; k < 20; ++k) ov += s[k] * bf2f(vbase[k * 512]);
  o[(size_t)b * 256 + h * 64 + d] = f2bf(ov * inv);
}

// LayerNorm(X + Y), bf16 in/out
__global__ __launch_bounds__(256) void ln_k(
    const unsigned short* __restrict__ X, const unsigned short* __restrict__ Y,
    const float* __restrict__ g, const float* __restrict__ bb,
    unsigned short* __restrict__ out)
{
  __shared__ float rs[4], rs2[4];
  int b = blockIdx.x, d = threadIdx.x;
  size_t i = (size_t)b * 256 + d;
  float v = bf2f(X[i]) + bf2f(Y[i]);
  float s = v, s2 = v * v;
  for (int off = 32; off > 0; off >>= 1) { s += __shfl_xor(s, off); s2 += __shfl_xor(s2, off); }
  int w = d >> 6, l = d & 63;
  if (l == 0) { rs[w] = s; rs2[w] = s2; }
  __syncthreads();
  s  = rs[0] + rs[1] + rs[2] + rs[3];
  s2 = rs2[0] + rs2[1] + rs2[2] + rs2[3];
  float mean = s * (1.f / 256.f);
  float var  = s2 * (1.f / 256.f) - mean * mean;
  out[i] = f2bf((v - mean) * rsqrtf(var + 1e-5f) * g[d] + bb[d]);
}

__global__ void final_k(const float* __restrict__ scal, float* __restrict__ out) {
  out[0] = scal[0] * (1.f / (1024.f * 256.f)) + 0.1f * scal[1] * (1.f / (1024.f * 50000.f));
}

// ---------------------------------------------------------------------------
extern "C" void kernel_launch(void* const* d_in, const int* in_sizes, int n_in,
                              void* d_out, int out_size, void* d_ws, size_t ws_size,
                              hipStream_t stream) {
  const float* x0      = (const float*)d_in[0];
  const int*   uid     = (const int*)  d_in[1];
  const int*   t       = (const int*)  d_in[2];
  const float* noise   = (const float*)d_in[3];
  const int*   nidx    = (const int*)  d_in[4];
  const float* item_emb= (const float*)d_in[5];
  const float* enc_w1  = (const float*)d_in[6];
  const float* enc_b1  = (const float*)d_in[7];
  const float* enc_w2  = (const float*)d_in[8];
  const float* enc_b2  = (const float*)d_in[9];
  const float* dec_w1  = (const float*)d_in[10];
  const float* dec_b1  = (const float*)d_in[11];
  const float* dec_w2  = (const float*)d_in[12];
  const float* dec_b2  = (const float*)d_in[13];
  const float* up_w    = (const float*)d_in[14];
  const float* up_b    = (const float*)d_in[15];
  const float* ip_w    = (const float*)d_in[16];
  const float* ip_b    = (const float*)d_in[17];
  const float* te_w1   = (const float*)d_in[18];
  const float* te_b1   = (const float*)d_in[19];
  const float* te_w2   = (const float*)d_in[20];
  const float* te_b2   = (const float*)d_in[21];
  const float* ca_wqkv = (const float*)d_in[22];
  const float* ca_bqkv = (const float*)d_in[23];
  const float* ca_wo   = (const float*)d_in[24];
  const float* ca_bo   = (const float*)d_in[25];
  const float* sa_wqkv = (const float*)d_in[26];
  const float* sa_bqkv = (const float*)d_in[27];
  const float* sa_wo   = (const float*)d_in[28];
  const float* sa_bo   = (const float*)d_in[29];
  const float* n1_g    = (const float*)d_in[30];
  const float* n1_b    = (const float*)d_in[31];
  const float* n2_g    = (const float*)d_in[32];
  const float* n2_b    = (const float*)d_in[33];
  const float* ff_w1   = (const float*)d_in[34];
  const float* ff_b1   = (const float*)d_in[35];
  const float* ff_w2   = (const float*)d_in[36];
  const float* ff_b2   = (const float*)d_in[37];
  (void)in_sizes; (void)n_in; (void)out_size; (void)ws_size;

  float* ws   = (float*)d_ws;
  float* scal = ws;                    // 4 (diff, recon)
  float* sab  = ws + 4;                // 1024
  float* s1ab = sab + 1024;
  float* te   = s1ab + 1024;           // 1024*256
  float* qhf  = te + 262144;           // 1024*256
  float* z0f  = qhf + 262144;          // 1024*256
  float* bkv  = z0f + 262144;          // 512
  float* bsa  = bkv + 512;             // 256
  unsigned int* xmask = (unsigned int*)(bsa + 256);           // 1024*MW
  // P-pool bank0: slices 0-15 (33,554,432 B) aliases [nbb|kvhb|f1b|Gb]
  unsigned short* sh  = (unsigned short*)(xmask + 1024 * MW);
  float*          OUTp = (float*)sh;                          // 8,388,608 f32
  unsigned short* nbb  = sh;                                  // 20480*256
  unsigned short* kvhb = nbb + 5242880;                       // 20480*512
  unsigned short* f1b  = kvhb + 10485760;                     // 1024*512
  unsigned short* Gb   = f1b + 524288;                        // 1024*512
  unsigned short* x0b  = Gb + 524288;                         // dead region: holds w2n + xmaskT
  unsigned short* w2n  = x0b;                                 // 25.6M shorts
  unsigned int*   xmaskT = (unsigned int*)(x0b + 26214400);   // MW*1024 words (6.4 MB)
  unsigned short* w1b  = x0b + (size_t)1024 * KP;             // 512*KP
  unsigned short* H1b  = w1b + (size_t)512 * KP;              // 1024*512
  unsigned short* z0b  = H1b + 524288;
  unsigned short* ztb  = z0b + 262144;
  unsigned short* qpb  = ztb + 262144;
  unsigned short* ob   = qpb + 262144;
  unsigned short* cab  = ob  + 262144;
  unsigned short* hb   = cab + 262144;
  unsigned short* saob = hb  + 262144;
  unsigned short* h2b  = saob+ 262144;
  unsigned short* enc_w2b = h2b + 262144;                     // 131072
  unsigned short* up_wb   = enc_w2b + 131072;
  unsigned short* ca_wqb  = up_wb + 65536;
  unsigned short* ca_wob  = ca_wqb + 65536;
  unsigned short* ff_w1b  = ca_wob + 65536;
  unsigned short* ff_w2b  = ff_w1b + 131072;
  unsigned short* dec_w1b = ff_w2b + 131072;
  unsigned short* Wkv     = dec_w1b + 131072;
  unsigned short* Wsab    = Wkv + 131072;
  // P-pool bank1: slices 16-31
  float*          OUTp2   = (float*)(Wsab + 131072);          // 8,388,608 f32

  hipMemsetAsync(scal, 0, 4 * sizeof(float), stream);

  // critical prep: bits (both layouts) + w1 bf16 — thin blocks, barrier-light
  prep_crit<<<PC_W1, 256, 0, stream>>>(x0, xmask, xmaskT, enc_w1, w1b);

  // enc GEMM (BK=64, transposed-mask GLD4) + all independent late prep fused
  enc_fused<<<EF_TE, 256, 0, stream>>>(
      xmaskT, w1b, OUTp, OUTp2,
      dec_w2, w2n,
      enc_w2, up_w, ca_wqkv, ca_wo, ff_w1, ff_w2, dec_w1,
      enc_w2b, up_wb, ca_wqb, ca_wob, ff_w1b, ff_w2b, dec_w1b,
      ca_wqkv, ca_bqkv, ip_w, ip_b, sa_wqkv, sa_bqkv, sa_wo, sa_bo,
      Wkv, bkv, Wsab, bsa,
      t, te_w1, te_b1, te_w2, te_b2, te, sab, s1ab);
  h1_epi<<<2048, 256, 0, stream>>>(OUTp, OUTp2, enc_b1, H1b);  // OUTp dead after

  // kv path (P-pool bank0 live again: OUTp dead)
  gather_nb<<<1024, 256, 0, stream>>>(uid, nidx, item_emb, nbb);
  gemm128<0><<<dim3(160, 4), 256, 0, stream>>>(
      nbb, 256, Wkv, 256, bkv, kvhb, 512, 256, nullptr, nullptr, 0);

  // z0 GEMM + fused z_t
  gemm64<3><<<dim3(16, 4), 256, 0, stream>>>(
      H1b, 512, enc_w2b, 512, enc_b2, z0f, 256, 512, noise, sab, s1ab, z0b, ztb, nullptr);

  // q path
  gemm64<4><<<dim3(16, 4), 256, 0, stream>>>(
      ztb, 256, up_wb, 256, up_b, qpb, 256, 256, te, nullptr, nullptr, nullptr, nullptr, nullptr);
  gemm64<0><<<dim3(16, 4), 256, 0, stream>>>(
      qpb, 256, ca_wqb, 256, ca_bqkv, qhf, 256, 256,
      nullptr, nullptr, nullptr, nullptr, nullptr, nullptr);

  // attention + out-proj + LN1
  attn_k<<<1024, 256, 0, stream>>>(qhf, kvhb, ob);
  gemm64<1><<<dim3(16, 4), 256, 0, stream>>>(
      ob, 256, ca_wob, 256, ca_bo, cab, 256, 256,
      nullptr, nullptr, nullptr, nullptr, nullptr, nullptr);
  ln_k<<<1024, 256, 0, stream>>>(qpb, cab, n1_g, n1_b, hb);

  // self-attn (seq=1, composed) + LN2
  gemm64<1><<<dim3(16, 4), 256, 0, stream>>>(
      hb, 256, Wsab, 256, bsa, saob, 256, 256,
      nullptr, nullptr, nullptr, nullptr, nullptr, nullptr);
  ln_k<<<1024, 256, 0, stream>>>(hb, saob, n2_g, n2_b, h2b);

  // FF with fused residual + diffusion loss
  gemm64<2><<<dim3(16, 8), 256, 0, stream>>>(
      h2b, 256, ff_w1b, 256, ff_b1, f1b, 512, 256,
      nullptr, nullptr, nullptr, nullptr, nullptr, nullptr);
  gemm64<5><<<dim3(16, 4), 256, 0, stream>>>(
      f1b, 512, ff_w2b, 512, ff_b2, nullptr, 256, 512,
      h2b, z0f, nullptr, nullptr, nullptr, &scal[0]);

  // decoder: G = gelu(z0@dec_w1^T+b) bf16, then big GEMM + fused recon loss
  gemm64<2><<<dim3(16, 8), 256, 0, stream>>>(
      z0b, 256, dec_w1b, 256, dec_b1, Gb, 512, 256,
      nullptr, nullptr, nullptr, nullptr, nullptr, nullptr);
  gemm128<1><<<3136, 256, 0, stream>>>(
      Gb, 512, w2n, 512, dec_b2, nullptr, 0, 512, xmask, &scal[1], NI);

  final_k<<<1, 1, 0, stream>>>(scal, (float*)d_out);
}